// Round 4
// baseline (589.931 us; speedup 1.0000x reference)
//
#include <hip/hip_runtime.h>
#include <cstdint>
#include <cstddef>

// ---------------------------------------------------------------------------
// EnhancedObj: visual/object attention block, bf16-MFMA implementation.
// Shapes (hardcoded): bs=8, F=64, obj=36, d=2048.
//   MO = 18432 object rows, MV = 512 visual rows, NOBJ = 2304.
// Round 4: obj GEMM -> 256x256 tile, 8 waves (2Mx4N, wave tile 128x64),
// 64 K-phases of 32, 4 rotating 32KB LDS half-slots (128KB), stage 3 phases
// ahead, counted vmcnt(8), raw barriers, setprio, column-major [k16][row]
// LDS (conflict-free without swizzle). Epilogue fused: tanh -> bf16 T +
// per-row LN partial sums; k_ep_ln2 finishes LN. fp32 Yo eliminated.
// ---------------------------------------------------------------------------

typedef __attribute__((ext_vector_type(4))) float f32x4;
typedef __attribute__((ext_vector_type(4))) unsigned int u32x4;
typedef __attribute__((ext_vector_type(8))) short bf16x8;

#define DD 2048
#define BS 8
#define FF 64
#define NOBJ 2304
#define MO 18432
#define MV 512

__device__ __forceinline__ unsigned short f2bf(float f) {
  unsigned int u = __float_as_uint(f);
  u += 0x7fffu + ((u >> 16) & 1u);          // RTNE (inputs finite)
  return (unsigned short)(u >> 16);
}
__device__ __forceinline__ unsigned int pk2(float a, float b) {
  return (unsigned int)f2bf(a) | ((unsigned int)f2bf(b) << 16);
}
__device__ __forceinline__ float bf2f(unsigned short u) {
  return __uint_as_float((unsigned int)u << 16);
}

typedef __attribute__((address_space(1))) const unsigned int gas_u32;
typedef __attribute__((address_space(3))) unsigned int las_u32;
__device__ __forceinline__ void gl_lds16(const void* g, void* l) {
  __builtin_amdgcn_global_load_lds((gas_u32*)g, (las_u32*)l, 16, 0, 0);
}

// --------------------------------------------------------------------------
// fp32 -> bf16 bulk convert. Each thread: 16 elements per iter.
// --------------------------------------------------------------------------
__global__ __launch_bounds__(256) void k_cvt_bf16(const float* __restrict__ X,
                                                  unsigned short* __restrict__ O,
                                                  int n16) {
  int idx = blockIdx.x * 256 + threadIdx.x;
  const int stride = gridDim.x * 256;
  for (int i = idx; i < n16; i += stride) {
    const f32x4* src = (const f32x4*)(X + (size_t)i * 16);
    f32x4 a = src[0], b = src[1], c = src[2], d = src[3];
    u32x4 p = {pk2(a.x, a.y), pk2(a.z, a.w), pk2(b.x, b.y), pk2(b.z, b.w)};
    u32x4 q = {pk2(c.x, c.y), pk2(c.z, c.w), pk2(d.x, d.y), pk2(d.z, d.w)};
    u32x4* dst = (u32x4*)(O + (size_t)i * 16);
    dst[0] = p;
    dst[1] = q;
  }
}

// --------------------------------------------------------------------------
// W[k][n] fp32 (2048x2048) -> Wt[n][k] bf16. 64x64 tiles via LDS.
// --------------------------------------------------------------------------
__global__ __launch_bounds__(256) void k_wprep(const float* __restrict__ W,
                                               unsigned short* __restrict__ Wt) {
  __shared__ unsigned short sh[64][65];
  const int t = threadIdx.x;
  const int kb = blockIdx.x * 64, nb = blockIdx.y * 64;
  {
    const int rk = t >> 2, seg = t & 3;
    const float* src = W + (size_t)(kb + rk) * DD + nb + seg * 16;
#pragma unroll
    for (int q = 0; q < 4; ++q) {
      f32x4 x = *(const f32x4*)(src + q * 4);
      sh[rk][seg * 16 + q * 4 + 0] = f2bf(x.x);
      sh[rk][seg * 16 + q * 4 + 1] = f2bf(x.y);
      sh[rk][seg * 16 + q * 4 + 2] = f2bf(x.z);
      sh[rk][seg * 16 + q * 4 + 3] = f2bf(x.w);
    }
  }
  __syncthreads();
  {
    const int nn = t >> 2, ks = t & 3;
    unsigned int o[8];
#pragma unroll
    for (int j = 0; j < 8; ++j)
      o[j] = (unsigned int)sh[ks * 16 + 2 * j][nn] |
             ((unsigned int)sh[ks * 16 + 2 * j + 1][nn] << 16);
    u32x4 p0 = {o[0], o[1], o[2], o[3]};
    u32x4 p1 = {o[4], o[5], o[6], o[7]};
    unsigned short* dst = Wt + (size_t)(nb + nn) * DD + kb + ks * 16;
    ((u32x4*)dst)[0] = p0;
    ((u32x4*)dst)[1] = p1;
  }
}

// --------------------------------------------------------------------------
// Obj GEMM fused: T[MO][2048] = bf16(tanh(A@Bt^T + bias)), plus per-row
// partial LN sums part[row][32][2] = {sum t, sum t^2} over 64-col groups.
// BM=256 BN=256 BK(phase)=32, 512 thr = 8 waves (wm 0..1, wn 0..3),
// wave tile 128x64. 64 phases; 4 rotating half-slots (A 16KB + B 16KB each).
// Phase P: stage half P+3 into slot (P+3)&3 (= slot read in phase P-1,
// safe past its tail barrier); ds_read frags of half P (slot P&3,
// column-major [k16][row] -> conflict-free); 32 MFMA; vmcnt(8) (half P+1
// landed, P+2/P+3 in flight across the barrier); s_barrier.
// grid = (8, 72); XCD-bijective swizzle.
// --------------------------------------------------------------------------
__global__ __launch_bounds__(512, 1) void k_gemm_bbf(const unsigned short* __restrict__ A,
                                                     const unsigned short* __restrict__ Bt,
                                                     const float* __restrict__ bias,
                                                     unsigned short* __restrict__ T,
                                                     float* __restrict__ part) {
  // 4 slots x (A-half 8192 shorts + B-half 8192 shorts) = 128 KiB
  __shared__ __align__(16) unsigned short lds[65536];
  const int tid = threadIdx.x;
  const int lane = tid & 63, wave = tid >> 6;
  const int r = lane & 15, g = lane >> 4;
  const int wm = wave >> 2, wn = wave & 3;

  // XCD-aware bijective remap (nwg = 576, %8 == 0, per = 72)
  const int orig = blockIdx.y * 8 + blockIdx.x;
  const int lin = (orig & 7) * 72 + (orig >> 3);
  const int bm = (lin >> 3) * 256;
  const int bn = (lin & 7) * 256;

  // staging: thread covers chunks c = tid and tid+512 of each half.
  // chunk c -> k16 = c>>8 (0..3), row = c&255. LDS offset = c*8 shorts.
  const int srow = tid & 255;
  const int k16a = tid >> 8;  // 0..1; second chunk is k16a+2
  const unsigned short* aS0 = A + (size_t)(bm + srow) * DD + k16a * 8;
  const unsigned short* bS0 = Bt + (size_t)(bn + srow) * DD + k16a * 8;

  auto stage = [&](int slot, int H) {
    unsigned short* base = lds + slot * 16384;
    const size_t ko = (size_t)H * 32;
    gl_lds16(aS0 + ko, base + tid * 8);
    gl_lds16(aS0 + ko + 16, base + (tid + 512) * 8);
    gl_lds16(bS0 + ko, base + 8192 + tid * 8);
    gl_lds16(bS0 + ko + 16, base + 8192 + (tid + 512) * 8);
  };

  // frag read offsets (shorts, within slot): A: (g*256 + wm*128 + mi*16 + r)*8
  const int aoff = (g * 256 + wm * 128 + r) * 8;
  const int boff = 8192 + (g * 256 + wn * 64 + r) * 8;

  f32x4 acc[8][4] = {};

  stage(0, 0);
  stage(1, 1);
  stage(2, 2);
  asm volatile("s_waitcnt vmcnt(8)" ::: "memory");  // half 0 landed
  __builtin_amdgcn_s_barrier();

  auto phase = [&](int P, int slotC, int slotS) {
    if (P + 3 < 64) stage(slotS, P + 3);
    const unsigned short* sb = lds + slotC * 16384;
    bf16x8 af[8], bfv[4];
#pragma unroll
    for (int mi = 0; mi < 8; ++mi)
      af[mi] = *(const bf16x8*)(sb + aoff + mi * 128);      // mi*16 rows * 8
#pragma unroll
    for (int ni = 0; ni < 4; ++ni)
      bfv[ni] = *(const bf16x8*)(sb + boff + ni * 128);
    __builtin_amdgcn_s_setprio(1);
#pragma unroll
    for (int mi = 0; mi < 8; ++mi)
#pragma unroll
      for (int ni = 0; ni < 4; ++ni)
        acc[mi][ni] = __builtin_amdgcn_mfma_f32_16x16x32_bf16(af[mi], bfv[ni], acc[mi][ni], 0, 0, 0);
    __builtin_amdgcn_s_setprio(0);
    if (P < 61) {
      asm volatile("s_waitcnt vmcnt(8)" ::: "memory");      // half P+1 landed
    } else if (P == 61) {
      asm volatile("s_waitcnt vmcnt(4)" ::: "memory");
    } else if (P == 62) {
      asm volatile("s_waitcnt vmcnt(0)" ::: "memory");
    }
    if (P < 63) __builtin_amdgcn_s_barrier();
  };

  for (int p4 = 0; p4 < 64; p4 += 4) {
    phase(p4 + 0, 0, 3);
    phase(p4 + 1, 1, 0);
    phase(p4 + 2, 2, 1);
    phase(p4 + 3, 3, 2);
  }

  // ---- fused epilogue: bias + tanh -> bf16 T, per-row partial LN sums ----
  float bv[4];
#pragma unroll
  for (int ni = 0; ni < 4; ++ni) bv[ni] = bias[bn + wn * 64 + ni * 16 + r];
  const int slot = ((lin & 7) << 2) + wn;  // 32 col-groups of 64
#pragma unroll
  for (int mi = 0; mi < 8; ++mi) {
#pragma unroll
    for (int i2 = 0; i2 < 4; ++i2) {
      const int row = bm + wm * 128 + mi * 16 + g * 4 + i2;
      unsigned short* trow = T + (size_t)row * DD + bn + wn * 64 + r;
      float s1 = 0.f, s2 = 0.f;
#pragma unroll
      for (int ni = 0; ni < 4; ++ni) {
        const float tv = tanhf(acc[mi][ni][i2] + bv[ni]);
        trow[ni * 16] = f2bf(tv);
        s1 += tv;
        s2 += tv * tv;
      }
#pragma unroll
      for (int m = 1; m < 16; m <<= 1) {
        s1 += __shfl_xor(s1, m, 64);
        s2 += __shfl_xor(s2, m, 64);
      }
      if (r == 0) {
        float2 p2 = make_float2(s1, s2);
        *(float2*)(part + (size_t)row * 64 + slot * 2) = p2;
      }
    }
  }
}

// --------------------------------------------------------------------------
// Finish obj LN: read T (bf16 tanh), partials; out oe_b = bf16(LN(t)*g+b).
// One block (256 thr) per row.
// --------------------------------------------------------------------------
__global__ __launch_bounds__(256) void k_ep_ln2(const unsigned short* __restrict__ T,
                                                const float* __restrict__ part,
                                                const float* __restrict__ gw,
                                                const float* __restrict__ bw,
                                                unsigned short* __restrict__ obf) {
  const int row = blockIdx.x, t = threadIdx.x;
  float s1 = 0.f, s2 = 0.f;
  if (t < 32) {
    float2 p = ((const float2*)(part + (size_t)row * 64))[t];
    s1 = p.x;
    s2 = p.y;
  }
#pragma unroll
  for (int m = 1; m < 64; m <<= 1) {
    s1 += __shfl_xor(s1, m, 64);
    s2 += __shfl_xor(s2, m, 64);
  }
  __shared__ float sh[2];
  if (t == 0) {
    sh[0] = s1;
    sh[1] = s2;
  }
  __syncthreads();
  const float mean = sh[0] * (1.0f / DD);
  const float var = sh[1] * (1.0f / DD) - mean * mean;
  const float rstd = rsqrtf(var + 1e-5f);
  const size_t base = (size_t)row * DD + t * 8;
  u32x4 tin = *(const u32x4*)(T + base);
  f32x4 g0 = ((const f32x4*)(gw + t * 8))[0], g1 = ((const f32x4*)(gw + t * 8))[1];
  f32x4 bb0 = ((const f32x4*)(bw + t * 8))[0], bb1 = ((const f32x4*)(bw + t * 8))[1];
  float o[8];
#pragma unroll
  for (int j = 0; j < 4; ++j) {
    const float tl = bf2f((unsigned short)(tin[j] & 0xffffu));
    const float th = bf2f((unsigned short)(tin[j] >> 16));
    o[2 * j] = (tl - mean) * rstd * ((const float*)&g0)[0] ;  // placeholder, fixed below
    (void)th;
  }
  // (recompute cleanly to avoid vector-index confusion)
  float gv[8], bvv[8];
  gv[0] = g0.x; gv[1] = g0.y; gv[2] = g0.z; gv[3] = g0.w;
  gv[4] = g1.x; gv[5] = g1.y; gv[6] = g1.z; gv[7] = g1.w;
  bvv[0] = bb0.x; bvv[1] = bb0.y; bvv[2] = bb0.z; bvv[3] = bb0.w;
  bvv[4] = bb1.x; bvv[5] = bb1.y; bvv[6] = bb1.z; bvv[7] = bb1.w;
#pragma unroll
  for (int j = 0; j < 4; ++j) {
    const float tl = bf2f((unsigned short)(tin[j] & 0xffffu));
    const float th = bf2f((unsigned short)(tin[j] >> 16));
    o[2 * j] = (tl - mean) * rstd * gv[2 * j] + bvv[2 * j];
    o[2 * j + 1] = (th - mean) * rstd * gv[2 * j + 1] + bvv[2 * j + 1];
  }
  u32x4 p = {pk2(o[0], o[1]), pk2(o[2], o[3]), pk2(o[4], o[5]), pk2(o[6], o[7])};
  *((u32x4*)(obf + base)) = p;
}

// --------------------------------------------------------------------------
// Y[M][2048] = X[M][2048](fp32) @ W + bias (inline convert). Visual branch.
// --------------------------------------------------------------------------
__global__ __launch_bounds__(256) void k_gemm_xw(const float* __restrict__ X,
                                                 const unsigned short* __restrict__ Wt,
                                                 const float* __restrict__ bias,
                                                 float* __restrict__ Y) {
  __shared__ __align__(16) unsigned short As[128 * 32];
  __shared__ __align__(16) unsigned short Bs[128 * 32];
  const int t = threadIdx.x;
  const int lane = t & 63, wave = t >> 6;
  const int r = lane & 15, g = lane >> 4;
  const int wm = wave >> 1, wn = wave & 1;
  const int bm = blockIdx.y * 128, bn = blockIdx.x * 128;
  const int arow = t >> 1, ah = t & 1;
  f32x4 acc[4][4] = {};
  const float* aptr = X + (size_t)(bm + arow) * DD + ah * 16;
  const unsigned short* bptr = Wt + (size_t)(bn + arow) * DD + ah * 16;
  for (int kt = 0; kt < DD / 32; ++kt) {
    const int kb = kt * 32;
    f32x4 a0 = *(const f32x4*)(aptr + kb);
    f32x4 a1 = *(const f32x4*)(aptr + kb + 4);
    f32x4 a2 = *(const f32x4*)(aptr + kb + 8);
    f32x4 a3 = *(const f32x4*)(aptr + kb + 12);
    u32x4 b0 = *(const u32x4*)(bptr + kb);
    u32x4 b1 = *(const u32x4*)(bptr + kb + 8);
    __syncthreads();
    u32x4 p0 = {pk2(a0.x, a0.y), pk2(a0.z, a0.w), pk2(a1.x, a1.y), pk2(a1.z, a1.w)};
    u32x4 p1 = {pk2(a2.x, a2.y), pk2(a2.z, a2.w), pk2(a3.x, a3.y), pk2(a3.z, a3.w)};
    ((u32x4*)As)[arow * 4 + ah * 2 + 0] = p0;
    ((u32x4*)As)[arow * 4 + ah * 2 + 1] = p1;
    ((u32x4*)Bs)[arow * 4 + ah * 2 + 0] = b0;
    ((u32x4*)Bs)[arow * 4 + ah * 2 + 1] = b1;
    __syncthreads();
    bf16x8 af[4], bfr[4];
#pragma unroll
    for (int m = 0; m < 4; ++m) af[m] = ((const bf16x8*)As)[(wm * 64 + m * 16 + r) * 4 + g];
#pragma unroll
    for (int n = 0; n < 4; ++n) bfr[n] = ((const bf16x8*)Bs)[(wn * 64 + n * 16 + r) * 4 + g];
#pragma unroll
    for (int m = 0; m < 4; ++m)
#pragma unroll
      for (int n = 0; n < 4; ++n)
        acc[m][n] = __builtin_amdgcn_mfma_f32_16x16x32_bf16(af[m], bfr[n], acc[m][n], 0, 0, 0);
  }
#pragma unroll
  for (int m = 0; m < 4; ++m) {
    const int row0 = bm + wm * 64 + m * 16 + g * 4;
#pragma unroll
    for (int n = 0; n < 4; ++n) {
      const int col = bn + wn * 64 + n * 16 + r;
      const float bvx = bias[col];
#pragma unroll
      for (int i = 0; i < 4; ++i)
        Y[(size_t)(row0 + i) * DD + col] = acc[m][n][i] + bvx;
    }
  }
}

// --------------------------------------------------------------------------
// Row-wise: t = tanh(Y[row] (+ Y2[row])); LN(t)*g+b -> optional bf16 / fp32.
// --------------------------------------------------------------------------
__global__ __launch_bounds__(256) void k_ep_ln(const float* __restrict__ Y,
                                               const float* __restrict__ Y2,
                                               const float* __restrict__ gw,
                                               const float* __restrict__ bw,
                                               unsigned short* __restrict__ obf,
                                               float* __restrict__ of32) {
  const int row = blockIdx.x, t = threadIdx.x;
  const size_t base = (size_t)row * DD + t * 8;
  f32x4 v0 = ((const f32x4*)(Y + base))[0];
  f32x4 v1 = ((const f32x4*)(Y + base))[1];
  if (Y2 != nullptr) {
    v0 += ((const f32x4*)(Y2 + base))[0];
    v1 += ((const f32x4*)(Y2 + base))[1];
  }
  float tv[8];
#pragma unroll
  for (int j = 0; j < 4; ++j) {
    tv[j] = tanhf(v0[j]);
    tv[4 + j] = tanhf(v1[j]);
  }
  float s1 = 0.f, s2 = 0.f;
#pragma unroll
  for (int j = 0; j < 8; ++j) {
    s1 += tv[j];
    s2 += tv[j] * tv[j];
  }
#pragma unroll
  for (int m = 1; m < 64; m <<= 1) {
    s1 += __shfl_xor(s1, m, 64);
    s2 += __shfl_xor(s2, m, 64);
  }
  __shared__ float r1[4], r2[4];
  const int wave = t >> 6;
  if ((t & 63) == 0) {
    r1[wave] = s1;
    r2[wave] = s2;
  }
  __syncthreads();
  const float S1 = r1[0] + r1[1] + r1[2] + r1[3];
  const float S2 = r2[0] + r2[1] + r2[2] + r2[3];
  const float mean = S1 * (1.0f / DD);
  const float var = S2 * (1.0f / DD) - mean * mean;
  const float rstd = rsqrtf(var + 1e-5f);
  f32x4 g0 = ((const f32x4*)(gw + t * 8))[0], g1 = ((const f32x4*)(gw + t * 8))[1];
  f32x4 bb0 = ((const f32x4*)(bw + t * 8))[0], bb1 = ((const f32x4*)(bw + t * 8))[1];
  float o[8];
#pragma unroll
  for (int j = 0; j < 4; ++j) {
    o[j] = (tv[j] - mean) * rstd * g0[j] + bb0[j];
    o[4 + j] = (tv[4 + j] - mean) * rstd * g1[j] + bb1[j];
  }
  if (obf != nullptr) {
    u32x4 p = {pk2(o[0], o[1]), pk2(o[2], o[3]), pk2(o[4], o[5]), pk2(o[6], o[7])};
    *((u32x4*)(obf + base)) = p;
  }
  if (of32 != nullptr) {
    f32x4 w0 = {o[0], o[1], o[2], o[3]}, w1 = {o[4], o[5], o[6], o[7]};
    ((f32x4*)(of32 + base))[0] = w0;
    ((f32x4*)(of32 + base))[1] = w1;
  }
}

// --------------------------------------------------------------------------
// oe[b][n][d] bf16 -> oeT[b][d][n] bf16, 64x64 tiles. grid (36, 32, 8).
// --------------------------------------------------------------------------
__global__ __launch_bounds__(256) void k_troe(const unsigned short* __restrict__ oe,
                                              unsigned short* __restrict__ oeT) {
  __shared__ unsigned short sh[64][65];
  const int t = threadIdx.x;
  const int b = blockIdx.z, nt = blockIdx.x, dt = blockIdx.y;
  {
    const int nn = t >> 2, seg = t & 3;
    const unsigned short* src = oe + ((size_t)b * NOBJ + nt * 64 + nn) * DD + dt * 64 + seg * 16;
    u32x4 x0 = ((const u32x4*)src)[0];
    u32x4 x1 = ((const u32x4*)src)[1];
    const unsigned short* px0 = (const unsigned short*)&x0;
    const unsigned short* px1 = (const unsigned short*)&x1;
#pragma unroll
    for (int j = 0; j < 8; ++j) {
      sh[nn][seg * 16 + j] = px0[j];
      sh[nn][seg * 16 + 8 + j] = px1[j];
    }
  }
  __syncthreads();
  {
    const int dd = t >> 2, ns = t & 3;
    unsigned int o[8];
#pragma unroll
    for (int j = 0; j < 8; ++j)
      o[j] = (unsigned int)sh[ns * 16 + 2 * j][dd] |
             ((unsigned int)sh[ns * 16 + 2 * j + 1][dd] << 16);
    u32x4 p0 = {o[0], o[1], o[2], o[3]};
    u32x4 p1 = {o[4], o[5], o[6], o[7]};
    unsigned short* dst = oeT + ((size_t)b * DD + dt * 64 + dd) * NOBJ + nt * 64 + ns * 16;
    ((u32x4*)dst)[0] = p0;
    ((u32x4*)dst)[1] = p1;
  }
}

// --------------------------------------------------------------------------
// adjT[b][f][n] = (oe[b][n][:] . ve[b][f][:]) / sqrt(2048).
// --------------------------------------------------------------------------
__global__ __launch_bounds__(256) void k_gemm_adj(const unsigned short* __restrict__ oe,
                                                  const unsigned short* __restrict__ veb,
                                                  float* __restrict__ adjT) {
  __shared__ __align__(16) unsigned short As[128 * 32];
  __shared__ __align__(16) unsigned short Bs[64 * 32];
  const int t = threadIdx.x;
  const int lane = t & 63, wave = t >> 6;
  const int r = lane & 15, g = lane >> 4;
  const int wm = wave >> 1, wn = wave & 1;
  const int b = blockIdx.y, bm = blockIdx.x * 128;
  const int arow = t >> 1, ah = t & 1;
  const int br_ = t >> 2, bseg = t & 3;
  f32x4 acc[4][2] = {};
  const unsigned short* aptr = oe + ((size_t)b * NOBJ + bm + arow) * DD + ah * 16;
  const unsigned short* bptr = veb + ((size_t)b * FF + br_) * DD + bseg * 8;
  for (int kt = 0; kt < DD / 32; ++kt) {
    const int kb = kt * 32;
    u32x4 a0 = ((const u32x4*)(aptr + kb))[0];
    u32x4 a1 = ((const u32x4*)(aptr + kb))[1];
    u32x4 bvx = *(const u32x4*)(bptr + kb);
    __syncthreads();
    ((u32x4*)As)[arow * 4 + ah * 2 + 0] = a0;
    ((u32x4*)As)[arow * 4 + ah * 2 + 1] = a1;
    ((u32x4*)Bs)[br_ * 4 + bseg] = bvx;
    __syncthreads();
    bf16x8 af[4], bfr[2];
#pragma unroll
    for (int m = 0; m < 4; ++m) af[m] = ((const bf16x8*)As)[(wm * 64 + m * 16 + r) * 4 + g];
#pragma unroll
    for (int n = 0; n < 2; ++n) bfr[n] = ((const bf16x8*)Bs)[(wn * 32 + n * 16 + r) * 4 + g];
#pragma unroll
    for (int m = 0; m < 4; ++m)
#pragma unroll
      for (int n = 0; n < 2; ++n)
        acc[m][n] = __builtin_amdgcn_mfma_f32_16x16x32_bf16(af[m], bfr[n], acc[m][n], 0, 0, 0);
  }
  const float scale = 0.02209708691207961f;  // 1/sqrt(2048)
#pragma unroll
  for (int m = 0; m < 4; ++m)
#pragma unroll
    for (int n = 0; n < 2; ++n) {
      const int f = wn * 32 + n * 16 + r;
      const int n0 = bm + wm * 64 + m * 16 + g * 4;
      f32x4 v = acc[m][n];
      v *= scale;
      *(f32x4*)(adjT + ((size_t)b * FF + f) * NOBJ + n0) = v;
    }
}

// --------------------------------------------------------------------------
// Row softmax over 2304 (rows of adjT), write bf16. grid = 512 rows.
// --------------------------------------------------------------------------
__global__ __launch_bounds__(256) void k_smax(const float* __restrict__ adjT,
                                              unsigned short* __restrict__ out) {
  const int t = threadIdx.x;
  const size_t base = (size_t)blockIdx.x * NOBJ;
  float v[9];
#pragma unroll
  for (int j = 0; j < 9; ++j) v[j] = adjT[base + t + j * 256];
  float m = v[0];
#pragma unroll
  for (int j = 1; j < 9; ++j) m = fmaxf(m, v[j]);
#pragma unroll
  for (int s = 1; s < 64; s <<= 1) m = fmaxf(m, __shfl_xor(m, s, 64));
  __shared__ float rm[4], rs[4];
  const int wave = t >> 6;
  if ((t & 63) == 0) rm[wave] = m;
  __syncthreads();
  m = fmaxf(fmaxf(rm[0], rm[1]), fmaxf(rm[2], rm[3]));
  float e[9];
  float s = 0.f;
#pragma unroll
  for (int j = 0; j < 9; ++j) {
    e[j] = __expf(v[j] - m);
    s += e[j];
  }
#pragma unroll
  for (int q = 1; q < 64; q <<= 1) s += __shfl_xor(s, q, 64);
  if ((t & 63) == 0) rs[wave] = s;
  __syncthreads();
  const float S = rs[0] + rs[1] + rs[2] + rs[3];
  const float inv = 1.0f / S;
#pragma unroll
  for (int j = 0; j < 9; ++j) out[base + t + j * 256] = f2bf(e[j] * inv);
}

// --------------------------------------------------------------------------
// agg[b][f][d] = sum_n adj_sm[b][f][n] * oeT[b][d][n].
// --------------------------------------------------------------------------
__global__ __launch_bounds__(256) void k_gemm_agg(const unsigned short* __restrict__ adjsm,
                                                  const unsigned short* __restrict__ oeT,
                                                  float* __restrict__ agg) {
  __shared__ __align__(16) unsigned short As[64 * 32];
  __shared__ __align__(16) unsigned short Bs[128 * 32];
  const int t = threadIdx.x;
  const int lane = t & 63, wave = t >> 6;
  const int r = lane & 15, g = lane >> 4;
  const int wm = wave >> 1, wn = wave & 1;
  const int b = blockIdx.y, bn = blockIdx.x * 128;
  const int ar = t >> 2, aseg = t & 3;
  const int brow = t >> 1, bh = t & 1;
  f32x4 acc[2][4] = {};
  const unsigned short* aptr = adjsm + ((size_t)b * FF + ar) * NOBJ + aseg * 8;
  const unsigned short* bptr = oeT + ((size_t)b * DD + bn + brow) * NOBJ + bh * 16;
  for (int kt = 0; kt < NOBJ / 32; ++kt) {
    const int kb = kt * 32;
    u32x4 av = *(const u32x4*)(aptr + kb);
    u32x4 b0 = ((const u32x4*)(bptr + kb))[0];
    u32x4 b1 = ((const u32x4*)(bptr + kb))[1];
    __syncthreads();
    ((u32x4*)As)[ar * 4 + aseg] = av;
    ((u32x4*)Bs)[brow * 4 + bh * 2 + 0] = b0;
    ((u32x4*)Bs)[brow * 4 + bh * 2 + 1] = b1;
    __syncthreads();
    bf16x8 af[2], bfr[4];
#pragma unroll
    for (int m = 0; m < 2; ++m) af[m] = ((const bf16x8*)As)[(wm * 32 + m * 16 + r) * 4 + g];
#pragma unroll
    for (int n = 0; n < 4; ++n) bfr[n] = ((const bf16x8*)Bs)[(wn * 64 + n * 16 + r) * 4 + g];
#pragma unroll
    for (int m = 0; m < 2; ++m)
#pragma unroll
      for (int n = 0; n < 4; ++n)
        acc[m][n] = __builtin_amdgcn_mfma_f32_16x16x32_bf16(af[m], bfr[n], acc[m][n], 0, 0, 0);
  }
#pragma unroll
  for (int m = 0; m < 2; ++m)
#pragma unroll
    for (int n = 0; n < 4; ++n) {
      const int d = bn + wn * 64 + n * 16 + r;
#pragma unroll
      for (int i = 0; i < 4; ++i) {
        const int f = wm * 32 + m * 16 + g * 4 + i;
        agg[((size_t)b * FF + f) * DD + d] = acc[m][n][i];
      }
    }
}

// --------------------------------------------------------------------------

extern "C" void kernel_launch(void* const* d_in, const int* in_sizes, int n_in,
                              void* d_out, int out_size, void* d_ws, size_t ws_size,
                              hipStream_t stream) {
  (void)in_sizes; (void)n_in; (void)out_size;
  const float* visual = (const float*)d_in[0];
  const float* obj    = (const float*)d_in[1];
  const float* W_v    = (const float*)d_in[2];
  const float* b_v    = (const float*)d_in[3];
  const float* W_o    = (const float*)d_in[4];
  const float* b_o    = (const float*)d_in[5];
  const float* ln_v_g = (const float*)d_in[6];
  const float* ln_v_b = (const float*)d_in[7];
  const float* ln_o_g = (const float*)d_in[8];
  const float* ln_o_b = (const float*)d_in[9];
  const float* ln_ov_g = (const float*)d_in[10];
  const float* ln_ov_b = (const float*)d_in[11];

  // Workspace layout (aliased; ~253 MiB, same as prior rounds):
  //   [0,8M)      WvT
  //   [8M,16M)    WoT
  //   [16M,88M)   objb (bf16) -> later oe_b (objb dead after obj GEMM)
  //   [88M,160M)  T (bf16 tanh) -> later oeT (T dead after ep_ln2)
  //   [160M,165M) part (LN partials, 4.6 MiB)
  //   [232M,..)   Yv, ve_f, ve_b, adjT, adjs, agg
  char* ws = (char*)d_ws;
  constexpr size_t OFF_WVT = 0;
  constexpr size_t OFF_WOT = 8ull << 20;
  constexpr size_t OFF_OBJB = 16ull << 20;
  constexpr size_t OFF_T   = 88ull << 20;
  constexpr size_t OFF_PART = 160ull << 20;
  constexpr size_t OFF_YV  = 232ull << 20;
  constexpr size_t OFF_VEF = 236ull << 20;
  constexpr size_t OFF_VEB = 240ull << 20;
  constexpr size_t OFF_ADJ = 242ull << 20;
  constexpr size_t OFF_ADJS = OFF_ADJ + 4718592ull;
  constexpr size_t OFF_AGG = OFF_ADJS + 2359296ull;
  constexpr size_t WS_NEED = OFF_AGG + 4194304ull;
  if (ws_size < WS_NEED) return;

  unsigned short* WvT  = (unsigned short*)(ws + OFF_WVT);
  unsigned short* WoT  = (unsigned short*)(ws + OFF_WOT);
  unsigned short* objb = (unsigned short*)(ws + OFF_OBJB);
  unsigned short* oe_b = (unsigned short*)(ws + OFF_OBJB);  // alias (objb dead)
  unsigned short* T    = (unsigned short*)(ws + OFF_T);
  unsigned short* oeT  = (unsigned short*)(ws + OFF_T);     // alias (T dead)
  float* part          = (float*)(ws + OFF_PART);
  float* Yv            = (float*)(ws + OFF_YV);
  float* ve_f          = (float*)(ws + OFF_VEF);
  unsigned short* ve_b = (unsigned short*)(ws + OFF_VEB);
  float* adjT          = (float*)(ws + OFF_ADJ);
  unsigned short* adjs = (unsigned short*)(ws + OFF_ADJS);
  float* agg           = (float*)(ws + OFF_AGG);

  dim3 b256(256);
  // 1) weight transpose+convert, obj fp32->bf16
  k_wprep<<<dim3(32, 32), b256, 0, stream>>>(W_v, WvT);
  k_wprep<<<dim3(32, 32), b256, 0, stream>>>(W_o, WoT);
  k_cvt_bf16<<<dim3(2048), b256, 0, stream>>>(obj, objb, MO * DD / 16);
  // 2) branch GEMMs (obj GEMM fused with tanh + LN partials)
  k_gemm_xw<<<dim3(16, MV / 128), b256, 0, stream>>>(visual, WvT, b_v, Yv);
  k_gemm_bbf<<<dim3(8, MO / 256), dim3(512), 0, stream>>>(objb, WoT, b_o, T, part);
  // 3) LN epilogues
  k_ep_ln<<<dim3(MV), b256, 0, stream>>>(Yv, nullptr, ln_v_g, ln_v_b, ve_b, ve_f);
  k_ep_ln2<<<dim3(MO), b256, 0, stream>>>(T, part, ln_o_g, ln_o_b, oe_b);
  // 4) oe transpose (oeT aliases T)
  k_troe<<<dim3(36, 32, 8), b256, 0, stream>>>(oe_b, oeT);
  // 5) adjacency + softmax
  k_gemm_adj<<<dim3(NOBJ / 128, BS), b256, 0, stream>>>(oe_b, ve_b, adjT);
  k_smax<<<dim3(MV), b256, 0, stream>>>(adjT, adjs);
  // 6) aggregation
  k_gemm_agg<<<dim3(DD / 128, BS), b256, 0, stream>>>(adjs, oeT, agg);
  // 7) final add + tanh + LN -> d_out (fp32)
  k_ep_ln<<<dim3(MV), b256, 0, stream>>>(agg, ve_f, ln_ov_g, ln_ov_b, nullptr, (float*)d_out);
}

// Round 5
// 538.184 us; speedup vs baseline: 1.0962x; 1.0962x over previous
//
#include <hip/hip_runtime.h>
#include <cstdint>
#include <cstddef>

// ---------------------------------------------------------------------------
// EnhancedObj: visual/object attention block, bf16-MFMA implementation.
// Shapes (hardcoded): bs=8, F=64, obj=36, d=2048.
//   MO = 18432 object rows, MV = 512 visual rows, NOBJ = 2304.
// Round 5: obj GEMM -> 256x256, BK=64, 8 waves (2Mx4N, wave tile 128x64),
// 4 phases/K-step (16 MFMA quadrants), 2x64KB LDS buffers, row-major
// XOR-swizzled LDS (coalesced global_load_lds source + conflict-free
// ds_read_b128 -- both HW-verified in round 3), stage-all at phase 0,
// vmcnt(0) drain at phase 3 (loads span 3 phases/barriers), setprio around
// MFMA clusters, per-phase double barriers for cross-wave ds_read/MFMA
// overlap. Fused epilogue: tanh -> bf16 T + per-row LN partials (round 4,
// verified). k_ep_ln2 finishes LN.
// ---------------------------------------------------------------------------

typedef __attribute__((ext_vector_type(4))) float f32x4;
typedef __attribute__((ext_vector_type(4))) unsigned int u32x4;
typedef __attribute__((ext_vector_type(8))) short bf16x8;

#define DD 2048
#define BS 8
#define FF 64
#define NOBJ 2304
#define MO 18432
#define MV 512

__device__ __forceinline__ unsigned short f2bf(float f) {
  unsigned int u = __float_as_uint(f);
  u += 0x7fffu + ((u >> 16) & 1u);          // RTNE (inputs finite)
  return (unsigned short)(u >> 16);
}
__device__ __forceinline__ unsigned int pk2(float a, float b) {
  return (unsigned int)f2bf(a) | ((unsigned int)f2bf(b) << 16);
}
__device__ __forceinline__ float bf2f(unsigned short u) {
  return __uint_as_float((unsigned int)u << 16);
}

typedef __attribute__((address_space(1))) const unsigned int gas_u32;
typedef __attribute__((address_space(3))) unsigned int las_u32;
__device__ __forceinline__ void gl_lds16(const void* g, void* l) {
  __builtin_amdgcn_global_load_lds((gas_u32*)g, (las_u32*)l, 16, 0, 0);
}

// --------------------------------------------------------------------------
// fp32 -> bf16 bulk convert. Each thread: 16 elements per iter.
// --------------------------------------------------------------------------
__global__ __launch_bounds__(256) void k_cvt_bf16(const float* __restrict__ X,
                                                  unsigned short* __restrict__ O,
                                                  int n16) {
  int idx = blockIdx.x * 256 + threadIdx.x;
  const int stride = gridDim.x * 256;
  for (int i = idx; i < n16; i += stride) {
    const f32x4* src = (const f32x4*)(X + (size_t)i * 16);
    f32x4 a = src[0], b = src[1], c = src[2], d = src[3];
    u32x4 p = {pk2(a.x, a.y), pk2(a.z, a.w), pk2(b.x, b.y), pk2(b.z, b.w)};
    u32x4 q = {pk2(c.x, c.y), pk2(c.z, c.w), pk2(d.x, d.y), pk2(d.z, d.w)};
    u32x4* dst = (u32x4*)(O + (size_t)i * 16);
    dst[0] = p;
    dst[1] = q;
  }
}

// --------------------------------------------------------------------------
// W[k][n] fp32 (2048x2048) -> Wt[n][k] bf16. 64x64 tiles via LDS.
// --------------------------------------------------------------------------
__global__ __launch_bounds__(256) void k_wprep(const float* __restrict__ W,
                                               unsigned short* __restrict__ Wt) {
  __shared__ unsigned short sh[64][65];
  const int t = threadIdx.x;
  const int kb = blockIdx.x * 64, nb = blockIdx.y * 64;
  {
    const int rk = t >> 2, seg = t & 3;
    const float* src = W + (size_t)(kb + rk) * DD + nb + seg * 16;
#pragma unroll
    for (int q = 0; q < 4; ++q) {
      f32x4 x = *(const f32x4*)(src + q * 4);
      sh[rk][seg * 16 + q * 4 + 0] = f2bf(x.x);
      sh[rk][seg * 16 + q * 4 + 1] = f2bf(x.y);
      sh[rk][seg * 16 + q * 4 + 2] = f2bf(x.z);
      sh[rk][seg * 16 + q * 4 + 3] = f2bf(x.w);
    }
  }
  __syncthreads();
  {
    const int nn = t >> 2, ks = t & 3;
    unsigned int o[8];
#pragma unroll
    for (int j = 0; j < 8; ++j)
      o[j] = (unsigned int)sh[ks * 16 + 2 * j][nn] |
             ((unsigned int)sh[ks * 16 + 2 * j + 1][nn] << 16);
    u32x4 p0 = {o[0], o[1], o[2], o[3]};
    u32x4 p1 = {o[4], o[5], o[6], o[7]};
    unsigned short* dst = Wt + (size_t)(nb + nn) * DD + kb + ks * 16;
    ((u32x4*)dst)[0] = p0;
    ((u32x4*)dst)[1] = p1;
  }
}

// --------------------------------------------------------------------------
// Obj GEMM fused: T[MO][2048] = bf16(tanh(A@Bt^T + bias)), plus per-row
// partial LN sums part[row][32][2] = {sum t, sum t^2} over 64-col groups.
// Geometry: BM=BN=256, BK=64, 512 thr = 8 waves (wm 0..1, wn 0..3),
// wave tile 128x64. LDS: 2 buffers x (A 256x64 + B 256x64) bf16 = 128 KiB.
// LDS layout (per tile): row-major, row r holds 8 16B-chunks; chunk at
// physical slot s holds logical k16 = s ^ (r&7). Staging source is
// 128B-coalesced per 8 lanes; ds_read_b128 is 2-way-conflict max (free).
// Per K-step kt: 4 phases (C-quadrants qa,qb). Phase = {12 ds_read frags;
// [phase0: stage tile kt+1, 8 gl_lds16]; s_barrier; setprio1; 16 MFMA;
// setprio0; [phase3: vmcnt(0) -- loads issued 3 phases ago]; s_barrier}.
// grid = (8, 72); XCD-bijective swizzle (576 wgs, 72/XCD).
// --------------------------------------------------------------------------
__global__ __launch_bounds__(512, 1) void k_gemm_bbf(const unsigned short* __restrict__ A,
                                                     const unsigned short* __restrict__ Bt,
                                                     const float* __restrict__ bias,
                                                     unsigned short* __restrict__ T,
                                                     float* __restrict__ part) {
  __shared__ __align__(16) unsigned short lds[2 * 32768];  // 128 KiB
  const int tid = threadIdx.x;
  const int lane = tid & 63, wave = tid >> 6;
  const int r = lane & 15, g = lane >> 4;
  const int wm = wave >> 2, wn = wave & 3;

  // XCD-aware bijective remap (nwg = 576, %8 == 0, per = 72)
  const int orig = blockIdx.y * 8 + blockIdx.x;
  const int lin = (orig & 7) * 72 + (orig >> 3);
  const int bm = (lin >> 3) * 256;
  const int bn = (lin & 7) * 256;

  // staging: issue i covers chunk c = i*512 + tid of the 2048-chunk tile.
  // chunk c: row = c>>3 (i*64 + tid>>3), physslot = c&7 = tid&7,
  // logical k16 = physslot ^ (row&7) = (tid&7) ^ ((tid>>3)&7).
  const int srow = tid >> 3;                 // 0..63 within each 64-row group
  const int k16s = (tid & 7) ^ (srow & 7);
  const unsigned short* aS = A + (size_t)(bm + srow) * DD + k16s * 8;
  const unsigned short* bS = Bt + (size_t)(bn + srow) * DD + k16s * 8;

  auto stage = [&](int buf, int kt) {
    unsigned short* ab = lds + buf * 32768;
    unsigned short* bb = ab + 16384;
    const size_t ko = (size_t)kt * 64;
#pragma unroll
    for (int i = 0; i < 4; ++i)
      gl_lds16(aS + ko + (size_t)(i * 64) * DD, ab + ((i * 512 + tid) << 3));
#pragma unroll
    for (int i = 0; i < 4; ++i)
      gl_lds16(bS + ko + (size_t)(i * 64) * DD, bb + ((i * 512 + tid) << 3));
  };

  // frag-read offsets (shorts): row*64 + slot*8, slot = (kk*4+g) ^ (r&7)
  const int rs = r & 7;
  const int s0 = ((0 + g) ^ rs) * 8;
  const int s1 = ((4 + g) ^ rs) * 8;
  const int abase = (wm * 128 + r) * 64;
  const int bbase = 16384 + (wn * 64 + r) * 64;

  f32x4 acc[8][4] = {};

  stage(0, 0);
  asm volatile("s_waitcnt vmcnt(0)" ::: "memory");
  __builtin_amdgcn_s_barrier();

  for (int kt = 0; kt < DD / 64; ++kt) {
    const unsigned short* bufp = lds + (kt & 1) * 32768;
    const bool st = (kt + 1 < DD / 64);

#define PHASE(QA, QB, DOSTAGE, DOWAIT)                                         \
    {                                                                          \
      bf16x8 af[4][2], bfv[2][2];                                              \
      _Pragma("unroll")                                                        \
      for (int mi = 0; mi < 4; ++mi) {                                         \
        const int ro = abase + ((QA) * 64 + mi * 16) * 64;                     \
        af[mi][0] = *(const bf16x8*)(bufp + ro + s0);                          \
        af[mi][1] = *(const bf16x8*)(bufp + ro + s1);                          \
      }                                                                        \
      _Pragma("unroll")                                                        \
      for (int ni = 0; ni < 2; ++ni) {                                         \
        const int ro = bbase + ((QB) * 32 + ni * 16) * 64;                     \
        bfv[ni][0] = *(const bf16x8*)(bufp + ro + s0);                         \
        bfv[ni][1] = *(const bf16x8*)(bufp + ro + s1);                         \
      }                                                                        \
      if (DOSTAGE) stage((kt + 1) & 1, kt + 1);                                \
      __builtin_amdgcn_s_barrier();                                            \
      __builtin_amdgcn_s_setprio(1);                                           \
      _Pragma("unroll")                                                        \
      for (int mi = 0; mi < 4; ++mi)                                           \
        _Pragma("unroll")                                                      \
        for (int ni = 0; ni < 2; ++ni) {                                       \
          acc[(QA) * 4 + mi][(QB) * 2 + ni] = __builtin_amdgcn_mfma_f32_16x16x32_bf16( \
              af[mi][0], bfv[ni][0], acc[(QA) * 4 + mi][(QB) * 2 + ni], 0, 0, 0);      \
          acc[(QA) * 4 + mi][(QB) * 2 + ni] = __builtin_amdgcn_mfma_f32_16x16x32_bf16( \
              af[mi][1], bfv[ni][1], acc[(QA) * 4 + mi][(QB) * 2 + ni], 0, 0, 0);      \
        }                                                                      \
      __builtin_amdgcn_s_setprio(0);                                           \
      if (DOWAIT) asm volatile("s_waitcnt vmcnt(0)" ::: "memory");             \
      __builtin_amdgcn_s_barrier();                                            \
    }

    PHASE(0, 0, st, false)
    PHASE(0, 1, false, false)
    PHASE(1, 0, false, false)
    PHASE(1, 1, false, st)
#undef PHASE
  }

  // ---- fused epilogue: bias + tanh -> bf16 T, per-row partial LN sums ----
  float bv[4];
#pragma unroll
  for (int ni = 0; ni < 4; ++ni) bv[ni] = bias[bn + wn * 64 + ni * 16 + r];
  const int slot = ((lin & 7) << 2) + wn;  // 32 col-groups of 64
#pragma unroll
  for (int mi = 0; mi < 8; ++mi) {
#pragma unroll
    for (int i2 = 0; i2 < 4; ++i2) {
      const int row = bm + wm * 128 + mi * 16 + g * 4 + i2;
      unsigned short* trow = T + (size_t)row * DD + bn + wn * 64 + r;
      float s1 = 0.f, s2 = 0.f;
#pragma unroll
      for (int ni = 0; ni < 4; ++ni) {
        const float tv = tanhf(acc[mi][ni][i2] + bv[ni]);
        trow[ni * 16] = f2bf(tv);
        s1 += tv;
        s2 += tv * tv;
      }
#pragma unroll
      for (int m = 1; m < 16; m <<= 1) {
        s1 += __shfl_xor(s1, m, 64);
        s2 += __shfl_xor(s2, m, 64);
      }
      if (r == 0) {
        float2 p2 = make_float2(s1, s2);
        *(float2*)(part + (size_t)row * 64 + slot * 2) = p2;
      }
    }
  }
}

// --------------------------------------------------------------------------
// Finish obj LN: read T (bf16 tanh), partials; out oe_b = bf16(LN(t)*g+b).
// One block (256 thr) per row.
// --------------------------------------------------------------------------
__global__ __launch_bounds__(256) void k_ep_ln2(const unsigned short* __restrict__ T,
                                                const float* __restrict__ part,
                                                const float* __restrict__ gw,
                                                const float* __restrict__ bw,
                                                unsigned short* __restrict__ obf) {
  const int row = blockIdx.x, t = threadIdx.x;
  float s1 = 0.f, s2 = 0.f;
  if (t < 32) {
    float2 p = ((const float2*)(part + (size_t)row * 64))[t];
    s1 = p.x;
    s2 = p.y;
  }
#pragma unroll
  for (int m = 1; m < 64; m <<= 1) {
    s1 += __shfl_xor(s1, m, 64);
    s2 += __shfl_xor(s2, m, 64);
  }
  __shared__ float sh[2];
  if (t == 0) {
    sh[0] = s1;
    sh[1] = s2;
  }
  __syncthreads();
  const float mean = sh[0] * (1.0f / DD);
  const float var = sh[1] * (1.0f / DD) - mean * mean;
  const float rstd = rsqrtf(var + 1e-5f);
  const size_t base = (size_t)row * DD + t * 8;
  u32x4 tin = *(const u32x4*)(T + base);
  f32x4 g0 = ((const f32x4*)(gw + t * 8))[0], g1 = ((const f32x4*)(gw + t * 8))[1];
  f32x4 bb0 = ((const f32x4*)(bw + t * 8))[0], bb1 = ((const f32x4*)(bw + t * 8))[1];
  float gv[8], bvv[8];
  gv[0] = g0.x; gv[1] = g0.y; gv[2] = g0.z; gv[3] = g0.w;
  gv[4] = g1.x; gv[5] = g1.y; gv[6] = g1.z; gv[7] = g1.w;
  bvv[0] = bb0.x; bvv[1] = bb0.y; bvv[2] = bb0.z; bvv[3] = bb0.w;
  bvv[4] = bb1.x; bvv[5] = bb1.y; bvv[6] = bb1.z; bvv[7] = bb1.w;
  float o[8];
#pragma unroll
  for (int j = 0; j < 4; ++j) {
    const float tl = bf2f((unsigned short)(tin[j] & 0xffffu));
    const float th = bf2f((unsigned short)(tin[j] >> 16));
    o[2 * j] = (tl - mean) * rstd * gv[2 * j] + bvv[2 * j];
    o[2 * j + 1] = (th - mean) * rstd * gv[2 * j + 1] + bvv[2 * j + 1];
  }
  u32x4 p = {pk2(o[0], o[1]), pk2(o[2], o[3]), pk2(o[4], o[5]), pk2(o[6], o[7])};
  *((u32x4*)(obf + base)) = p;
}

// --------------------------------------------------------------------------
// Y[M][2048] = X[M][2048](fp32) @ W + bias (inline convert). Visual branch.
// --------------------------------------------------------------------------
__global__ __launch_bounds__(256) void k_gemm_xw(const float* __restrict__ X,
                                                 const unsigned short* __restrict__ Wt,
                                                 const float* __restrict__ bias,
                                                 float* __restrict__ Y) {
  __shared__ __align__(16) unsigned short As[128 * 32];
  __shared__ __align__(16) unsigned short Bs[128 * 32];
  const int t = threadIdx.x;
  const int lane = t & 63, wave = t >> 6;
  const int r = lane & 15, g = lane >> 4;
  const int wm = wave >> 1, wn = wave & 1;
  const int bm = blockIdx.y * 128, bn = blockIdx.x * 128;
  const int arow = t >> 1, ah = t & 1;
  f32x4 acc[4][4] = {};
  const float* aptr = X + (size_t)(bm + arow) * DD + ah * 16;
  const unsigned short* bptr = Wt + (size_t)(bn + arow) * DD + ah * 16;
  for (int kt = 0; kt < DD / 32; ++kt) {
    const int kb = kt * 32;
    f32x4 a0 = *(const f32x4*)(aptr + kb);
    f32x4 a1 = *(const f32x4*)(aptr + kb + 4);
    f32x4 a2 = *(const f32x4*)(aptr + kb + 8);
    f32x4 a3 = *(const f32x4*)(aptr + kb + 12);
    u32x4 b0 = *(const u32x4*)(bptr + kb);
    u32x4 b1 = *(const u32x4*)(bptr + kb + 8);
    __syncthreads();
    u32x4 p0 = {pk2(a0.x, a0.y), pk2(a0.z, a0.w), pk2(a1.x, a1.y), pk2(a1.z, a1.w)};
    u32x4 p1 = {pk2(a2.x, a2.y), pk2(a2.z, a2.w), pk2(a3.x, a3.y), pk2(a3.z, a3.w)};
    ((u32x4*)As)[arow * 4 + ah * 2 + 0] = p0;
    ((u32x4*)As)[arow * 4 + ah * 2 + 1] = p1;
    ((u32x4*)Bs)[arow * 4 + ah * 2 + 0] = b0;
    ((u32x4*)Bs)[arow * 4 + ah * 2 + 1] = b1;
    __syncthreads();
    bf16x8 af[4], bfr[4];
#pragma unroll
    for (int m = 0; m < 4; ++m) af[m] = ((const bf16x8*)As)[(wm * 64 + m * 16 + r) * 4 + g];
#pragma unroll
    for (int n = 0; n < 4; ++n) bfr[n] = ((const bf16x8*)Bs)[(wn * 64 + n * 16 + r) * 4 + g];
#pragma unroll
    for (int m = 0; m < 4; ++m)
#pragma unroll
      for (int n = 0; n < 4; ++n)
        acc[m][n] = __builtin_amdgcn_mfma_f32_16x16x32_bf16(af[m], bfr[n], acc[m][n], 0, 0, 0);
  }
#pragma unroll
  for (int m = 0; m < 4; ++m) {
    const int row0 = bm + wm * 64 + m * 16 + g * 4;
#pragma unroll
    for (int n = 0; n < 4; ++n) {
      const int col = bn + wn * 64 + n * 16 + r;
      const float bvx = bias[col];
#pragma unroll
      for (int i = 0; i < 4; ++i)
        Y[(size_t)(row0 + i) * DD + col] = acc[m][n][i] + bvx;
    }
  }
}

// --------------------------------------------------------------------------
// Row-wise: t = tanh(Y[row] (+ Y2[row])); LN(t)*g+b -> optional bf16 / fp32.
// --------------------------------------------------------------------------
__global__ __launch_bounds__(256) void k_ep_ln(const float* __restrict__ Y,
                                               const float* __restrict__ Y2,
                                               const float* __restrict__ gw,
                                               const float* __restrict__ bw,
                                               unsigned short* __restrict__ obf,
                                               float* __restrict__ of32) {
  const int row = blockIdx.x, t = threadIdx.x;
  const size_t base = (size_t)row * DD + t * 8;
  f32x4 v0 = ((const f32x4*)(Y + base))[0];
  f32x4 v1 = ((const f32x4*)(Y + base))[1];
  if (Y2 != nullptr) {
    v0 += ((const f32x4*)(Y2 + base))[0];
    v1 += ((const f32x4*)(Y2 + base))[1];
  }
  float tv[8];
#pragma unroll
  for (int j = 0; j < 4; ++j) {
    tv[j] = tanhf(v0[j]);
    tv[4 + j] = tanhf(v1[j]);
  }
  float s1 = 0.f, s2 = 0.f;
#pragma unroll
  for (int j = 0; j < 8; ++j) {
    s1 += tv[j];
    s2 += tv[j] * tv[j];
  }
#pragma unroll
  for (int m = 1; m < 64; m <<= 1) {
    s1 += __shfl_xor(s1, m, 64);
    s2 += __shfl_xor(s2, m, 64);
  }
  __shared__ float r1[4], r2[4];
  const int wave = t >> 6;
  if ((t & 63) == 0) {
    r1[wave] = s1;
    r2[wave] = s2;
  }
  __syncthreads();
  const float S1 = r1[0] + r1[1] + r1[2] + r1[3];
  const float S2 = r2[0] + r2[1] + r2[2] + r2[3];
  const float mean = S1 * (1.0f / DD);
  const float var = S2 * (1.0f / DD) - mean * mean;
  const float rstd = rsqrtf(var + 1e-5f);
  f32x4 g0 = ((const f32x4*)(gw + t * 8))[0], g1 = ((const f32x4*)(gw + t * 8))[1];
  f32x4 bb0 = ((const f32x4*)(bw + t * 8))[0], bb1 = ((const f32x4*)(bw + t * 8))[1];
  float o[8];
#pragma unroll
  for (int j = 0; j < 4; ++j) {
    o[j] = (tv[j] - mean) * rstd * g0[j] + bb0[j];
    o[4 + j] = (tv[4 + j] - mean) * rstd * g1[j] + bb1[j];
  }
  if (obf != nullptr) {
    u32x4 p = {pk2(o[0], o[1]), pk2(o[2], o[3]), pk2(o[4], o[5]), pk2(o[6], o[7])};
    *((u32x4*)(obf + base)) = p;
  }
  if (of32 != nullptr) {
    f32x4 w0 = {o[0], o[1], o[2], o[3]}, w1 = {o[4], o[5], o[6], o[7]};
    ((f32x4*)(of32 + base))[0] = w0;
    ((f32x4*)(of32 + base))[1] = w1;
  }
}

// --------------------------------------------------------------------------
// oe[b][n][d] bf16 -> oeT[b][d][n] bf16, 64x64 tiles. grid (36, 32, 8).
// --------------------------------------------------------------------------
__global__ __launch_bounds__(256) void k_troe(const unsigned short* __restrict__ oe,
                                              unsigned short* __restrict__ oeT) {
  __shared__ unsigned short sh[64][65];
  const int t = threadIdx.x;
  const int b = blockIdx.z, nt = blockIdx.x, dt = blockIdx.y;
  {
    const int nn = t >> 2, seg = t & 3;
    const unsigned short* src = oe + ((size_t)b * NOBJ + nt * 64 + nn) * DD + dt * 64 + seg * 16;
    u32x4 x0 = ((const u32x4*)src)[0];
    u32x4 x1 = ((const u32x4*)src)[1];
    const unsigned short* px0 = (const unsigned short*)&x0;
    const unsigned short* px1 = (const unsigned short*)&x1;
#pragma unroll
    for (int j = 0; j < 8; ++j) {
      sh[nn][seg * 16 + j] = px0[j];
      sh[nn][seg * 16 + 8 + j] = px1[j];
    }
  }
  __syncthreads();
  {
    const int dd = t >> 2, ns = t & 3;
    unsigned int o[8];
#pragma unroll
    for (int j = 0; j < 8; ++j)
      o[j] = (unsigned int)sh[ns * 16 + 2 * j][dd] |
             ((unsigned int)sh[ns * 16 + 2 * j + 1][dd] << 16);
    u32x4 p0 = {o[0], o[1], o[2], o[3]};
    u32x4 p1 = {o[4], o[5], o[6], o[7]};
    unsigned short* dst = oeT + ((size_t)b * DD + dt * 64 + dd) * NOBJ + nt * 64 + ns * 16;
    ((u32x4*)dst)[0] = p0;
    ((u32x4*)dst)[1] = p1;
  }
}

// --------------------------------------------------------------------------
// adjT[b][f][n] = (oe[b][n][:] . ve[b][f][:]) / sqrt(2048).
// --------------------------------------------------------------------------
__global__ __launch_bounds__(256) void k_gemm_adj(const unsigned short* __restrict__ oe,
                                                  const unsigned short* __restrict__ veb,
                                                  float* __restrict__ adjT) {
  __shared__ __align__(16) unsigned short As[128 * 32];
  __shared__ __align__(16) unsigned short Bs[64 * 32];
  const int t = threadIdx.x;
  const int lane = t & 63, wave = t >> 6;
  const int r = lane & 15, g = lane >> 4;
  const int wm = wave >> 1, wn = wave & 1;
  const int b = blockIdx.y, bm = blockIdx.x * 128;
  const int arow = t >> 1, ah = t & 1;
  const int br_ = t >> 2, bseg = t & 3;
  f32x4 acc[4][2] = {};
  const unsigned short* aptr = oe + ((size_t)b * NOBJ + bm + arow) * DD + ah * 16;
  const unsigned short* bptr = veb + ((size_t)b * FF + br_) * DD + bseg * 8;
  for (int kt = 0; kt < DD / 32; ++kt) {
    const int kb = kt * 32;
    u32x4 a0 = ((const u32x4*)(aptr + kb))[0];
    u32x4 a1 = ((const u32x4*)(aptr + kb))[1];
    u32x4 bvx = *(const u32x4*)(bptr + kb);
    __syncthreads();
    ((u32x4*)As)[arow * 4 + ah * 2 + 0] = a0;
    ((u32x4*)As)[arow * 4 + ah * 2 + 1] = a1;
    ((u32x4*)Bs)[br_ * 4 + bseg] = bvx;
    __syncthreads();
    bf16x8 af[4], bfr[2];
#pragma unroll
    for (int m = 0; m < 4; ++m) af[m] = ((const bf16x8*)As)[(wm * 64 + m * 16 + r) * 4 + g];
#pragma unroll
    for (int n = 0; n < 2; ++n) bfr[n] = ((const bf16x8*)Bs)[(wn * 32 + n * 16 + r) * 4 + g];
#pragma unroll
    for (int m = 0; m < 4; ++m)
#pragma unroll
      for (int n = 0; n < 2; ++n)
        acc[m][n] = __builtin_amdgcn_mfma_f32_16x16x32_bf16(af[m], bfr[n], acc[m][n], 0, 0, 0);
  }
  const float scale = 0.02209708691207961f;  // 1/sqrt(2048)
#pragma unroll
  for (int m = 0; m < 4; ++m)
#pragma unroll
    for (int n = 0; n < 2; ++n) {
      const int f = wn * 32 + n * 16 + r;
      const int n0 = bm + wm * 64 + m * 16 + g * 4;
      f32x4 v = acc[m][n];
      v *= scale;
      *(f32x4*)(adjT + ((size_t)b * FF + f) * NOBJ + n0) = v;
    }
}

// --------------------------------------------------------------------------
// Row softmax over 2304 (rows of adjT), write bf16. grid = 512 rows.
// --------------------------------------------------------------------------
__global__ __launch_bounds__(256) void k_smax(const float* __restrict__ adjT,
                                              unsigned short* __restrict__ out) {
  const int t = threadIdx.x;
  const size_t base = (size_t)blockIdx.x * NOBJ;
  float v[9];
#pragma unroll
  for (int j = 0; j < 9; ++j) v[j] = adjT[base + t + j * 256];
  float m = v[0];
#pragma unroll
  for (int j = 1; j < 9; ++j) m = fmaxf(m, v[j]);
#pragma unroll
  for (int s = 1; s < 64; s <<= 1) m = fmaxf(m, __shfl_xor(m, s, 64));
  __shared__ float rm[4], rs[4];
  const int wave = t >> 6;
  if ((t & 63) == 0) rm[wave] = m;
  __syncthreads();
  m = fmaxf(fmaxf(rm[0], rm[1]), fmaxf(rm[2], rm[3]));
  float e[9];
  float s = 0.f;
#pragma unroll
  for (int j = 0; j < 9; ++j) {
    e[j] = __expf(v[j] - m);
    s += e[j];
  }
#pragma unroll
  for (int q = 1; q < 64; q <<= 1) s += __shfl_xor(s, q, 64);
  if ((t & 63) == 0) rs[wave] = s;
  __syncthreads();
  const float S = rs[0] + rs[1] + rs[2] + rs[3];
  const float inv = 1.0f / S;
#pragma unroll
  for (int j = 0; j < 9; ++j) out[base + t + j * 256] = f2bf(e[j] * inv);
}

// --------------------------------------------------------------------------
// agg[b][f][d] = sum_n adj_sm[b][f][n] * oeT[b][d][n].
// --------------------------------------------------------------------------
__global__ __launch_bounds__(256) void k_gemm_agg(const unsigned short* __restrict__ adjsm,
                                                  const unsigned short* __restrict__ oeT,
                                                  float* __restrict__ agg) {
  __shared__ __align__(16) unsigned short As[64 * 32];
  __shared__ __align__(16) unsigned short Bs[128 * 32];
  const int t = threadIdx.x;
  const int lane = t & 63, wave = t >> 6;
  const int r = lane & 15, g = lane >> 4;
  const int wm = wave >> 1, wn = wave & 1;
  const int b = blockIdx.y, bn = blockIdx.x * 128;
  const int ar = t >> 2, aseg = t & 3;
  const int brow = t >> 1, bh = t & 1;
  f32x4 acc[2][4] = {};
  const unsigned short* aptr = adjsm + ((size_t)b * FF + ar) * NOBJ + aseg * 8;
  const unsigned short* bptr = oeT + ((size_t)b * DD + bn + brow) * NOBJ + bh * 16;
  for (int kt = 0; kt < NOBJ / 32; ++kt) {
    const int kb = kt * 32;
    u32x4 av = *(const u32x4*)(aptr + kb);
    u32x4 b0 = ((const u32x4*)(bptr + kb))[0];
    u32x4 b1 = ((const u32x4*)(bptr + kb))[1];
    __syncthreads();
    ((u32x4*)As)[ar * 4 + aseg] = av;
    ((u32x4*)Bs)[brow * 4 + bh * 2 + 0] = b0;
    ((u32x4*)Bs)[brow * 4 + bh * 2 + 1] = b1;
    __syncthreads();
    bf16x8 af[2], bfr[4];
#pragma unroll
    for (int m = 0; m < 2; ++m) af[m] = ((const bf16x8*)As)[(wm * 32 + m * 16 + r) * 4 + g];
#pragma unroll
    for (int n = 0; n < 4; ++n) bfr[n] = ((const bf16x8*)Bs)[(wn * 64 + n * 16 + r) * 4 + g];
#pragma unroll
    for (int m = 0; m < 2; ++m)
#pragma unroll
      for (int n = 0; n < 4; ++n)
        acc[m][n] = __builtin_amdgcn_mfma_f32_16x16x32_bf16(af[m], bfr[n], acc[m][n], 0, 0, 0);
  }
#pragma unroll
  for (int m = 0; m < 2; ++m)
#pragma unroll
    for (int n = 0; n < 4; ++n) {
      const int d = bn + wn * 64 + n * 16 + r;
#pragma unroll
      for (int i = 0; i < 4; ++i) {
        const int f = wm * 32 + m * 16 + g * 4 + i;
        agg[((size_t)b * FF + f) * DD + d] = acc[m][n][i];
      }
    }
}

// --------------------------------------------------------------------------

extern "C" void kernel_launch(void* const* d_in, const int* in_sizes, int n_in,
                              void* d_out, int out_size, void* d_ws, size_t ws_size,
                              hipStream_t stream) {
  (void)in_sizes; (void)n_in; (void)out_size;
  const float* visual = (const float*)d_in[0];
  const float* obj    = (const float*)d_in[1];
  const float* W_v    = (const float*)d_in[2];
  const float* b_v    = (const float*)d_in[3];
  const float* W_o    = (const float*)d_in[4];
  const float* b_o    = (const float*)d_in[5];
  const float* ln_v_g = (const float*)d_in[6];
  const float* ln_v_b = (const float*)d_in[7];
  const float* ln_o_g = (const float*)d_in[8];
  const float* ln_o_b = (const float*)d_in[9];
  const float* ln_ov_g = (const float*)d_in[10];
  const float* ln_ov_b = (const float*)d_in[11];

  // Workspace layout (aliased; ~253 MiB):
  //   [0,8M)      WvT
  //   [8M,16M)    WoT
  //   [16M,88M)   objb (bf16) -> later oe_b (objb dead after obj GEMM)
  //   [88M,160M)  T (bf16 tanh) -> later oeT (T dead after ep_ln2)
  //   [160M,165M) part (LN partials, 4.6 MiB)
  //   [232M,..)   Yv, ve_f, ve_b, adjT, adjs, agg
  char* ws = (char*)d_ws;
  constexpr size_t OFF_WVT = 0;
  constexpr size_t OFF_WOT = 8ull << 20;
  constexpr size_t OFF_OBJB = 16ull << 20;
  constexpr size_t OFF_T   = 88ull << 20;
  constexpr size_t OFF_PART = 160ull << 20;
  constexpr size_t OFF_YV  = 232ull << 20;
  constexpr size_t OFF_VEF = 236ull << 20;
  constexpr size_t OFF_VEB = 240ull << 20;
  constexpr size_t OFF_ADJ = 242ull << 20;
  constexpr size_t OFF_ADJS = OFF_ADJ + 4718592ull;
  constexpr size_t OFF_AGG = OFF_ADJS + 2359296ull;
  constexpr size_t WS_NEED = OFF_AGG + 4194304ull;
  if (ws_size < WS_NEED) return;

  unsigned short* WvT  = (unsigned short*)(ws + OFF_WVT);
  unsigned short* WoT  = (unsigned short*)(ws + OFF_WOT);
  unsigned short* objb = (unsigned short*)(ws + OFF_OBJB);
  unsigned short* oe_b = (unsigned short*)(ws + OFF_OBJB);  // alias (objb dead)
  unsigned short* T    = (unsigned short*)(ws + OFF_T);
  unsigned short* oeT  = (unsigned short*)(ws + OFF_T);     // alias (T dead)
  float* part          = (float*)(ws + OFF_PART);
  float* Yv            = (float*)(ws + OFF_YV);
  float* ve_f          = (float*)(ws + OFF_VEF);
  unsigned short* ve_b = (unsigned short*)(ws + OFF_VEB);
  float* adjT          = (float*)(ws + OFF_ADJ);
  unsigned short* adjs = (unsigned short*)(ws + OFF_ADJS);
  float* agg           = (float*)(ws + OFF_AGG);

  dim3 b256(256);
  // 1) weight transpose+convert, obj fp32->bf16
  k_wprep<<<dim3(32, 32), b256, 0, stream>>>(W_v, WvT);
  k_wprep<<<dim3(32, 32), b256, 0, stream>>>(W_o, WoT);
  k_cvt_bf16<<<dim3(2048), b256, 0, stream>>>(obj, objb, MO * DD / 16);
  // 2) branch GEMMs (obj GEMM fused with tanh + LN partials)
  k_gemm_xw<<<dim3(16, MV / 128), b256, 0, stream>>>(visual, WvT, b_v, Yv);
  k_gemm_bbf<<<dim3(8, MO / 256), dim3(512), 0, stream>>>(objb, WoT, b_o, T, part);
  // 3) LN epilogues
  k_ep_ln<<<dim3(MV), b256, 0, stream>>>(Yv, nullptr, ln_v_g, ln_v_b, ve_b, ve_f);
  k_ep_ln2<<<dim3(MO), b256, 0, stream>>>(T, part, ln_o_g, ln_o_b, oe_b);
  // 4) oe transpose (oeT aliases T)
  k_troe<<<dim3(36, 32, 8), b256, 0, stream>>>(oe_b, oeT);
  // 5) adjacency + softmax
  k_gemm_adj<<<dim3(NOBJ / 128, BS), b256, 0, stream>>>(oe_b, ve_b, adjT);
  k_smax<<<dim3(MV), b256, 0, stream>>>(adjT, adjs);
  // 6) aggregation
  k_gemm_agg<<<dim3(DD / 128, BS), b256, 0, stream>>>(adjs, oeT, agg);
  // 7) final add + tanh + LN -> d_out (fp32)
  k_ep_ln<<<dim3(MV), b256, 0, stream>>>(agg, ve_f, ln_ov_g, ln_ov_b, nullptr, (float*)d_out);
}

// Round 6
// 487.325 us; speedup vs baseline: 1.2105x; 1.1044x over previous
//
#include <hip/hip_runtime.h>
#include <cstdint>
#include <cstddef>

// ---------------------------------------------------------------------------
// EnhancedObj: visual/object attention block, bf16-MFMA implementation.
// Shapes (hardcoded): bs=8, F=64, obj=36, d=2048.
//   MO = 18432 object rows, MV = 512 visual rows, NOBJ = 2304.
// Round 6: obj GEMM keeps r5 skeleton (256x256, BK=64, 8 waves 2Mx4N,
// 2x64KB LDS dbuf, row-major XOR-swizzled LDS, stage-all-early + vmcnt(0)
// at step end, XCD swizzle, fused tanh+LN-partial epilogue) with the
// operand-residency fix: B-frags (8 x b128) loaded ONCE per K-step and held
// in registers; A loaded per-quadrant (4 x b128). LDS reads 48 -> 24 per
// wave per K-step (the round-5 limiter). Mid-phase barriers dropped: only
// end-of-step vmcnt+barrier is correctness-required; waves free-run within
// the step so ds_read of one wave overlaps MFMA of the other.
// ---------------------------------------------------------------------------

typedef __attribute__((ext_vector_type(4))) float f32x4;
typedef __attribute__((ext_vector_type(4))) unsigned int u32x4;
typedef __attribute__((ext_vector_type(8))) short bf16x8;

#define DD 2048
#define BS 8
#define FF 64
#define NOBJ 2304
#define MO 18432
#define MV 512

__device__ __forceinline__ unsigned short f2bf(float f) {
  unsigned int u = __float_as_uint(f);
  u += 0x7fffu + ((u >> 16) & 1u);          // RTNE (inputs finite)
  return (unsigned short)(u >> 16);
}
__device__ __forceinline__ unsigned int pk2(float a, float b) {
  return (unsigned int)f2bf(a) | ((unsigned int)f2bf(b) << 16);
}
__device__ __forceinline__ float bf2f(unsigned short u) {
  return __uint_as_float((unsigned int)u << 16);
}

typedef __attribute__((address_space(1))) const unsigned int gas_u32;
typedef __attribute__((address_space(3))) unsigned int las_u32;
__device__ __forceinline__ void gl_lds16(const void* g, void* l) {
  __builtin_amdgcn_global_load_lds((gas_u32*)g, (las_u32*)l, 16, 0, 0);
}

// --------------------------------------------------------------------------
// fp32 -> bf16 bulk convert. Each thread: 16 elements per iter.
// --------------------------------------------------------------------------
__global__ __launch_bounds__(256) void k_cvt_bf16(const float* __restrict__ X,
                                                  unsigned short* __restrict__ O,
                                                  int n16) {
  int idx = blockIdx.x * 256 + threadIdx.x;
  const int stride = gridDim.x * 256;
  for (int i = idx; i < n16; i += stride) {
    const f32x4* src = (const f32x4*)(X + (size_t)i * 16);
    f32x4 a = src[0], b = src[1], c = src[2], d = src[3];
    u32x4 p = {pk2(a.x, a.y), pk2(a.z, a.w), pk2(b.x, b.y), pk2(b.z, b.w)};
    u32x4 q = {pk2(c.x, c.y), pk2(c.z, c.w), pk2(d.x, d.y), pk2(d.z, d.w)};
    u32x4* dst = (u32x4*)(O + (size_t)i * 16);
    dst[0] = p;
    dst[1] = q;
  }
}

// --------------------------------------------------------------------------
// Both W[k][n] fp32 (2048x2048) -> Wt[n][k] bf16. 64x64 tiles via LDS.
// grid (32, 32, 2): z selects (W_v -> WvT) or (W_o -> WoT).
// --------------------------------------------------------------------------
__global__ __launch_bounds__(256) void k_wprep2(const float* __restrict__ Wv,
                                                const float* __restrict__ Wo,
                                                unsigned short* __restrict__ WvT,
                                                unsigned short* __restrict__ WoT) {
  __shared__ unsigned short sh[64][65];
  const float* W = blockIdx.z ? Wo : Wv;
  unsigned short* Wt = blockIdx.z ? WoT : WvT;
  const int t = threadIdx.x;
  const int kb = blockIdx.x * 64, nb = blockIdx.y * 64;
  {
    const int rk = t >> 2, seg = t & 3;
    const float* src = W + (size_t)(kb + rk) * DD + nb + seg * 16;
#pragma unroll
    for (int q = 0; q < 4; ++q) {
      f32x4 x = *(const f32x4*)(src + q * 4);
      sh[rk][seg * 16 + q * 4 + 0] = f2bf(x.x);
      sh[rk][seg * 16 + q * 4 + 1] = f2bf(x.y);
      sh[rk][seg * 16 + q * 4 + 2] = f2bf(x.z);
      sh[rk][seg * 16 + q * 4 + 3] = f2bf(x.w);
    }
  }
  __syncthreads();
  {
    const int nn = t >> 2, ks = t & 3;
    unsigned int o[8];
#pragma unroll
    for (int j = 0; j < 8; ++j)
      o[j] = (unsigned int)sh[ks * 16 + 2 * j][nn] |
             ((unsigned int)sh[ks * 16 + 2 * j + 1][nn] << 16);
    u32x4 p0 = {o[0], o[1], o[2], o[3]};
    u32x4 p1 = {o[4], o[5], o[6], o[7]};
    unsigned short* dst = Wt + (size_t)(nb + nn) * DD + kb + ks * 16;
    ((u32x4*)dst)[0] = p0;
    ((u32x4*)dst)[1] = p1;
  }
}

// --------------------------------------------------------------------------
// Obj GEMM fused: T[MO][2048] = bf16(tanh(A@Bt^T + bias)), plus per-row
// partial LN sums part[row][32][2] = {sum t, sum t^2} over 64-col groups.
// Geometry: BM=BN=256, BK=64, 512 thr = 8 waves (wm 0..1, wn 0..3),
// wave tile 128x64. LDS: 2 buffers x (A 256x64 + B 256x64) bf16 = 128 KiB.
// LDS layout: row-major; row r's 16B-chunk at physical slot s holds logical
// k16 = s ^ (r&7). Staging source 128B-coalesced; ds_read_b128 conflict-free.
// K-step: stage(next) first (8 gl_lds16, drains ~2480cyc later = free);
// read B once (8 b128, resident all step); per A-quadrant {4 b128, 16 MFMA}.
// One vmcnt(0) + s_barrier per step. grid = (8, 72); XCD-bijective swizzle.
// --------------------------------------------------------------------------
__global__ __launch_bounds__(512, 1) void k_gemm_bbf(const unsigned short* __restrict__ A,
                                                     const unsigned short* __restrict__ Bt,
                                                     const float* __restrict__ bias,
                                                     unsigned short* __restrict__ T,
                                                     float* __restrict__ part) {
  __shared__ __align__(16) unsigned short lds[2 * 32768];  // 128 KiB
  const int tid = threadIdx.x;
  const int lane = tid & 63, wave = tid >> 6;
  const int r = lane & 15, g = lane >> 4;
  const int wm = wave >> 2, wn = wave & 3;

  // XCD-aware bijective remap (nwg = 576, %8 == 0, per = 72)
  const int orig = blockIdx.y * 8 + blockIdx.x;
  const int lin = (orig & 7) * 72 + (orig >> 3);
  const int bm = (lin >> 3) * 256;
  const int bn = (lin & 7) * 256;

  // staging: issue i covers chunk c = i*512 + tid; row = i*64 + tid>>3,
  // physslot = tid&7, logical k16 = physslot ^ (row&7).
  const int srow = tid >> 3;
  const int k16s = (tid & 7) ^ (srow & 7);
  const unsigned short* aS = A + (size_t)(bm + srow) * DD + k16s * 8;
  const unsigned short* bS = Bt + (size_t)(bn + srow) * DD + k16s * 8;

  auto stage = [&](int buf, int kt) {
    unsigned short* ab = lds + buf * 32768;
    unsigned short* bb = ab + 16384;
    const size_t ko = (size_t)kt * 64;
#pragma unroll
    for (int i = 0; i < 4; ++i)
      gl_lds16(aS + ko + (size_t)(i * 64) * DD, ab + ((i * 512 + tid) << 3));
#pragma unroll
    for (int i = 0; i < 4; ++i)
      gl_lds16(bS + ko + (size_t)(i * 64) * DD, bb + ((i * 512 + tid) << 3));
  };

  // frag-read offsets (shorts): row*64 + slot*8, slot = (kk*4+g) ^ (r&7)
  const int rs = r & 7;
  const int s0 = ((0 + g) ^ rs) * 8;
  const int s1 = ((4 + g) ^ rs) * 8;
  const int abase = (wm * 128 + r) * 64;
  const int bbase = 16384 + (wn * 64 + r) * 64;

  f32x4 acc[8][4] = {};

  stage(0, 0);
  asm volatile("s_waitcnt vmcnt(0)" ::: "memory");
  __builtin_amdgcn_s_barrier();

  for (int kt = 0; kt < DD / 64; ++kt) {
    const unsigned short* bufp = lds + (kt & 1) * 32768;
    const bool st = (kt + 1 < DD / 64);
    if (st) stage((kt + 1) & 1, kt + 1);     // DMA to other buffer, issued first

    bf16x8 bAll[4][2];                        // B resident for the whole step
#pragma unroll
    for (int ni = 0; ni < 4; ++ni) {
      const int ro = bbase + ni * 1024;       // (ni*16 rows) * 64
      bAll[ni][0] = *(const bf16x8*)(bufp + ro + s0);
      bAll[ni][1] = *(const bf16x8*)(bufp + ro + s1);
    }
#pragma unroll
    for (int q = 0; q < 4; ++q) {             // A-quadrants: rows q*32..q*32+31
      bf16x8 af[2][2];
#pragma unroll
      for (int mi = 0; mi < 2; ++mi) {
        const int ro = abase + (q * 32 + mi * 16) * 64;
        af[mi][0] = *(const bf16x8*)(bufp + ro + s0);
        af[mi][1] = *(const bf16x8*)(bufp + ro + s1);
      }
      __builtin_amdgcn_s_setprio(1);
#pragma unroll
      for (int mi = 0; mi < 2; ++mi)
#pragma unroll
        for (int ni = 0; ni < 4; ++ni) {
          acc[q * 2 + mi][ni] = __builtin_amdgcn_mfma_f32_16x16x32_bf16(
              af[mi][0], bAll[ni][0], acc[q * 2 + mi][ni], 0, 0, 0);
          acc[q * 2 + mi][ni] = __builtin_amdgcn_mfma_f32_16x16x32_bf16(
              af[mi][1], bAll[ni][1], acc[q * 2 + mi][ni], 0, 0, 0);
        }
      __builtin_amdgcn_s_setprio(0);
    }
    if (st) asm volatile("s_waitcnt vmcnt(0)" ::: "memory");  // issued ~full step ago
    __builtin_amdgcn_s_barrier();
  }

  // ---- fused epilogue: bias + tanh -> bf16 T, per-row partial LN sums ----
  float bv[4];
#pragma unroll
  for (int ni = 0; ni < 4; ++ni) bv[ni] = bias[bn + wn * 64 + ni * 16 + r];
  const int slot = ((lin & 7) << 2) + wn;  // 32 col-groups of 64
#pragma unroll
  for (int mi = 0; mi < 8; ++mi) {
#pragma unroll
    for (int i2 = 0; i2 < 4; ++i2) {
      const int row = bm + wm * 128 + mi * 16 + g * 4 + i2;
      unsigned short* trow = T + (size_t)row * DD + bn + wn * 64 + r;
      float s1 = 0.f, s2 = 0.f;
#pragma unroll
      for (int ni = 0; ni < 4; ++ni) {
        const float tv = tanhf(acc[mi][ni][i2] + bv[ni]);
        trow[ni * 16] = f2bf(tv);
        s1 += tv;
        s2 += tv * tv;
      }
#pragma unroll
      for (int m = 1; m < 16; m <<= 1) {
        s1 += __shfl_xor(s1, m, 64);
        s2 += __shfl_xor(s2, m, 64);
      }
      if (r == 0) {
        float2 p2 = make_float2(s1, s2);
        *(float2*)(part + (size_t)row * 64 + slot * 2) = p2;
      }
    }
  }
}

// --------------------------------------------------------------------------
// Finish obj LN: read T (bf16 tanh), partials; out oe_b = bf16(LN(t)*g+b).
// One block (256 thr) per row.
// --------------------------------------------------------------------------
__global__ __launch_bounds__(256) void k_ep_ln2(const unsigned short* __restrict__ T,
                                                const float* __restrict__ part,
                                                const float* __restrict__ gw,
                                                const float* __restrict__ bw,
                                                unsigned short* __restrict__ obf) {
  const int row = blockIdx.x, t = threadIdx.x;
  float s1 = 0.f, s2 = 0.f;
  if (t < 32) {
    float2 p = ((const float2*)(part + (size_t)row * 64))[t];
    s1 = p.x;
    s2 = p.y;
  }
#pragma unroll
  for (int m = 1; m < 64; m <<= 1) {
    s1 += __shfl_xor(s1, m, 64);
    s2 += __shfl_xor(s2, m, 64);
  }
  __shared__ float sh[2];
  if (t == 0) {
    sh[0] = s1;
    sh[1] = s2;
  }
  __syncthreads();
  const float mean = sh[0] * (1.0f / DD);
  const float var = sh[1] * (1.0f / DD) - mean * mean;
  const float rstd = rsqrtf(var + 1e-5f);
  const size_t base = (size_t)row * DD + t * 8;
  u32x4 tin = *(const u32x4*)(T + base);
  f32x4 g0 = ((const f32x4*)(gw + t * 8))[0], g1 = ((const f32x4*)(gw + t * 8))[1];
  f32x4 bb0 = ((const f32x4*)(bw + t * 8))[0], bb1 = ((const f32x4*)(bw + t * 8))[1];
  float gv[8], bvv[8];
  gv[0] = g0.x; gv[1] = g0.y; gv[2] = g0.z; gv[3] = g0.w;
  gv[4] = g1.x; gv[5] = g1.y; gv[6] = g1.z; gv[7] = g1.w;
  bvv[0] = bb0.x; bvv[1] = bb0.y; bvv[2] = bb0.z; bvv[3] = bb0.w;
  bvv[4] = bb1.x; bvv[5] = bb1.y; bvv[6] = bb1.z; bvv[7] = bb1.w;
  float o[8];
#pragma unroll
  for (int j = 0; j < 4; ++j) {
    const float tl = bf2f((unsigned short)(tin[j] & 0xffffu));
    const float th = bf2f((unsigned short)(tin[j] >> 16));
    o[2 * j] = (tl - mean) * rstd * gv[2 * j] + bvv[2 * j];
    o[2 * j + 1] = (th - mean) * rstd * gv[2 * j + 1] + bvv[2 * j + 1];
  }
  u32x4 p = {pk2(o[0], o[1]), pk2(o[2], o[3]), pk2(o[4], o[5]), pk2(o[6], o[7])};
  *((u32x4*)(obf + base)) = p;
}

// --------------------------------------------------------------------------
// Y[M][2048] = X[M][2048](fp32) @ W + bias (inline convert). Visual branch.
// --------------------------------------------------------------------------
__global__ __launch_bounds__(256) void k_gemm_xw(const float* __restrict__ X,
                                                 const unsigned short* __restrict__ Wt,
                                                 const float* __restrict__ bias,
                                                 float* __restrict__ Y) {
  __shared__ __align__(16) unsigned short As[128 * 32];
  __shared__ __align__(16) unsigned short Bs[128 * 32];
  const int t = threadIdx.x;
  const int lane = t & 63, wave = t >> 6;
  const int r = lane & 15, g = lane >> 4;
  const int wm = wave >> 1, wn = wave & 1;
  const int bm = blockIdx.y * 128, bn = blockIdx.x * 128;
  const int arow = t >> 1, ah = t & 1;
  f32x4 acc[4][4] = {};
  const float* aptr = X + (size_t)(bm + arow) * DD + ah * 16;
  const unsigned short* bptr = Wt + (size_t)(bn + arow) * DD + ah * 16;
  for (int kt = 0; kt < DD / 32; ++kt) {
    const int kb = kt * 32;
    f32x4 a0 = *(const f32x4*)(aptr + kb);
    f32x4 a1 = *(const f32x4*)(aptr + kb + 4);
    f32x4 a2 = *(const f32x4*)(aptr + kb + 8);
    f32x4 a3 = *(const f32x4*)(aptr + kb + 12);
    u32x4 b0 = *(const u32x4*)(bptr + kb);
    u32x4 b1 = *(const u32x4*)(bptr + kb + 8);
    __syncthreads();
    u32x4 p0 = {pk2(a0.x, a0.y), pk2(a0.z, a0.w), pk2(a1.x, a1.y), pk2(a1.z, a1.w)};
    u32x4 p1 = {pk2(a2.x, a2.y), pk2(a2.z, a2.w), pk2(a3.x, a3.y), pk2(a3.z, a3.w)};
    ((u32x4*)As)[arow * 4 + ah * 2 + 0] = p0;
    ((u32x4*)As)[arow * 4 + ah * 2 + 1] = p1;
    ((u32x4*)Bs)[arow * 4 + ah * 2 + 0] = b0;
    ((u32x4*)Bs)[arow * 4 + ah * 2 + 1] = b1;
    __syncthreads();
    bf16x8 af[4], bfr[4];
#pragma unroll
    for (int m = 0; m < 4; ++m) af[m] = ((const bf16x8*)As)[(wm * 64 + m * 16 + r) * 4 + g];
#pragma unroll
    for (int n = 0; n < 4; ++n) bfr[n] = ((const bf16x8*)Bs)[(wn * 64 + n * 16 + r) * 4 + g];
#pragma unroll
    for (int m = 0; m < 4; ++m)
#pragma unroll
      for (int n = 0; n < 4; ++n)
        acc[m][n] = __builtin_amdgcn_mfma_f32_16x16x32_bf16(af[m], bfr[n], acc[m][n], 0, 0, 0);
  }
#pragma unroll
  for (int m = 0; m < 4; ++m) {
    const int row0 = bm + wm * 64 + m * 16 + g * 4;
#pragma unroll
    for (int n = 0; n < 4; ++n) {
      const int col = bn + wn * 64 + n * 16 + r;
      const float bvx = bias[col];
#pragma unroll
      for (int i = 0; i < 4; ++i)
        Y[(size_t)(row0 + i) * DD + col] = acc[m][n][i] + bvx;
    }
  }
}

// --------------------------------------------------------------------------
// Row-wise: t = tanh(Y[row] (+ Y2[row])); LN(t)*g+b -> optional bf16 / fp32.
// --------------------------------------------------------------------------
__global__ __launch_bounds__(256) void k_ep_ln(const float* __restrict__ Y,
                                               const float* __restrict__ Y2,
                                               const float* __restrict__ gw,
                                               const float* __restrict__ bw,
                                               unsigned short* __restrict__ obf,
                                               float* __restrict__ of32) {
  const int row = blockIdx.x, t = threadIdx.x;
  const size_t base = (size_t)row * DD + t * 8;
  f32x4 v0 = ((const f32x4*)(Y + base))[0];
  f32x4 v1 = ((const f32x4*)(Y + base))[1];
  if (Y2 != nullptr) {
    v0 += ((const f32x4*)(Y2 + base))[0];
    v1 += ((const f32x4*)(Y2 + base))[1];
  }
  float tv[8];
#pragma unroll
  for (int j = 0; j < 4; ++j) {
    tv[j] = tanhf(v0[j]);
    tv[4 + j] = tanhf(v1[j]);
  }
  float s1 = 0.f, s2 = 0.f;
#pragma unroll
  for (int j = 0; j < 8; ++j) {
    s1 += tv[j];
    s2 += tv[j] * tv[j];
  }
#pragma unroll
  for (int m = 1; m < 64; m <<= 1) {
    s1 += __shfl_xor(s1, m, 64);
    s2 += __shfl_xor(s2, m, 64);
  }
  __shared__ float r1[4], r2[4];
  const int wave = t >> 6;
  if ((t & 63) == 0) {
    r1[wave] = s1;
    r2[wave] = s2;
  }
  __syncthreads();
  const float S1 = r1[0] + r1[1] + r1[2] + r1[3];
  const float S2 = r2[0] + r2[1] + r2[2] + r2[3];
  const float mean = S1 * (1.0f / DD);
  const float var = S2 * (1.0f / DD) - mean * mean;
  const float rstd = rsqrtf(var + 1e-5f);
  f32x4 g0 = ((const f32x4*)(gw + t * 8))[0], g1 = ((const f32x4*)(gw + t * 8))[1];
  f32x4 bb0 = ((const f32x4*)(bw + t * 8))[0], bb1 = ((const f32x4*)(bw + t * 8))[1];
  float o[8];
#pragma unroll
  for (int j = 0; j < 4; ++j) {
    o[j] = (tv[j] - mean) * rstd * g0[j] + bb0[j];
    o[4 + j] = (tv[4 + j] - mean) * rstd * g1[j] + bb1[j];
  }
  if (obf != nullptr) {
    u32x4 p = {pk2(o[0], o[1]), pk2(o[2], o[3]), pk2(o[4], o[5]), pk2(o[6], o[7])};
    *((u32x4*)(obf + base)) = p;
  }
  if (of32 != nullptr) {
    f32x4 w0 = {o[0], o[1], o[2], o[3]}, w1 = {o[4], o[5], o[6], o[7]};
    ((f32x4*)(of32 + base))[0] = w0;
    ((f32x4*)(of32 + base))[1] = w1;
  }
}

// --------------------------------------------------------------------------
// oe[b][n][d] bf16 -> oeT[b][d][n] bf16, 64x64 tiles. grid (36, 32, 8).
// --------------------------------------------------------------------------
__global__ __launch_bounds__(256) void k_troe(const unsigned short* __restrict__ oe,
                                              unsigned short* __restrict__ oeT) {
  __shared__ unsigned short sh[64][65];
  const int t = threadIdx.x;
  const int b = blockIdx.z, nt = blockIdx.x, dt = blockIdx.y;
  {
    const int nn = t >> 2, seg = t & 3;
    const unsigned short* src = oe + ((size_t)b * NOBJ + nt * 64 + nn) * DD + dt * 64 + seg * 16;
    u32x4 x0 = ((const u32x4*)src)[0];
    u32x4 x1 = ((const u32x4*)src)[1];
    const unsigned short* px0 = (const unsigned short*)&x0;
    const unsigned short* px1 = (const unsigned short*)&x1;
#pragma unroll
    for (int j = 0; j < 8; ++j) {
      sh[nn][seg * 16 + j] = px0[j];
      sh[nn][seg * 16 + 8 + j] = px1[j];
    }
  }
  __syncthreads();
  {
    const int dd = t >> 2, ns = t & 3;
    unsigned int o[8];
#pragma unroll
    for (int j = 0; j < 8; ++j)
      o[j] = (unsigned int)sh[ns * 16 + 2 * j][dd] |
             ((unsigned int)sh[ns * 16 + 2 * j + 1][dd] << 16);
    u32x4 p0 = {o[0], o[1], o[2], o[3]};
    u32x4 p1 = {o[4], o[5], o[6], o[7]};
    unsigned short* dst = oeT + ((size_t)b * DD + dt * 64 + dd) * NOBJ + nt * 64 + ns * 16;
    ((u32x4*)dst)[0] = p0;
    ((u32x4*)dst)[1] = p1;
  }
}

// --------------------------------------------------------------------------
// adjT[b][f][n] = (oe[b][n][:] . ve[b][f][:]) / sqrt(2048).
// --------------------------------------------------------------------------
__global__ __launch_bounds__(256) void k_gemm_adj(const unsigned short* __restrict__ oe,
                                                  const unsigned short* __restrict__ veb,
                                                  float* __restrict__ adjT) {
  __shared__ __align__(16) unsigned short As[128 * 32];
  __shared__ __align__(16) unsigned short Bs[64 * 32];
  const int t = threadIdx.x;
  const int lane = t & 63, wave = t >> 6;
  const int r = lane & 15, g = lane >> 4;
  const int wm = wave >> 1, wn = wave & 1;
  const int b = blockIdx.y, bm = blockIdx.x * 128;
  const int arow = t >> 1, ah = t & 1;
  const int br_ = t >> 2, bseg = t & 3;
  f32x4 acc[4][2] = {};
  const unsigned short* aptr = oe + ((size_t)b * NOBJ + bm + arow) * DD + ah * 16;
  const unsigned short* bptr = veb + ((size_t)b * FF + br_) * DD + bseg * 8;
  for (int kt = 0; kt < DD / 32; ++kt) {
    const int kb = kt * 32;
    u32x4 a0 = ((const u32x4*)(aptr + kb))[0];
    u32x4 a1 = ((const u32x4*)(aptr + kb))[1];
    u32x4 bvx = *(const u32x4*)(bptr + kb);
    __syncthreads();
    ((u32x4*)As)[arow * 4 + ah * 2 + 0] = a0;
    ((u32x4*)As)[arow * 4 + ah * 2 + 1] = a1;
    ((u32x4*)Bs)[br_ * 4 + bseg] = bvx;
    __syncthreads();
    bf16x8 af[4], bfr[2];
#pragma unroll
    for (int m = 0; m < 4; ++m) af[m] = ((const bf16x8*)As)[(wm * 64 + m * 16 + r) * 4 + g];
#pragma unroll
    for (int n = 0; n < 2; ++n) bfr[n] = ((const bf16x8*)Bs)[(wn * 32 + n * 16 + r) * 4 + g];
#pragma unroll
    for (int m = 0; m < 4; ++m)
#pragma unroll
      for (int n = 0; n < 2; ++n)
        acc[m][n] = __builtin_amdgcn_mfma_f32_16x16x32_bf16(af[m], bfr[n], acc[m][n], 0, 0, 0);
  }
  const float scale = 0.02209708691207961f;  // 1/sqrt(2048)
#pragma unroll
  for (int m = 0; m < 4; ++m)
#pragma unroll
    for (int n = 0; n < 2; ++n) {
      const int f = wn * 32 + n * 16 + r;
      const int n0 = bm + wm * 64 + m * 16 + g * 4;
      f32x4 v = acc[m][n];
      v *= scale;
      *(f32x4*)(adjT + ((size_t)b * FF + f) * NOBJ + n0) = v;
    }
}

// --------------------------------------------------------------------------
// Row softmax over 2304 (rows of adjT), write bf16. grid = 512 rows.
// --------------------------------------------------------------------------
__global__ __launch_bounds__(256) void k_smax(const float* __restrict__ adjT,
                                              unsigned short* __restrict__ out) {
  const int t = threadIdx.x;
  const size_t base = (size_t)blockIdx.x * NOBJ;
  float v[9];
#pragma unroll
  for (int j = 0; j < 9; ++j) v[j] = adjT[base + t + j * 256];
  float m = v[0];
#pragma unroll
  for (int j = 1; j < 9; ++j) m = fmaxf(m, v[j]);
#pragma unroll
  for (int s = 1; s < 64; s <<= 1) m = fmaxf(m, __shfl_xor(m, s, 64));
  __shared__ float rm[4], rs[4];
  const int wave = t >> 6;
  if ((t & 63) == 0) rm[wave] = m;
  __syncthreads();
  m = fmaxf(fmaxf(rm[0], rm[1]), fmaxf(rm[2], rm[3]));
  float e[9];
  float s = 0.f;
#pragma unroll
  for (int j = 0; j < 9; ++j) {
    e[j] = __expf(v[j] - m);
    s += e[j];
  }
#pragma unroll
  for (int q = 1; q < 64; q <<= 1) s += __shfl_xor(s, q, 64);
  if ((t & 63) == 0) rs[wave] = s;
  __syncthreads();
  const float S = rs[0] + rs[1] + rs[2] + rs[3];
  const float inv = 1.0f / S;
#pragma unroll
  for (int j = 0; j < 9; ++j) out[base + t + j * 256] = f2bf(e[j] * inv);
}

// --------------------------------------------------------------------------
// agg[b][f][d] = sum_n adj_sm[b][f][n] * oeT[b][d][n].
// --------------------------------------------------------------------------
__global__ __launch_bounds__(256) void k_gemm_agg(const unsigned short* __restrict__ adjsm,
                                                  const unsigned short* __restrict__ oeT,
                                                  float* __restrict__ agg) {
  __shared__ __align__(16) unsigned short As[64 * 32];
  __shared__ __align__(16) unsigned short Bs[128 * 32];
  const int t = threadIdx.x;
  const int lane = t & 63, wave = t >> 6;
  const int r = lane & 15, g = lane >> 4;
  const int wm = wave >> 1, wn = wave & 1;
  const int b = blockIdx.y, bn = blockIdx.x * 128;
  const int ar = t >> 2, aseg = t & 3;
  const int brow = t >> 1, bh = t & 1;
  f32x4 acc[2][4] = {};
  const unsigned short* aptr = adjsm + ((size_t)b * FF + ar) * NOBJ + aseg * 8;
  const unsigned short* bptr = oeT + ((size_t)b * DD + bn + brow) * NOBJ + bh * 16;
  for (int kt = 0; kt < NOBJ / 32; ++kt) {
    const int kb = kt * 32;
    u32x4 av = *(const u32x4*)(aptr + kb);
    u32x4 b0 = ((const u32x4*)(bptr + kb))[0];
    u32x4 b1 = ((const u32x4*)(bptr + kb))[1];
    __syncthreads();
    ((u32x4*)As)[ar * 4 + aseg] = av;
    ((u32x4*)Bs)[brow * 4 + bh * 2 + 0] = b0;
    ((u32x4*)Bs)[brow * 4 + bh * 2 + 1] = b1;
    __syncthreads();
    bf16x8 af[2], bfr[4];
#pragma unroll
    for (int m = 0; m < 2; ++m) af[m] = ((const bf16x8*)As)[(wm * 32 + m * 16 + r) * 4 + g];
#pragma unroll
    for (int n = 0; n < 4; ++n) bfr[n] = ((const bf16x8*)Bs)[(wn * 64 + n * 16 + r) * 4 + g];
#pragma unroll
    for (int m = 0; m < 2; ++m)
#pragma unroll
      for (int n = 0; n < 4; ++n)
        acc[m][n] = __builtin_amdgcn_mfma_f32_16x16x32_bf16(af[m], bfr[n], acc[m][n], 0, 0, 0);
  }
#pragma unroll
  for (int m = 0; m < 2; ++m)
#pragma unroll
    for (int n = 0; n < 4; ++n) {
      const int d = bn + wn * 64 + n * 16 + r;
#pragma unroll
      for (int i = 0; i < 4; ++i) {
        const int f = wm * 32 + m * 16 + g * 4 + i;
        agg[((size_t)b * FF + f) * DD + d] = acc[m][n][i];
      }
    }
}

// --------------------------------------------------------------------------

extern "C" void kernel_launch(void* const* d_in, const int* in_sizes, int n_in,
                              void* d_out, int out_size, void* d_ws, size_t ws_size,
                              hipStream_t stream) {
  (void)in_sizes; (void)n_in; (void)out_size;
  const float* visual = (const float*)d_in[0];
  const float* obj    = (const float*)d_in[1];
  const float* W_v    = (const float*)d_in[2];
  const float* b_v    = (const float*)d_in[3];
  const float* W_o    = (const float*)d_in[4];
  const float* b_o    = (const float*)d_in[5];
  const float* ln_v_g = (const float*)d_in[6];
  const float* ln_v_b = (const float*)d_in[7];
  const float* ln_o_g = (const float*)d_in[8];
  const float* ln_o_b = (const float*)d_in[9];
  const float* ln_ov_g = (const float*)d_in[10];
  const float* ln_ov_b = (const float*)d_in[11];

  // Workspace layout (aliased; ~253 MiB):
  //   [0,8M)      WvT
  //   [8M,16M)    WoT
  //   [16M,88M)   objb (bf16) -> later oe_b (objb dead after obj GEMM)
  //   [88M,160M)  T (bf16 tanh) -> later oeT (T dead after ep_ln2)
  //   [160M,165M) part (LN partials, 4.6 MiB)
  //   [232M,..)   Yv, ve_f, ve_b, adjT, adjs, agg
  char* ws = (char*)d_ws;
  constexpr size_t OFF_WVT = 0;
  constexpr size_t OFF_WOT = 8ull << 20;
  constexpr size_t OFF_OBJB = 16ull << 20;
  constexpr size_t OFF_T   = 88ull << 20;
  constexpr size_t OFF_PART = 160ull << 20;
  constexpr size_t OFF_YV  = 232ull << 20;
  constexpr size_t OFF_VEF = 236ull << 20;
  constexpr size_t OFF_VEB = 240ull << 20;
  constexpr size_t OFF_ADJ = 242ull << 20;
  constexpr size_t OFF_ADJS = OFF_ADJ + 4718592ull;
  constexpr size_t OFF_AGG = OFF_ADJS + 2359296ull;
  constexpr size_t WS_NEED = OFF_AGG + 4194304ull;
  if (ws_size < WS_NEED) return;

  unsigned short* WvT  = (unsigned short*)(ws + OFF_WVT);
  unsigned short* WoT  = (unsigned short*)(ws + OFF_WOT);
  unsigned short* objb = (unsigned short*)(ws + OFF_OBJB);
  unsigned short* oe_b = (unsigned short*)(ws + OFF_OBJB);  // alias (objb dead)
  unsigned short* T    = (unsigned short*)(ws + OFF_T);
  unsigned short* oeT  = (unsigned short*)(ws + OFF_T);     // alias (T dead)
  float* part          = (float*)(ws + OFF_PART);
  float* Yv            = (float*)(ws + OFF_YV);
  float* ve_f          = (float*)(ws + OFF_VEF);
  unsigned short* ve_b = (unsigned short*)(ws + OFF_VEB);
  float* adjT          = (float*)(ws + OFF_ADJ);
  unsigned short* adjs = (unsigned short*)(ws + OFF_ADJS);
  float* agg           = (float*)(ws + OFF_AGG);

  dim3 b256(256);
  // 1) weight transpose+convert (both), obj fp32->bf16
  k_wprep2<<<dim3(32, 32, 2), b256, 0, stream>>>(W_v, W_o, WvT, WoT);
  k_cvt_bf16<<<dim3(2048), b256, 0, stream>>>(obj, objb, MO * DD / 16);
  // 2) branch GEMMs (obj GEMM fused with tanh + LN partials)
  k_gemm_xw<<<dim3(16, MV / 128), b256, 0, stream>>>(visual, WvT, b_v, Yv);
  k_gemm_bbf<<<dim3(8, MO / 256), dim3(512), 0, stream>>>(objb, WoT, b_o, T, part);
  // 3) LN epilogues
  k_ep_ln<<<dim3(MV), b256, 0, stream>>>(Yv, nullptr, ln_v_g, ln_v_b, ve_b, ve_f);
  k_ep_ln2<<<dim3(MO), b256, 0, stream>>>(T, part, ln_o_g, ln_o_b, oe_b);
  // 4) oe transpose (oeT aliases T)
  k_troe<<<dim3(36, 32, 8), b256, 0, stream>>>(oe_b, oeT);
  // 5) adjacency + softmax
  k_gemm_adj<<<dim3(NOBJ / 128, BS), b256, 0, stream>>>(oe_b, ve_b, adjT);
  k_smax<<<dim3(MV), b256, 0, stream>>>(adjT, adjs);
  // 6) aggregation
  k_gemm_agg<<<dim3(DD / 128, BS), b256, 0, stream>>>(adjs, oeT, agg);
  // 7) final add + tanh + LN -> d_out (fp32)
  k_ep_ln<<<dim3(MV), b256, 0, stream>>>(agg, ve_f, ln_ov_g, ln_ov_b, nullptr, (float*)d_out);
}

// Round 7
// 486.823 us; speedup vs baseline: 1.2118x; 1.0010x over previous
//
#include <hip/hip_runtime.h>
#include <cstdint>
#include <cstddef>

// ---------------------------------------------------------------------------
// EnhancedObj: visual/object attention block, bf16-MFMA implementation.
// Shapes (hardcoded): bs=8, F=64, obj=36, d=2048.
//   MO = 18432 object rows, MV = 512 visual rows, NOBJ = 2304.
// Round 7: obj GEMM = m201-template phase choreography on the r6 skeleton.
// 256x256, BK=64, 8 waves 2Mx4N (wave tile 128x64), 2x64KB LDS dbuf,
// XOR-swizzled row-major LDS. Per K-tile: 4 phases (C-quadrants), each
// {ds_reads, gl_lds stage chunk, s_barrier, setprio1, 16 MFMA, setprio0,
// s_barrier}; B fully register-resident per tile (read ph0/ph1), A-halves
// resident 2 phases; 24 ds_read_b128 per wave per K-tile; staging 4+4 at
// phases 0/1; single vmcnt(0) at ph3 (>=1200cyc after last issue).
// Fused epilogue: tanh -> bf16 T + per-row LN partials.
// ---------------------------------------------------------------------------

typedef __attribute__((ext_vector_type(4))) float f32x4;
typedef __attribute__((ext_vector_type(4))) unsigned int u32x4;
typedef __attribute__((ext_vector_type(8))) short bf16x8;

#define DD 2048
#define BS 8
#define FF 64
#define NOBJ 2304
#define MO 18432
#define MV 512

__device__ __forceinline__ unsigned short f2bf(float f) {
  unsigned int u = __float_as_uint(f);
  u += 0x7fffu + ((u >> 16) & 1u);          // RTNE (inputs finite)
  return (unsigned short)(u >> 16);
}
__device__ __forceinline__ unsigned int pk2(float a, float b) {
  return (unsigned int)f2bf(a) | ((unsigned int)f2bf(b) << 16);
}
__device__ __forceinline__ float bf2f(unsigned short u) {
  return __uint_as_float((unsigned int)u << 16);
}

typedef __attribute__((address_space(1))) const unsigned int gas_u32;
typedef __attribute__((address_space(3))) unsigned int las_u32;
__device__ __forceinline__ void gl_lds16(const void* g, void* l) {
  __builtin_amdgcn_global_load_lds((gas_u32*)g, (las_u32*)l, 16, 0, 0);
}

// --------------------------------------------------------------------------
// fp32 -> bf16 bulk convert. Each thread: 16 elements per iter.
// --------------------------------------------------------------------------
__global__ __launch_bounds__(256) void k_cvt_bf16(const float* __restrict__ X,
                                                  unsigned short* __restrict__ O,
                                                  int n16) {
  int idx = blockIdx.x * 256 + threadIdx.x;
  const int stride = gridDim.x * 256;
  for (int i = idx; i < n16; i += stride) {
    const f32x4* src = (const f32x4*)(X + (size_t)i * 16);
    f32x4 a = src[0], b = src[1], c = src[2], d = src[3];
    u32x4 p = {pk2(a.x, a.y), pk2(a.z, a.w), pk2(b.x, b.y), pk2(b.z, b.w)};
    u32x4 q = {pk2(c.x, c.y), pk2(c.z, c.w), pk2(d.x, d.y), pk2(d.z, d.w)};
    u32x4* dst = (u32x4*)(O + (size_t)i * 16);
    dst[0] = p;
    dst[1] = q;
  }
}

// --------------------------------------------------------------------------
// Both W[k][n] fp32 (2048x2048) -> Wt[n][k] bf16. 64x64 tiles via LDS.
// grid (32, 32, 2): z selects (W_v -> WvT) or (W_o -> WoT).
// --------------------------------------------------------------------------
__global__ __launch_bounds__(256) void k_wprep2(const float* __restrict__ Wv,
                                                const float* __restrict__ Wo,
                                                unsigned short* __restrict__ WvT,
                                                unsigned short* __restrict__ WoT) {
  __shared__ unsigned short sh[64][65];
  const float* W = blockIdx.z ? Wo : Wv;
  unsigned short* Wt = blockIdx.z ? WoT : WvT;
  const int t = threadIdx.x;
  const int kb = blockIdx.x * 64, nb = blockIdx.y * 64;
  {
    const int rk = t >> 2, seg = t & 3;
    const float* src = W + (size_t)(kb + rk) * DD + nb + seg * 16;
#pragma unroll
    for (int q = 0; q < 4; ++q) {
      f32x4 x = *(const f32x4*)(src + q * 4);
      sh[rk][seg * 16 + q * 4 + 0] = f2bf(x.x);
      sh[rk][seg * 16 + q * 4 + 1] = f2bf(x.y);
      sh[rk][seg * 16 + q * 4 + 2] = f2bf(x.z);
      sh[rk][seg * 16 + q * 4 + 3] = f2bf(x.w);
    }
  }
  __syncthreads();
  {
    const int nn = t >> 2, ks = t & 3;
    unsigned int o[8];
#pragma unroll
    for (int j = 0; j < 8; ++j)
      o[j] = (unsigned int)sh[ks * 16 + 2 * j][nn] |
             ((unsigned int)sh[ks * 16 + 2 * j + 1][nn] << 16);
    u32x4 p0 = {o[0], o[1], o[2], o[3]};
    u32x4 p1 = {o[4], o[5], o[6], o[7]};
    unsigned short* dst = Wt + (size_t)(nb + nn) * DD + kb + ks * 16;
    ((u32x4*)dst)[0] = p0;
    ((u32x4*)dst)[1] = p1;
  }
}

// --------------------------------------------------------------------------
// Obj GEMM fused: T[MO][2048] = bf16(tanh(A@Bt^T + bias)), plus per-row
// partial LN sums part[row][32][2] = {sum t, sum t^2} over 64-col groups.
// grid = (8, 72); XCD-bijective swizzle. See header comment for schedule.
// --------------------------------------------------------------------------
__global__ __launch_bounds__(512, 1) void k_gemm_bbf(const unsigned short* __restrict__ A,
                                                     const unsigned short* __restrict__ Bt,
                                                     const float* __restrict__ bias,
                                                     unsigned short* __restrict__ T,
                                                     float* __restrict__ part) {
  __shared__ __align__(16) unsigned short lds[2 * 32768];  // 128 KiB
  const int tid = threadIdx.x;
  const int lane = tid & 63, wave = tid >> 6;
  const int r = lane & 15, g = lane >> 4;
  const int wm = wave >> 2, wn = wave & 3;

  // XCD-aware bijective remap (nwg = 576, %8 == 0, per = 72)
  const int orig = blockIdx.y * 8 + blockIdx.x;
  const int lin = (orig & 7) * 72 + (orig >> 3);
  const int bm = (lin >> 3) * 256;
  const int bn = (lin & 7) * 256;

  // staging: issue i covers chunk c = i*512 + tid; row = i*64 + tid>>3,
  // physslot = tid&7, logical k16 = physslot ^ (row&7).
  const int srow = tid >> 3;
  const int k16s = (tid & 7) ^ (srow & 7);
  const unsigned short* aS = A + (size_t)(bm + srow) * DD + k16s * 8;
  const unsigned short* bS = Bt + (size_t)(bn + srow) * DD + k16s * 8;

  auto stageA = [&](int buf, int kt) {
    unsigned short* ab = lds + buf * 32768;
    const size_t ko = (size_t)kt * 64;
#pragma unroll
    for (int i = 0; i < 4; ++i)
      gl_lds16(aS + ko + (size_t)(i * 64) * DD, ab + ((i * 512 + tid) << 3));
  };
  auto stageB = [&](int buf, int kt) {
    unsigned short* bb = lds + buf * 32768 + 16384;
    const size_t ko = (size_t)kt * 64;
#pragma unroll
    for (int i = 0; i < 4; ++i)
      gl_lds16(bS + ko + (size_t)(i * 64) * DD, bb + ((i * 512 + tid) << 3));
  };

  // frag-read offsets (shorts): row*64 + slot*8, slot = (kk*4+g) ^ (r&7)
  const int rs = r & 7;
  const int s0 = ((0 + g) ^ rs) * 8;
  const int s1 = ((4 + g) ^ rs) * 8;
  const int abase = (wm * 128 + r) * 64;
  const int bbase = 16384 + (wn * 64 + r) * 64;

  f32x4 acc[8][4] = {};
  bf16x8 aH[4][2];    // resident A-half (rows qa*64 .. qa*64+63 of wave tile)
  bf16x8 bAll[4][2];  // resident B (all 64 cols of wave tile)

  stageA(0, 0);
  stageB(0, 0);
  asm volatile("s_waitcnt vmcnt(0)" ::: "memory");
  __builtin_amdgcn_s_barrier();

  for (int kt = 0; kt < DD / 64; ++kt) {
    const unsigned short* bufp = lds + (kt & 1) * 32768;
    const bool st = (kt + 1 < DD / 64);

    // ---- phase 0: quadrant (A0, B0). reads: A0 (8) + B0 (4). stage A-next.
#pragma unroll
    for (int mi = 0; mi < 4; ++mi) {
      const int ro = abase + mi * 1024;            // (mi*16 rows)*64
      aH[mi][0] = *(const bf16x8*)(bufp + ro + s0);
      aH[mi][1] = *(const bf16x8*)(bufp + ro + s1);
    }
#pragma unroll
    for (int ni = 0; ni < 2; ++ni) {
      const int ro = bbase + ni * 1024;
      bAll[ni][0] = *(const bf16x8*)(bufp + ro + s0);
      bAll[ni][1] = *(const bf16x8*)(bufp + ro + s1);
    }
    if (st) stageA((kt + 1) & 1, kt + 1);
    __builtin_amdgcn_s_barrier();
    __builtin_amdgcn_s_setprio(1);
#pragma unroll
    for (int mi = 0; mi < 4; ++mi)
#pragma unroll
      for (int ni = 0; ni < 2; ++ni) {
        acc[mi][ni] = __builtin_amdgcn_mfma_f32_16x16x32_bf16(aH[mi][0], bAll[ni][0], acc[mi][ni], 0, 0, 0);
        acc[mi][ni] = __builtin_amdgcn_mfma_f32_16x16x32_bf16(aH[mi][1], bAll[ni][1], acc[mi][ni], 0, 0, 0);
      }
    __builtin_amdgcn_s_setprio(0);
    __builtin_amdgcn_s_barrier();

    // ---- phase 1: quadrant (A0, B1). reads: B1 (4). stage B-next.
#pragma unroll
    for (int ni = 2; ni < 4; ++ni) {
      const int ro = bbase + ni * 1024;
      bAll[ni][0] = *(const bf16x8*)(bufp + ro + s0);
      bAll[ni][1] = *(const bf16x8*)(bufp + ro + s1);
    }
    if (st) stageB((kt + 1) & 1, kt + 1);
    __builtin_amdgcn_s_barrier();
    __builtin_amdgcn_s_setprio(1);
#pragma unroll
    for (int mi = 0; mi < 4; ++mi)
#pragma unroll
      for (int ni = 2; ni < 4; ++ni) {
        acc[mi][ni] = __builtin_amdgcn_mfma_f32_16x16x32_bf16(aH[mi][0], bAll[ni][0], acc[mi][ni], 0, 0, 0);
        acc[mi][ni] = __builtin_amdgcn_mfma_f32_16x16x32_bf16(aH[mi][1], bAll[ni][1], acc[mi][ni], 0, 0, 0);
      }
    __builtin_amdgcn_s_setprio(0);
    __builtin_amdgcn_s_barrier();

    // ---- phase 2: quadrant (A1, B0). reads: A1 (8).
#pragma unroll
    for (int mi = 0; mi < 4; ++mi) {
      const int ro = abase + (64 + mi * 16) * 64;
      aH[mi][0] = *(const bf16x8*)(bufp + ro + s0);
      aH[mi][1] = *(const bf16x8*)(bufp + ro + s1);
    }
    __builtin_amdgcn_s_barrier();
    __builtin_amdgcn_s_setprio(1);
#pragma unroll
    for (int mi = 0; mi < 4; ++mi)
#pragma unroll
      for (int ni = 0; ni < 2; ++ni) {
        acc[4 + mi][ni] = __builtin_amdgcn_mfma_f32_16x16x32_bf16(aH[mi][0], bAll[ni][0], acc[4 + mi][ni], 0, 0, 0);
        acc[4 + mi][ni] = __builtin_amdgcn_mfma_f32_16x16x32_bf16(aH[mi][1], bAll[ni][1], acc[4 + mi][ni], 0, 0, 0);
      }
    __builtin_amdgcn_s_setprio(0);
    __builtin_amdgcn_s_barrier();

    // ---- phase 3: quadrant (A1, B1). no reads. vmcnt drain + dbuf barrier.
    __builtin_amdgcn_s_setprio(1);
#pragma unroll
    for (int mi = 0; mi < 4; ++mi)
#pragma unroll
      for (int ni = 2; ni < 4; ++ni) {
        acc[4 + mi][ni] = __builtin_amdgcn_mfma_f32_16x16x32_bf16(aH[mi][0], bAll[ni][0], acc[4 + mi][ni], 0, 0, 0);
        acc[4 + mi][ni] = __builtin_amdgcn_mfma_f32_16x16x32_bf16(aH[mi][1], bAll[ni][1], acc[4 + mi][ni], 0, 0, 0);
      }
    __builtin_amdgcn_s_setprio(0);
    if (st) asm volatile("s_waitcnt vmcnt(0)" ::: "memory");  // issued >=2 phases ago
    __builtin_amdgcn_s_barrier();
  }

  // ---- fused epilogue: bias + tanh -> bf16 T, per-row partial LN sums ----
  float bv[4];
#pragma unroll
  for (int ni = 0; ni < 4; ++ni) bv[ni] = bias[bn + wn * 64 + ni * 16 + r];
  const int slot = ((lin & 7) << 2) + wn;  // 32 col-groups of 64
#pragma unroll
  for (int mi = 0; mi < 8; ++mi) {
#pragma unroll
    for (int i2 = 0; i2 < 4; ++i2) {
      const int row = bm + wm * 128 + mi * 16 + g * 4 + i2;
      unsigned short* trow = T + (size_t)row * DD + bn + wn * 64 + r;
      float s1 = 0.f, s2 = 0.f;
#pragma unroll
      for (int ni = 0; ni < 4; ++ni) {
        const float tv = tanhf(acc[mi][ni][i2] + bv[ni]);
        trow[ni * 16] = f2bf(tv);
        s1 += tv;
        s2 += tv * tv;
      }
#pragma unroll
      for (int m = 1; m < 16; m <<= 1) {
        s1 += __shfl_xor(s1, m, 64);
        s2 += __shfl_xor(s2, m, 64);
      }
      if (r == 0) {
        float2 p2 = make_float2(s1, s2);
        *(float2*)(part + (size_t)row * 64 + slot * 2) = p2;
      }
    }
  }
}

// --------------------------------------------------------------------------
// Finish obj LN: read T (bf16 tanh), partials; out oe_b = bf16(LN(t)*g+b).
// One block (256 thr) per row.
// --------------------------------------------------------------------------
__global__ __launch_bounds__(256) void k_ep_ln2(const unsigned short* __restrict__ T,
                                                const float* __restrict__ part,
                                                const float* __restrict__ gw,
                                                const float* __restrict__ bw,
                                                unsigned short* __restrict__ obf) {
  const int row = blockIdx.x, t = threadIdx.x;
  float s1 = 0.f, s2 = 0.f;
  if (t < 32) {
    float2 p = ((const float2*)(part + (size_t)row * 64))[t];
    s1 = p.x;
    s2 = p.y;
  }
#pragma unroll
  for (int m = 1; m < 64; m <<= 1) {
    s1 += __shfl_xor(s1, m, 64);
    s2 += __shfl_xor(s2, m, 64);
  }
  __shared__ float sh[2];
  if (t == 0) {
    sh[0] = s1;
    sh[1] = s2;
  }
  __syncthreads();
  const float mean = sh[0] * (1.0f / DD);
  const float var = sh[1] * (1.0f / DD) - mean * mean;
  const float rstd = rsqrtf(var + 1e-5f);
  const size_t base = (size_t)row * DD + t * 8;
  u32x4 tin = *(const u32x4*)(T + base);
  f32x4 g0 = ((const f32x4*)(gw + t * 8))[0], g1 = ((const f32x4*)(gw + t * 8))[1];
  f32x4 bb0 = ((const f32x4*)(bw + t * 8))[0], bb1 = ((const f32x4*)(bw + t * 8))[1];
  float gv[8], bvv[8];
  gv[0] = g0.x; gv[1] = g0.y; gv[2] = g0.z; gv[3] = g0.w;
  gv[4] = g1.x; gv[5] = g1.y; gv[6] = g1.z; gv[7] = g1.w;
  bvv[0] = bb0.x; bvv[1] = bb0.y; bvv[2] = bb0.z; bvv[3] = bb0.w;
  bvv[4] = bb1.x; bvv[5] = bb1.y; bvv[6] = bb1.z; bvv[7] = bb1.w;
  float o[8];
#pragma unroll
  for (int j = 0; j < 4; ++j) {
    const float tl = bf2f((unsigned short)(tin[j] & 0xffffu));
    const float th = bf2f((unsigned short)(tin[j] >> 16));
    o[2 * j] = (tl - mean) * rstd * gv[2 * j] + bvv[2 * j];
    o[2 * j + 1] = (th - mean) * rstd * gv[2 * j + 1] + bvv[2 * j + 1];
  }
  u32x4 p = {pk2(o[0], o[1]), pk2(o[2], o[3]), pk2(o[4], o[5]), pk2(o[6], o[7])};
  *((u32x4*)(obf + base)) = p;
}

// --------------------------------------------------------------------------
// Y[M][2048] = X[M][2048](fp32) @ W + bias (inline convert). Visual branch.
// --------------------------------------------------------------------------
__global__ __launch_bounds__(256) void k_gemm_xw(const float* __restrict__ X,
                                                 const unsigned short* __restrict__ Wt,
                                                 const float* __restrict__ bias,
                                                 float* __restrict__ Y) {
  __shared__ __align__(16) unsigned short As[128 * 32];
  __shared__ __align__(16) unsigned short Bs[128 * 32];
  const int t = threadIdx.x;
  const int lane = t & 63, wave = t >> 6;
  const int r = lane & 15, g = lane >> 4;
  const int wm = wave >> 1, wn = wave & 1;
  const int bm = blockIdx.y * 128, bn = blockIdx.x * 128;
  const int arow = t >> 1, ah = t & 1;
  f32x4 acc[4][4] = {};
  const float* aptr = X + (size_t)(bm + arow) * DD + ah * 16;
  const unsigned short* bptr = Wt + (size_t)(bn + arow) * DD + ah * 16;
  for (int kt = 0; kt < DD / 32; ++kt) {
    const int kb = kt * 32;
    f32x4 a0 = *(const f32x4*)(aptr + kb);
    f32x4 a1 = *(const f32x4*)(aptr + kb + 4);
    f32x4 a2 = *(const f32x4*)(aptr + kb + 8);
    f32x4 a3 = *(const f32x4*)(aptr + kb + 12);
    u32x4 b0 = *(const u32x4*)(bptr + kb);
    u32x4 b1 = *(const u32x4*)(bptr + kb + 8);
    __syncthreads();
    u32x4 p0 = {pk2(a0.x, a0.y), pk2(a0.z, a0.w), pk2(a1.x, a1.y), pk2(a1.z, a1.w)};
    u32x4 p1 = {pk2(a2.x, a2.y), pk2(a2.z, a2.w), pk2(a3.x, a3.y), pk2(a3.z, a3.w)};
    ((u32x4*)As)[arow * 4 + ah * 2 + 0] = p0;
    ((u32x4*)As)[arow * 4 + ah * 2 + 1] = p1;
    ((u32x4*)Bs)[arow * 4 + ah * 2 + 0] = b0;
    ((u32x4*)Bs)[arow * 4 + ah * 2 + 1] = b1;
    __syncthreads();
    bf16x8 af[4], bfr[4];
#pragma unroll
    for (int m = 0; m < 4; ++m) af[m] = ((const bf16x8*)As)[(wm * 64 + m * 16 + r) * 4 + g];
#pragma unroll
    for (int n = 0; n < 4; ++n) bfr[n] = ((const bf16x8*)Bs)[(wn * 64 + n * 16 + r) * 4 + g];
#pragma unroll
    for (int m = 0; m < 4; ++m)
#pragma unroll
      for (int n = 0; n < 4; ++n)
        acc[m][n] = __builtin_amdgcn_mfma_f32_16x16x32_bf16(af[m], bfr[n], acc[m][n], 0, 0, 0);
  }
#pragma unroll
  for (int m = 0; m < 4; ++m) {
    const int row0 = bm + wm * 64 + m * 16 + g * 4;
#pragma unroll
    for (int n = 0; n < 4; ++n) {
      const int col = bn + wn * 64 + n * 16 + r;
      const float bvx = bias[col];
#pragma unroll
      for (int i = 0; i < 4; ++i)
        Y[(size_t)(row0 + i) * DD + col] = acc[m][n][i] + bvx;
    }
  }
}

// --------------------------------------------------------------------------
// Row-wise: t = tanh(Y[row] (+ Y2[row])); LN(t)*g+b -> optional bf16 / fp32.
// --------------------------------------------------------------------------
__global__ __launch_bounds__(256) void k_ep_ln(const float* __restrict__ Y,
                                               const float* __restrict__ Y2,
                                               const float* __restrict__ gw,
                                               const float* __restrict__ bw,
                                               unsigned short* __restrict__ obf,
                                               float* __restrict__ of32) {
  const int row = blockIdx.x, t = threadIdx.x;
  const size_t base = (size_t)row * DD + t * 8;
  f32x4 v0 = ((const f32x4*)(Y + base))[0];
  f32x4 v1 = ((const f32x4*)(Y + base))[1];
  if (Y2 != nullptr) {
    v0 += ((const f32x4*)(Y2 + base))[0];
    v1 += ((const f32x4*)(Y2 + base))[1];
  }
  float tv[8];
#pragma unroll
  for (int j = 0; j < 4; ++j) {
    tv[j] = tanhf(v0[j]);
    tv[4 + j] = tanhf(v1[j]);
  }
  float s1 = 0.f, s2 = 0.f;
#pragma unroll
  for (int j = 0; j < 8; ++j) {
    s1 += tv[j];
    s2 += tv[j] * tv[j];
  }
#pragma unroll
  for (int m = 1; m < 64; m <<= 1) {
    s1 += __shfl_xor(s1, m, 64);
    s2 += __shfl_xor(s2, m, 64);
  }
  __shared__ float r1[4], r2[4];
  const int wave = t >> 6;
  if ((t & 63) == 0) {
    r1[wave] = s1;
    r2[wave] = s2;
  }
  __syncthreads();
  const float S1 = r1[0] + r1[1] + r1[2] + r1[3];
  const float S2 = r2[0] + r2[1] + r2[2] + r2[3];
  const float mean = S1 * (1.0f / DD);
  const float var = S2 * (1.0f / DD) - mean * mean;
  const float rstd = rsqrtf(var + 1e-5f);
  f32x4 g0 = ((const f32x4*)(gw + t * 8))[0], g1 = ((const f32x4*)(gw + t * 8))[1];
  f32x4 bb0 = ((const f32x4*)(bw + t * 8))[0], bb1 = ((const f32x4*)(bw + t * 8))[1];
  float o[8];
#pragma unroll
  for (int j = 0; j < 4; ++j) {
    o[j] = (tv[j] - mean) * rstd * g0[j] + bb0[j];
    o[4 + j] = (tv[4 + j] - mean) * rstd * g1[j] + bb1[j];
  }
  if (obf != nullptr) {
    u32x4 p = {pk2(o[0], o[1]), pk2(o[2], o[3]), pk2(o[4], o[5]), pk2(o[6], o[7])};
    *((u32x4*)(obf + base)) = p;
  }
  if (of32 != nullptr) {
    f32x4 w0 = {o[0], o[1], o[2], o[3]}, w1 = {o[4], o[5], o[6], o[7]};
    ((f32x4*)(of32 + base))[0] = w0;
    ((f32x4*)(of32 + base))[1] = w1;
  }
}

// --------------------------------------------------------------------------
// oe[b][n][d] bf16 -> oeT[b][d][n] bf16, 64x64 tiles. grid (36, 32, 8).
// --------------------------------------------------------------------------
__global__ __launch_bounds__(256) void k_troe(const unsigned short* __restrict__ oe,
                                              unsigned short* __restrict__ oeT) {
  __shared__ unsigned short sh[64][65];
  const int t = threadIdx.x;
  const int b = blockIdx.z, nt = blockIdx.x, dt = blockIdx.y;
  {
    const int nn = t >> 2, seg = t & 3;
    const unsigned short* src = oe + ((size_t)b * NOBJ + nt * 64 + nn) * DD + dt * 64 + seg * 16;
    u32x4 x0 = ((const u32x4*)src)[0];
    u32x4 x1 = ((const u32x4*)src)[1];
    const unsigned short* px0 = (const unsigned short*)&x0;
    const unsigned short* px1 = (const unsigned short*)&x1;
#pragma unroll
    for (int j = 0; j < 8; ++j) {
      sh[nn][seg * 16 + j] = px0[j];
      sh[nn][seg * 16 + 8 + j] = px1[j];
    }
  }
  __syncthreads();
  {
    const int dd = t >> 2, ns = t & 3;
    unsigned int o[8];
#pragma unroll
    for (int j = 0; j < 8; ++j)
      o[j] = (unsigned int)sh[ns * 16 + 2 * j][dd] |
             ((unsigned int)sh[ns * 16 + 2 * j + 1][dd] << 16);
    u32x4 p0 = {o[0], o[1], o[2], o[3]};
    u32x4 p1 = {o[4], o[5], o[6], o[7]};
    unsigned short* dst = oeT + ((size_t)b * DD + dt * 64 + dd) * NOBJ + nt * 64 + ns * 16;
    ((u32x4*)dst)[0] = p0;
    ((u32x4*)dst)[1] = p1;
  }
}

// --------------------------------------------------------------------------
// adjT[b][f][n] = (oe[b][n][:] . ve[b][f][:]) / sqrt(2048).
// --------------------------------------------------------------------------
__global__ __launch_bounds__(256) void k_gemm_adj(const unsigned short* __restrict__ oe,
                                                  const unsigned short* __restrict__ veb,
                                                  float* __restrict__ adjT) {
  __shared__ __align__(16) unsigned short As[128 * 32];
  __shared__ __align__(16) unsigned short Bs[64 * 32];
  const int t = threadIdx.x;
  const int lane = t & 63, wave = t >> 6;
  const int r = lane & 15, g = lane >> 4;
  const int wm = wave >> 1, wn = wave & 1;
  const int b = blockIdx.y, bm = blockIdx.x * 128;
  const int arow = t >> 1, ah = t & 1;
  const int br_ = t >> 2, bseg = t & 3;
  f32x4 acc[4][2] = {};
  const unsigned short* aptr = oe + ((size_t)b * NOBJ + bm + arow) * DD + ah * 16;
  const unsigned short* bptr = veb + ((size_t)b * FF + br_) * DD + bseg * 8;
  for (int kt = 0; kt < DD / 32; ++kt) {
    const int kb = kt * 32;
    u32x4 a0 = ((const u32x4*)(aptr + kb))[0];
    u32x4 a1 = ((const u32x4*)(aptr + kb))[1];
    u32x4 bvx = *(const u32x4*)(bptr + kb);
    __syncthreads();
    ((u32x4*)As)[arow * 4 + ah * 2 + 0] = a0;
    ((u32x4*)As)[arow * 4 + ah * 2 + 1] = a1;
    ((u32x4*)Bs)[br_ * 4 + bseg] = bvx;
    __syncthreads();
    bf16x8 af[4], bfr[2];
#pragma unroll
    for (int m = 0; m < 4; ++m) af[m] = ((const bf16x8*)As)[(wm * 64 + m * 16 + r) * 4 + g];
#pragma unroll
    for (int n = 0; n < 2; ++n) bfr[n] = ((const bf16x8*)Bs)[(wn * 32 + n * 16 + r) * 4 + g];
#pragma unroll
    for (int m = 0; m < 4; ++m)
#pragma unroll
      for (int n = 0; n < 2; ++n)
        acc[m][n] = __builtin_amdgcn_mfma_f32_16x16x32_bf16(af[m], bfr[n], acc[m][n], 0, 0, 0);
  }
  const float scale = 0.02209708691207961f;  // 1/sqrt(2048)
#pragma unroll
  for (int m = 0; m < 4; ++m)
#pragma unroll
    for (int n = 0; n < 2; ++n) {
      const int f = wn * 32 + n * 16 + r;
      const int n0 = bm + wm * 64 + m * 16 + g * 4;
      f32x4 v = acc[m][n];
      v *= scale;
      *(f32x4*)(adjT + ((size_t)b * FF + f) * NOBJ + n0) = v;
    }
}

// --------------------------------------------------------------------------
// Row softmax over 2304 (rows of adjT), write bf16. grid = 512 rows.
// --------------------------------------------------------------------------
__global__ __launch_bounds__(256) void k_smax(const float* __restrict__ adjT,
                                              unsigned short* __restrict__ out) {
  const int t = threadIdx.x;
  const size_t base = (size_t)blockIdx.x * NOBJ;
  float v[9];
#pragma unroll
  for (int j = 0; j < 9; ++j) v[j] = adjT[base + t + j * 256];
  float m = v[0];
#pragma unroll
  for (int j = 1; j < 9; ++j) m = fmaxf(m, v[j]);
#pragma unroll
  for (int s = 1; s < 64; s <<= 1) m = fmaxf(m, __shfl_xor(m, s, 64));
  __shared__ float rm[4], rs[4];
  const int wave = t >> 6;
  if ((t & 63) == 0) rm[wave] = m;
  __syncthreads();
  m = fmaxf(fmaxf(rm[0], rm[1]), fmaxf(rm[2], rm[3]));
  float e[9];
  float s = 0.f;
#pragma unroll
  for (int j = 0; j < 9; ++j) {
    e[j] = __expf(v[j] - m);
    s += e[j];
  }
#pragma unroll
  for (int q = 1; q < 64; q <<= 1) s += __shfl_xor(s, q, 64);
  if ((t & 63) == 0) rs[wave] = s;
  __syncthreads();
  const float S = rs[0] + rs[1] + rs[2] + rs[3];
  const float inv = 1.0f / S;
#pragma unroll
  for (int j = 0; j < 9; ++j) out[base + t + j * 256] = f2bf(e[j] * inv);
}

// --------------------------------------------------------------------------
// agg[b][f][d] = sum_n adj_sm[b][f][n] * oeT[b][d][n].
// --------------------------------------------------------------------------
__global__ __launch_bounds__(256) void k_gemm_agg(const unsigned short* __restrict__ adjsm,
                                                  const unsigned short* __restrict__ oeT,
                                                  float* __restrict__ agg) {
  __shared__ __align__(16) unsigned short As[64 * 32];
  __shared__ __align__(16) unsigned short Bs[128 * 32];
  const int t = threadIdx.x;
  const int lane = t & 63, wave = t >> 6;
  const int r = lane & 15, g = lane >> 4;
  const int wm = wave >> 1, wn = wave & 1;
  const int b = blockIdx.y, bn = blockIdx.x * 128;
  const int ar = t >> 2, aseg = t & 3;
  const int brow = t >> 1, bh = t & 1;
  f32x4 acc[2][4] = {};
  const unsigned short* aptr = adjsm + ((size_t)b * FF + ar) * NOBJ + aseg * 8;
  const unsigned short* bptr = oeT + ((size_t)b * DD + bn + brow) * NOBJ + bh * 16;
  for (int kt = 0; kt < NOBJ / 32; ++kt) {
    const int kb = kt * 32;
    u32x4 av = *(const u32x4*)(aptr + kb);
    u32x4 b0 = ((const u32x4*)(bptr + kb))[0];
    u32x4 b1 = ((const u32x4*)(bptr + kb))[1];
    __syncthreads();
    ((u32x4*)As)[ar * 4 + aseg] = av;
    ((u32x4*)Bs)[brow * 4 + bh * 2 + 0] = b0;
    ((u32x4*)Bs)[brow * 4 + bh * 2 + 1] = b1;
    __syncthreads();
    bf16x8 af[2], bfr[4];
#pragma unroll
    for (int m = 0; m < 2; ++m) af[m] = ((const bf16x8*)As)[(wm * 32 + m * 16 + r) * 4 + g];
#pragma unroll
    for (int n = 0; n < 4; ++n) bfr[n] = ((const bf16x8*)Bs)[(wn * 64 + n * 16 + r) * 4 + g];
#pragma unroll
    for (int m = 0; m < 2; ++m)
#pragma unroll
      for (int n = 0; n < 4; ++n)
        acc[m][n] = __builtin_amdgcn_mfma_f32_16x16x32_bf16(af[m], bfr[n], acc[m][n], 0, 0, 0);
  }
#pragma unroll
  for (int m = 0; m < 2; ++m)
#pragma unroll
    for (int n = 0; n < 4; ++n) {
      const int d = bn + wn * 64 + n * 16 + r;
#pragma unroll
      for (int i = 0; i < 4; ++i) {
        const int f = wm * 32 + m * 16 + g * 4 + i;
        agg[((size_t)b * FF + f) * DD + d] = acc[m][n][i];
      }
    }
}

// --------------------------------------------------------------------------

extern "C" void kernel_launch(void* const* d_in, const int* in_sizes, int n_in,
                              void* d_out, int out_size, void* d_ws, size_t ws_size,
                              hipStream_t stream) {
  (void)in_sizes; (void)n_in; (void)out_size;
  const float* visual = (const float*)d_in[0];
  const float* obj    = (const float*)d_in[1];
  const float* W_v    = (const float*)d_in[2];
  const float* b_v    = (const float*)d_in[3];
  const float* W_o    = (const float*)d_in[4];
  const float* b_o    = (const float*)d_in[5];
  const float* ln_v_g = (const float*)d_in[6];
  const float* ln_v_b = (const float*)d_in[7];
  const float* ln_o_g = (const float*)d_in[8];
  const float* ln_o_b = (const float*)d_in[9];
  const float* ln_ov_g = (const float*)d_in[10];
  const float* ln_ov_b = (const float*)d_in[11];

  // Workspace layout (aliased; ~253 MiB):
  //   [0,8M)      WvT
  //   [8M,16M)    WoT
  //   [16M,88M)   objb (bf16) -> later oe_b (objb dead after obj GEMM)
  //   [88M,160M)  T (bf16 tanh) -> later oeT (T dead after ep_ln2)
  //   [160M,165M) part (LN partials, 4.6 MiB)
  //   [232M,..)   Yv, ve_f, ve_b, adjT, adjs, agg
  char* ws = (char*)d_ws;
  constexpr size_t OFF_WVT = 0;
  constexpr size_t OFF_WOT = 8ull << 20;
  constexpr size_t OFF_OBJB = 16ull << 20;
  constexpr size_t OFF_T   = 88ull << 20;
  constexpr size_t OFF_PART = 160ull << 20;
  constexpr size_t OFF_YV  = 232ull << 20;
  constexpr size_t OFF_VEF = 236ull << 20;
  constexpr size_t OFF_VEB = 240ull << 20;
  constexpr size_t OFF_ADJ = 242ull << 20;
  constexpr size_t OFF_ADJS = OFF_ADJ + 4718592ull;
  constexpr size_t OFF_AGG = OFF_ADJS + 2359296ull;
  constexpr size_t WS_NEED = OFF_AGG + 4194304ull;
  if (ws_size < WS_NEED) return;

  unsigned short* WvT  = (unsigned short*)(ws + OFF_WVT);
  unsigned short* WoT  = (unsigned short*)(ws + OFF_WOT);
  unsigned short* objb = (unsigned short*)(ws + OFF_OBJB);
  unsigned short* oe_b = (unsigned short*)(ws + OFF_OBJB);  // alias (objb dead)
  unsigned short* T    = (unsigned short*)(ws + OFF_T);
  unsigned short* oeT  = (unsigned short*)(ws + OFF_T);     // alias (T dead)
  float* part          = (float*)(ws + OFF_PART);
  float* Yv            = (float*)(ws + OFF_YV);
  float* ve_f          = (float*)(ws + OFF_VEF);
  unsigned short* ve_b = (unsigned short*)(ws + OFF_VEB);
  float* adjT          = (float*)(ws + OFF_ADJ);
  unsigned short* adjs = (unsigned short*)(ws + OFF_ADJS);
  float* agg           = (float*)(ws + OFF_AGG);

  dim3 b256(256);
  // 1) weight transpose+convert (both), obj fp32->bf16
  k_wprep2<<<dim3(32, 32, 2), b256, 0, stream>>>(W_v, W_o, WvT, WoT);
  k_cvt_bf16<<<dim3(2048), b256, 0, stream>>>(obj, objb, MO * DD / 16);
  // 2) branch GEMMs (obj GEMM fused with tanh + LN partials)
  k_gemm_xw<<<dim3(16, MV / 128), b256, 0, stream>>>(visual, WvT, b_v, Yv);
  k_gemm_bbf<<<dim3(8, MO / 256), dim3(512), 0, stream>>>(objb, WoT, b_o, T, part);
  // 3) LN epilogues
  k_ep_ln<<<dim3(MV), b256, 0, stream>>>(Yv, nullptr, ln_v_g, ln_v_b, ve_b, ve_f);
  k_ep_ln2<<<dim3(MO), b256, 0, stream>>>(T, part, ln_o_g, ln_o_b, oe_b);
  // 4) oe transpose (oeT aliases T)
  k_troe<<<dim3(36, 32, 8), b256, 0, stream>>>(oe_b, oeT);
  // 5) adjacency + softmax
  k_gemm_adj<<<dim3(NOBJ / 128, BS), b256, 0, stream>>>(oe_b, ve_b, adjT);
  k_smax<<<dim3(MV), b256, 0, stream>>>(adjT, adjs);
  // 6) aggregation
  k_gemm_agg<<<dim3(DD / 128, BS), b256, 0, stream>>>(adjs, oeT, agg);
  // 7) final add + tanh + LN -> d_out (fp32)
  k_ep_ln<<<dim3(MV), b256, 0, stream>>>(agg, ve_f, ln_ov_g, ln_ov_b, nullptr, (float*)d_out);
}

// Round 8
// 457.629 us; speedup vs baseline: 1.2891x; 1.0638x over previous
//
#include <hip/hip_runtime.h>
#include <cstdint>
#include <cstddef>

// ---------------------------------------------------------------------------
// EnhancedObj: visual/object attention block, bf16-MFMA implementation.
// Shapes (hardcoded): bs=8, F=64, obj=36, d=2048.
//   MO = 18432 object rows, MV = 512 visual rows, NOBJ = 2304.
// Round 8: obj GEMM reverted to the round-3 winner (BM=256 BN=128 BK=64,
// 512 thr 8 waves 4Mx2N, 3 rotating 48KB LDS buffers, counted vmcnt(6),
// raw s_barrier, XOR-swizzled row-major LDS, XCD-bijective swizzle) with
// the round-4-verified fused epilogue grafted on: tanh -> bf16 T + per-row
// LN partial sums (kills the fp32 Yo write + separate MO epilogue pass).
// Tail: adj/agg GEMMs re-tiled to 288/256 blocks (were 144/128 = half the
// CUs idle). All accumulation orders unchanged -> bit-identical output.
// ---------------------------------------------------------------------------

typedef __attribute__((ext_vector_type(4))) float f32x4;
typedef __attribute__((ext_vector_type(4))) unsigned int u32x4;
typedef __attribute__((ext_vector_type(8))) short bf16x8;

#define DD 2048
#define BS 8
#define FF 64
#define NOBJ 2304
#define MO 18432
#define MV 512

__device__ __forceinline__ unsigned short f2bf(float f) {
  unsigned int u = __float_as_uint(f);
  u += 0x7fffu + ((u >> 16) & 1u);          // RTNE (inputs finite)
  return (unsigned short)(u >> 16);
}
__device__ __forceinline__ unsigned int pk2(float a, float b) {
  return (unsigned int)f2bf(a) | ((unsigned int)f2bf(b) << 16);
}
__device__ __forceinline__ float bf2f(unsigned short u) {
  return __uint_as_float((unsigned int)u << 16);
}

typedef __attribute__((address_space(1))) const unsigned int gas_u32;
typedef __attribute__((address_space(3))) unsigned int las_u32;
__device__ __forceinline__ void gl_lds16(const void* g, void* l) {
  __builtin_amdgcn_global_load_lds((gas_u32*)g, (las_u32*)l, 16, 0, 0);
}

// --------------------------------------------------------------------------
// fp32 -> bf16 bulk convert. Each thread: 16 elements per iter.
// --------------------------------------------------------------------------
__global__ __launch_bounds__(256) void k_cvt_bf16(const float* __restrict__ X,
                                                  unsigned short* __restrict__ O,
                                                  int n16) {
  int idx = blockIdx.x * 256 + threadIdx.x;
  const int stride = gridDim.x * 256;
  for (int i = idx; i < n16; i += stride) {
    const f32x4* src = (const f32x4*)(X + (size_t)i * 16);
    f32x4 a = src[0], b = src[1], c = src[2], d = src[3];
    u32x4 p = {pk2(a.x, a.y), pk2(a.z, a.w), pk2(b.x, b.y), pk2(b.z, b.w)};
    u32x4 q = {pk2(c.x, c.y), pk2(c.z, c.w), pk2(d.x, d.y), pk2(d.z, d.w)};
    u32x4* dst = (u32x4*)(O + (size_t)i * 16);
    dst[0] = p;
    dst[1] = q;
  }
}

// --------------------------------------------------------------------------
// Both W[k][n] fp32 (2048x2048) -> Wt[n][k] bf16. 64x64 tiles via LDS.
// grid (32, 32, 2): z selects (W_v -> WvT) or (W_o -> WoT).
// --------------------------------------------------------------------------
__global__ __launch_bounds__(256) void k_wprep2(const float* __restrict__ Wv,
                                                const float* __restrict__ Wo,
                                                unsigned short* __restrict__ WvT,
                                                unsigned short* __restrict__ WoT) {
  __shared__ unsigned short sh[64][65];
  const float* W = blockIdx.z ? Wo : Wv;
  unsigned short* Wt = blockIdx.z ? WoT : WvT;
  const int t = threadIdx.x;
  const int kb = blockIdx.x * 64, nb = blockIdx.y * 64;
  {
    const int rk = t >> 2, seg = t & 3;
    const float* src = W + (size_t)(kb + rk) * DD + nb + seg * 16;
#pragma unroll
    for (int q = 0; q < 4; ++q) {
      f32x4 x = *(const f32x4*)(src + q * 4);
      sh[rk][seg * 16 + q * 4 + 0] = f2bf(x.x);
      sh[rk][seg * 16 + q * 4 + 1] = f2bf(x.y);
      sh[rk][seg * 16 + q * 4 + 2] = f2bf(x.z);
      sh[rk][seg * 16 + q * 4 + 3] = f2bf(x.w);
    }
  }
  __syncthreads();
  {
    const int nn = t >> 2, ks = t & 3;
    unsigned int o[8];
#pragma unroll
    for (int j = 0; j < 8; ++j)
      o[j] = (unsigned int)sh[ks * 16 + 2 * j][nn] |
             ((unsigned int)sh[ks * 16 + 2 * j + 1][nn] << 16);
    u32x4 p0 = {o[0], o[1], o[2], o[3]};
    u32x4 p1 = {o[4], o[5], o[6], o[7]};
    unsigned short* dst = Wt + (size_t)(nb + nn) * DD + kb + ks * 16;
    ((u32x4*)dst)[0] = p0;
    ((u32x4*)dst)[1] = p1;
  }
}

// --------------------------------------------------------------------------
// Obj GEMM fused (round-3 pipeline + fused epilogue):
// T[MO][2048] = bf16(tanh(A@Bt^T + bias)); part[row][32][2] = {sum, sumsq}
// of tanh over 64-col groups.
// BM=256 BN=128 BK=64, 512 thr = 8 waves (wm 0..3, wn 0..1), 64x64 out/wave.
// 3 LDS buffers rotate; iter kt computes buf[kt%3], stages tile kt+2 into
// buf[(kt+2)%3]; end-of-iter s_waitcnt vmcnt(6) (tile kt+1 landed; kt+2's 6
// loads stay in flight ACROSS the barrier) + raw s_barrier.
// LDS: row-major, row r's 16B chunk at phys slot s holds logical
// k16 = s ^ (r&7) (source pre-permuted; ds_read_b128 conflict-free).
// grid = (16, 72); XCD-bijective swizzle (1152 wgs).
// --------------------------------------------------------------------------
__global__ __launch_bounds__(512, 1) void k_gemm_bbf(const unsigned short* __restrict__ A,
                                                     const unsigned short* __restrict__ Bt,
                                                     const float* __restrict__ bias,
                                                     unsigned short* __restrict__ T,
                                                     float* __restrict__ part) {
  // per buffer: A tile 256x64 (16384 e) + B tile 128x64 (8192 e) = 48 KiB
  __shared__ __align__(16) unsigned short lds[3 * 24576];
  const int tid = threadIdx.x;
  const int lane = tid & 63, wave = tid >> 6;
  const int r = lane & 15, g = lane >> 4;
  const int wm = wave >> 1, wn = wave & 1;

  // XCD-aware bijective remap (nwg = 1152, %8 == 0, per = 144)
  const int orig = blockIdx.y * 16 + blockIdx.x;
  const int lin = (orig & 7) * 144 + (orig >> 3);
  const int bm = (lin >> 4) * 256;
  const int bn = (lin & 15) * 128;

  // staging: thread covers 16B chunk c = q*512+tid -> row = c>>3, slot = c&7
  // physical slot holds logical k16 = slot ^ (row&7)  (XOR involution)
  const int srow = tid >> 3;                    // 0..63 (row within q-block)
  const int k16s = (tid & 7) ^ (srow & 7);
  const unsigned short* aSrc[4];
#pragma unroll
  for (int q = 0; q < 4; ++q)
    aSrc[q] = A + (size_t)(bm + q * 64 + srow) * DD + k16s * 8;
  const unsigned short* bSrc[2];
#pragma unroll
  for (int q = 0; q < 2; ++q)
    bSrc[q] = Bt + (size_t)(bn + q * 64 + srow) * DD + k16s * 8;

  auto stage = [&](int buf, int kt) {
    unsigned short* ab = lds + buf * 24576;
    unsigned short* bb = ab + 16384;
    const size_t ko = (size_t)kt * 64;
#pragma unroll
    for (int q = 0; q < 4; ++q)
      gl_lds16(aSrc[q] + ko, ab + ((q * 512 + tid) << 3));
#pragma unroll
    for (int q = 0; q < 2; ++q)
      gl_lds16(bSrc[q] + ko, bb + ((q * 512 + tid) << 3));
  };

  // frag-read swizzled slot offsets (elements): slot = (kk*4+g) ^ (r&7)
  const int rs = r & 7;
  const int sa0 = ((0 + g) ^ rs) * 8;
  const int sa1 = ((4 + g) ^ rs) * 8;
  const int arow0 = wm * 64 + r;
  const int brow0 = wn * 64 + r;

  f32x4 acc[4][4] = {};
  stage(0, 0);
  stage(1, 1);
  asm volatile("s_waitcnt vmcnt(6)" ::: "memory");  // tile0 landed (per wave)
  __builtin_amdgcn_s_barrier();

  for (int kt = 0; kt < DD / 64; ++kt) {
    const int cur = kt % 3;
    if (kt + 2 < DD / 64) stage((kt + 2) % 3, kt + 2);
    const unsigned short* ab = lds + cur * 24576;
    const unsigned short* bb = ab + 16384;
    bf16x8 af[4][2], bfr[4][2];
#pragma unroll
    for (int mi = 0; mi < 4; ++mi) {
      const int ro = (arow0 + mi * 16) * 64;
      af[mi][0] = *(const bf16x8*)(ab + ro + sa0);
      af[mi][1] = *(const bf16x8*)(ab + ro + sa1);
    }
#pragma unroll
    for (int ni = 0; ni < 4; ++ni) {
      const int ro = (brow0 + ni * 16) * 64;
      bfr[ni][0] = *(const bf16x8*)(bb + ro + sa0);
      bfr[ni][1] = *(const bf16x8*)(bb + ro + sa1);
    }
    __builtin_amdgcn_s_setprio(1);
#pragma unroll
    for (int mi = 0; mi < 4; ++mi)
#pragma unroll
      for (int ni = 0; ni < 4; ++ni) {
        acc[mi][ni] = __builtin_amdgcn_mfma_f32_16x16x32_bf16(af[mi][0], bfr[ni][0], acc[mi][ni], 0, 0, 0);
        acc[mi][ni] = __builtin_amdgcn_mfma_f32_16x16x32_bf16(af[mi][1], bfr[ni][1], acc[mi][ni], 0, 0, 0);
      }
    __builtin_amdgcn_s_setprio(0);
    if (kt < DD / 64 - 2) {
      asm volatile("s_waitcnt vmcnt(6)" ::: "memory");  // tile kt+1 landed
    } else {
      asm volatile("s_waitcnt vmcnt(0)" ::: "memory");  // tail drain
    }
    __builtin_amdgcn_s_barrier();
  }

  // ---- fused epilogue: bias + tanh -> bf16 T, per-row partial LN sums ----
  float bv[4];
#pragma unroll
  for (int ni = 0; ni < 4; ++ni) bv[ni] = bias[bn + wn * 64 + ni * 16 + r];
  const int slot = ((lin & 15) << 1) + wn;  // 32 col-groups of 64
#pragma unroll
  for (int mi = 0; mi < 4; ++mi) {
#pragma unroll
    for (int i2 = 0; i2 < 4; ++i2) {
      const int row = bm + wm * 64 + mi * 16 + g * 4 + i2;
      unsigned short* trow = T + (size_t)row * DD + bn + wn * 64 + r;
      float s1 = 0.f, s2 = 0.f;
#pragma unroll
      for (int ni = 0; ni < 4; ++ni) {
        const float tv = tanhf(acc[mi][ni][i2] + bv[ni]);
        trow[ni * 16] = f2bf(tv);
        s1 += tv;
        s2 += tv * tv;
      }
#pragma unroll
      for (int m = 1; m < 16; m <<= 1) {
        s1 += __shfl_xor(s1, m, 64);
        s2 += __shfl_xor(s2, m, 64);
      }
      if (r == 0) {
        float2 p2 = make_float2(s1, s2);
        *(float2*)(part + (size_t)row * 64 + slot * 2) = p2;
      }
    }
  }
}

// --------------------------------------------------------------------------
// Finish obj LN: read T (bf16 tanh), partials; out oe_b = bf16(LN(t)*g+b).
// One block (256 thr) per row.
// --------------------------------------------------------------------------
__global__ __launch_bounds__(256) void k_ep_ln2(const unsigned short* __restrict__ T,
                                                const float* __restrict__ part,
                                                const float* __restrict__ gw,
                                                const float* __restrict__ bw,
                                                unsigned short* __restrict__ obf) {
  const int row = blockIdx.x, t = threadIdx.x;
  float s1 = 0.f, s2 = 0.f;
  if (t < 32) {
    float2 p = ((const float2*)(part + (size_t)row * 64))[t];
    s1 = p.x;
    s2 = p.y;
  }
#pragma unroll
  for (int m = 1; m < 64; m <<= 1) {
    s1 += __shfl_xor(s1, m, 64);
    s2 += __shfl_xor(s2, m, 64);
  }
  __shared__ float sh[2];
  if (t == 0) {
    sh[0] = s1;
    sh[1] = s2;
  }
  __syncthreads();
  const float mean = sh[0] * (1.0f / DD);
  const float var = sh[1] * (1.0f / DD) - mean * mean;
  const float rstd = rsqrtf(var + 1e-5f);
  const size_t base = (size_t)row * DD + t * 8;
  u32x4 tin = *(const u32x4*)(T + base);
  f32x4 g0 = ((const f32x4*)(gw + t * 8))[0], g1 = ((const f32x4*)(gw + t * 8))[1];
  f32x4 bb0 = ((const f32x4*)(bw + t * 8))[0], bb1 = ((const f32x4*)(bw + t * 8))[1];
  float gv[8], bvv[8];
  gv[0] = g0.x; gv[1] = g0.y; gv[2] = g0.z; gv[3] = g0.w;
  gv[4] = g1.x; gv[5] = g1.y; gv[6] = g1.z; gv[7] = g1.w;
  bvv[0] = bb0.x; bvv[1] = bb0.y; bvv[2] = bb0.z; bvv[3] = bb0.w;
  bvv[4] = bb1.x; bvv[5] = bb1.y; bvv[6] = bb1.z; bvv[7] = bb1.w;
  float o[8];
#pragma unroll
  for (int j = 0; j < 4; ++j) {
    const float tl = bf2f((unsigned short)(tin[j] & 0xffffu));
    const float th = bf2f((unsigned short)(tin[j] >> 16));
    o[2 * j] = (tl - mean) * rstd * gv[2 * j] + bvv[2 * j];
    o[2 * j + 1] = (th - mean) * rstd * gv[2 * j + 1] + bvv[2 * j + 1];
  }
  u32x4 p = {pk2(o[0], o[1]), pk2(o[2], o[3]), pk2(o[4], o[5]), pk2(o[6], o[7])};
  *((u32x4*)(obf + base)) = p;
}

// --------------------------------------------------------------------------
// Y[M][2048] = X[M][2048](fp32) @ W + bias (inline convert). Visual branch.
// --------------------------------------------------------------------------
__global__ __launch_bounds__(256) void k_gemm_xw(const float* __restrict__ X,
                                                 const unsigned short* __restrict__ Wt,
                                                 const float* __restrict__ bias,
                                                 float* __restrict__ Y) {
  __shared__ __align__(16) unsigned short As[128 * 32];
  __shared__ __align__(16) unsigned short Bs[128 * 32];
  const int t = threadIdx.x;
  const int lane = t & 63, wave = t >> 6;
  const int r = lane & 15, g = lane >> 4;
  const int wm = wave >> 1, wn = wave & 1;
  const int bm = blockIdx.y * 128, bn = blockIdx.x * 128;
  const int arow = t >> 1, ah = t & 1;
  f32x4 acc[4][4] = {};
  const float* aptr = X + (size_t)(bm + arow) * DD + ah * 16;
  const unsigned short* bptr = Wt + (size_t)(bn + arow) * DD + ah * 16;
  for (int kt = 0; kt < DD / 32; ++kt) {
    const int kb = kt * 32;
    f32x4 a0 = *(const f32x4*)(aptr + kb);
    f32x4 a1 = *(const f32x4*)(aptr + kb + 4);
    f32x4 a2 = *(const f32x4*)(aptr + kb + 8);
    f32x4 a3 = *(const f32x4*)(aptr + kb + 12);
    u32x4 b0 = *(const u32x4*)(bptr + kb);
    u32x4 b1 = *(const u32x4*)(bptr + kb + 8);
    __syncthreads();
    u32x4 p0 = {pk2(a0.x, a0.y), pk2(a0.z, a0.w), pk2(a1.x, a1.y), pk2(a1.z, a1.w)};
    u32x4 p1 = {pk2(a2.x, a2.y), pk2(a2.z, a2.w), pk2(a3.x, a3.y), pk2(a3.z, a3.w)};
    ((u32x4*)As)[arow * 4 + ah * 2 + 0] = p0;
    ((u32x4*)As)[arow * 4 + ah * 2 + 1] = p1;
    ((u32x4*)Bs)[arow * 4 + ah * 2 + 0] = b0;
    ((u32x4*)Bs)[arow * 4 + ah * 2 + 1] = b1;
    __syncthreads();
    bf16x8 af[4], bfr[4];
#pragma unroll
    for (int m = 0; m < 4; ++m) af[m] = ((const bf16x8*)As)[(wm * 64 + m * 16 + r) * 4 + g];
#pragma unroll
    for (int n = 0; n < 4; ++n) bfr[n] = ((const bf16x8*)Bs)[(wn * 64 + n * 16 + r) * 4 + g];
#pragma unroll
    for (int m = 0; m < 4; ++m)
#pragma unroll
      for (int n = 0; n < 4; ++n)
        acc[m][n] = __builtin_amdgcn_mfma_f32_16x16x32_bf16(af[m], bfr[n], acc[m][n], 0, 0, 0);
  }
#pragma unroll
  for (int m = 0; m < 4; ++m) {
    const int row0 = bm + wm * 64 + m * 16 + g * 4;
#pragma unroll
    for (int n = 0; n < 4; ++n) {
      const int col = bn + wn * 64 + n * 16 + r;
      const float bvx = bias[col];
#pragma unroll
      for (int i = 0; i < 4; ++i)
        Y[(size_t)(row0 + i) * DD + col] = acc[m][n][i] + bvx;
    }
  }
}

// --------------------------------------------------------------------------
// Row-wise: t = tanh(Y[row] (+ Y2[row])); LN(t)*g+b -> optional bf16 / fp32.
// --------------------------------------------------------------------------
__global__ __launch_bounds__(256) void k_ep_ln(const float* __restrict__ Y,
                                               const float* __restrict__ Y2,
                                               const float* __restrict__ gw,
                                               const float* __restrict__ bw,
                                               unsigned short* __restrict__ obf,
                                               float* __restrict__ of32) {
  const int row = blockIdx.x, t = threadIdx.x;
  const size_t base = (size_t)row * DD + t * 8;
  f32x4 v0 = ((const f32x4*)(Y + base))[0];
  f32x4 v1 = ((const f32x4*)(Y + base))[1];
  if (Y2 != nullptr) {
    v0 += ((const f32x4*)(Y2 + base))[0];
    v1 += ((const f32x4*)(Y2 + base))[1];
  }
  float tv[8];
#pragma unroll
  for (int j = 0; j < 4; ++j) {
    tv[j] = tanhf(v0[j]);
    tv[4 + j] = tanhf(v1[j]);
  }
  float s1 = 0.f, s2 = 0.f;
#pragma unroll
  for (int j = 0; j < 8; ++j) {
    s1 += tv[j];
    s2 += tv[j] * tv[j];
  }
#pragma unroll
  for (int m = 1; m < 64; m <<= 1) {
    s1 += __shfl_xor(s1, m, 64);
    s2 += __shfl_xor(s2, m, 64);
  }
  __shared__ float r1[4], r2[4];
  const int wave = t >> 6;
  if ((t & 63) == 0) {
    r1[wave] = s1;
    r2[wave] = s2;
  }
  __syncthreads();
  const float S1 = r1[0] + r1[1] + r1[2] + r1[3];
  const float S2 = r2[0] + r2[1] + r2[2] + r2[3];
  const float mean = S1 * (1.0f / DD);
  const float var = S2 * (1.0f / DD) - mean * mean;
  const float rstd = rsqrtf(var + 1e-5f);
  f32x4 g0 = ((const f32x4*)(gw + t * 8))[0], g1 = ((const f32x4*)(gw + t * 8))[1];
  f32x4 bb0 = ((const f32x4*)(bw + t * 8))[0], bb1 = ((const f32x4*)(bw + t * 8))[1];
  float o[8];
#pragma unroll
  for (int j = 0; j < 4; ++j) {
    o[j] = (tv[j] - mean) * rstd * g0[j] + bb0[j];
    o[4 + j] = (tv[4 + j] - mean) * rstd * g1[j] + bb1[j];
  }
  if (obf != nullptr) {
    u32x4 p = {pk2(o[0], o[1]), pk2(o[2], o[3]), pk2(o[4], o[5]), pk2(o[6], o[7])};
    *((u32x4*)(obf + base)) = p;
  }
  if (of32 != nullptr) {
    f32x4 w0 = {o[0], o[1], o[2], o[3]}, w1 = {o[4], o[5], o[6], o[7]};
    ((f32x4*)(of32 + base))[0] = w0;
    ((f32x4*)(of32 + base))[1] = w1;
  }
}

// --------------------------------------------------------------------------
// oe[b][n][d] bf16 -> oeT[b][d][n] bf16, 64x64 tiles. grid (36, 32, 8).
// --------------------------------------------------------------------------
__global__ __launch_bounds__(256) void k_troe(const unsigned short* __restrict__ oe,
                                              unsigned short* __restrict__ oeT) {
  __shared__ unsigned short sh[64][65];
  const int t = threadIdx.x;
  const int b = blockIdx.z, nt = blockIdx.x, dt = blockIdx.y;
  {
    const int nn = t >> 2, seg = t & 3;
    const unsigned short* src = oe + ((size_t)b * NOBJ + nt * 64 + nn) * DD + dt * 64 + seg * 16;
    u32x4 x0 = ((const u32x4*)src)[0];
    u32x4 x1 = ((const u32x4*)src)[1];
    const unsigned short* px0 = (const unsigned short*)&x0;
    const unsigned short* px1 = (const unsigned short*)&x1;
#pragma unroll
    for (int j = 0; j < 8; ++j) {
      sh[nn][seg * 16 + j] = px0[j];
      sh[nn][seg * 16 + 8 + j] = px1[j];
    }
  }
  __syncthreads();
  {
    const int dd = t >> 2, ns = t & 3;
    unsigned int o[8];
#pragma unroll
    for (int j = 0; j < 8; ++j)
      o[j] = (unsigned int)sh[ns * 16 + 2 * j][dd] |
             ((unsigned int)sh[ns * 16 + 2 * j + 1][dd] << 16);
    u32x4 p0 = {o[0], o[1], o[2], o[3]};
    u32x4 p1 = {o[4], o[5], o[6], o[7]};
    unsigned short* dst = oeT + ((size_t)b * DD + dt * 64 + dd) * NOBJ + nt * 64 + ns * 16;
    ((u32x4*)dst)[0] = p0;
    ((u32x4*)dst)[1] = p1;
  }
}

// --------------------------------------------------------------------------
// adjT[b][f][n] = (oe[b][n][:] . ve[b][f][:]) / sqrt(2048).
// BM=64(n), 256 thr 4 waves (wm 0..1 x 32 rows, wn 0..1 x 32 f).
// grid (36, 8) = 288 blocks.
// --------------------------------------------------------------------------
__global__ __launch_bounds__(256) void k_gemm_adj(const unsigned short* __restrict__ oe,
                                                  const unsigned short* __restrict__ veb,
                                                  float* __restrict__ adjT) {
  __shared__ __align__(16) unsigned short As[64 * 32];
  __shared__ __align__(16) unsigned short Bs[64 * 32];
  const int t = threadIdx.x;
  const int lane = t & 63, wave = t >> 6;
  const int r = lane & 15, g = lane >> 4;
  const int wm = wave >> 1, wn = wave & 1;
  const int b = blockIdx.y, bm = blockIdx.x * 64;
  const int arow = t >> 2, aseg = t & 3;
  f32x4 acc[2][2] = {};
  const unsigned short* aptr = oe + ((size_t)b * NOBJ + bm + arow) * DD + aseg * 8;
  const unsigned short* bptr = veb + ((size_t)b * FF + arow) * DD + aseg * 8;
  for (int kt = 0; kt < DD / 32; ++kt) {
    const int kb = kt * 32;
    u32x4 a0 = *(const u32x4*)(aptr + kb);
    u32x4 bvx = *(const u32x4*)(bptr + kb);
    __syncthreads();
    ((u32x4*)As)[arow * 4 + aseg] = a0;
    ((u32x4*)Bs)[arow * 4 + aseg] = bvx;
    __syncthreads();
    bf16x8 af[2], bfr[2];
#pragma unroll
    for (int m = 0; m < 2; ++m) af[m] = ((const bf16x8*)As)[(wm * 32 + m * 16 + r) * 4 + g];
#pragma unroll
    for (int n = 0; n < 2; ++n) bfr[n] = ((const bf16x8*)Bs)[(wn * 32 + n * 16 + r) * 4 + g];
#pragma unroll
    for (int m = 0; m < 2; ++m)
#pragma unroll
      for (int n = 0; n < 2; ++n)
        acc[m][n] = __builtin_amdgcn_mfma_f32_16x16x32_bf16(af[m], bfr[n], acc[m][n], 0, 0, 0);
  }
  const float scale = 0.02209708691207961f;  // 1/sqrt(2048)
#pragma unroll
  for (int m = 0; m < 2; ++m)
#pragma unroll
    for (int n = 0; n < 2; ++n) {
      const int f = wn * 32 + n * 16 + r;
      const int n0 = bm + wm * 32 + m * 16 + g * 4;
      f32x4 v = acc[m][n];
      v *= scale;
      *(f32x4*)(adjT + ((size_t)b * FF + f) * NOBJ + n0) = v;
    }
}

// --------------------------------------------------------------------------
// Row softmax over 2304 (rows of adjT), write bf16. grid = 512 rows.
// --------------------------------------------------------------------------
__global__ __launch_bounds__(256) void k_smax(const float* __restrict__ adjT,
                                              unsigned short* __restrict__ out) {
  const int t = threadIdx.x;
  const size_t base = (size_t)blockIdx.x * NOBJ;
  float v[9];
#pragma unroll
  for (int j = 0; j < 9; ++j) v[j] = adjT[base + t + j * 256];
  float m = v[0];
#pragma unroll
  for (int j = 1; j < 9; ++j) m = fmaxf(m, v[j]);
#pragma unroll
  for (int s = 1; s < 64; s <<= 1) m = fmaxf(m, __shfl_xor(m, s, 64));
  __shared__ float rm[4], rs[4];
  const int wave = t >> 6;
  if ((t & 63) == 0) rm[wave] = m;
  __syncthreads();
  m = fmaxf(fmaxf(rm[0], rm[1]), fmaxf(rm[2], rm[3]));
  float e[9];
  float s = 0.f;
#pragma unroll
  for (int j = 0; j < 9; ++j) {
    e[j] = __expf(v[j] - m);
    s += e[j];
  }
#pragma unroll
  for (int q = 1; q < 64; q <<= 1) s += __shfl_xor(s, q, 64);
  if ((t & 63) == 0) rs[wave] = s;
  __syncthreads();
  const float S = rs[0] + rs[1] + rs[2] + rs[3];
  const float inv = 1.0f / S;
#pragma unroll
  for (int j = 0; j < 9; ++j) out[base + t + j * 256] = f2bf(e[j] * inv);
}

// --------------------------------------------------------------------------
// agg[b][f][d] = sum_n adj_sm[b][f][n] * oeT[b][d][n].
// BN=64(d), 256 thr 4 waves (wm 0..1 x 32 f, wn 0..1 x 32 d).
// grid (32, 8) = 256 blocks.
// --------------------------------------------------------------------------
__global__ __launch_bounds__(256) void k_gemm_agg(const unsigned short* __restrict__ adjsm,
                                                  const unsigned short* __restrict__ oeT,
                                                  float* __restrict__ agg) {
  __shared__ __align__(16) unsigned short As[64 * 32];
  __shared__ __align__(16) unsigned short Bs[64 * 32];
  const int t = threadIdx.x;
  const int lane = t & 63, wave = t >> 6;
  const int r = lane & 15, g = lane >> 4;
  const int wm = wave >> 1, wn = wave & 1;
  const int b = blockIdx.y, bn = blockIdx.x * 64;
  const int arow = t >> 2, aseg = t & 3;
  f32x4 acc[2][2] = {};
  const unsigned short* aptr = adjsm + ((size_t)b * FF + arow) * NOBJ + aseg * 8;
  const unsigned short* bptr = oeT + ((size_t)b * DD + bn + arow) * NOBJ + aseg * 8;
  for (int kt = 0; kt < NOBJ / 32; ++kt) {
    const int kb = kt * 32;
    u32x4 av = *(const u32x4*)(aptr + kb);
    u32x4 bvx = *(const u32x4*)(bptr + kb);
    __syncthreads();
    ((u32x4*)As)[arow * 4 + aseg] = av;
    ((u32x4*)Bs)[arow * 4 + aseg] = bvx;
    __syncthreads();
    bf16x8 af[2], bfr[2];
#pragma unroll
    for (int m = 0; m < 2; ++m) af[m] = ((const bf16x8*)As)[(wm * 32 + m * 16 + r) * 4 + g];
#pragma unroll
    for (int n = 0; n < 2; ++n) bfr[n] = ((const bf16x8*)Bs)[(wn * 32 + n * 16 + r) * 4 + g];
#pragma unroll
    for (int m = 0; m < 2; ++m)
#pragma unroll
      for (int n = 0; n < 2; ++n)
        acc[m][n] = __builtin_amdgcn_mfma_f32_16x16x32_bf16(af[m], bfr[n], acc[m][n], 0, 0, 0);
  }
#pragma unroll
  for (int m = 0; m < 2; ++m)
#pragma unroll
    for (int n = 0; n < 2; ++n) {
      const int d = bn + wn * 32 + n * 16 + r;
#pragma unroll
      for (int i = 0; i < 4; ++i) {
        const int f = wm * 32 + m * 16 + g * 4 + i;
        agg[((size_t)b * FF + f) * DD + d] = acc[m][n][i];
      }
    }
}

// --------------------------------------------------------------------------

extern "C" void kernel_launch(void* const* d_in, const int* in_sizes, int n_in,
                              void* d_out, int out_size, void* d_ws, size_t ws_size,
                              hipStream_t stream) {
  (void)in_sizes; (void)n_in; (void)out_size;
  const float* visual = (const float*)d_in[0];
  const float* obj    = (const float*)d_in[1];
  const float* W_v    = (const float*)d_in[2];
  const float* b_v    = (const float*)d_in[3];
  const float* W_o    = (const float*)d_in[4];
  const float* b_o    = (const float*)d_in[5];
  const float* ln_v_g = (const float*)d_in[6];
  const float* ln_v_b = (const float*)d_in[7];
  const float* ln_o_g = (const float*)d_in[8];
  const float* ln_o_b = (const float*)d_in[9];
  const float* ln_ov_g = (const float*)d_in[10];
  const float* ln_ov_b = (const float*)d_in[11];

  // Workspace layout (aliased; ~249 MiB):
  //   [0,8M)      WvT
  //   [8M,16M)    WoT
  //   [16M,88M)   objb (bf16) -> later oe_b (objb dead after obj GEMM)
  //   [88M,160M)  T (bf16 tanh) -> later oeT (T dead after ep_ln2)
  //   [160M,165M) part (LN partials, 4.6 MiB)
  //   [232M,..)   Yv, ve_f, ve_b, adjT, adjs, agg
  char* ws = (char*)d_ws;
  constexpr size_t OFF_WVT = 0;
  constexpr size_t OFF_WOT = 8ull << 20;
  constexpr size_t OFF_OBJB = 16ull << 20;
  constexpr size_t OFF_T   = 88ull << 20;
  constexpr size_t OFF_PART = 160ull << 20;
  constexpr size_t OFF_YV  = 232ull << 20;
  constexpr size_t OFF_VEF = 236ull << 20;
  constexpr size_t OFF_VEB = 240ull << 20;
  constexpr size_t OFF_ADJ = 242ull << 20;
  constexpr size_t OFF_ADJS = OFF_ADJ + 4718592ull;
  constexpr size_t OFF_AGG = OFF_ADJS + 2359296ull;
  constexpr size_t WS_NEED = OFF_AGG + 4194304ull;
  if (ws_size < WS_NEED) return;

  unsigned short* WvT  = (unsigned short*)(ws + OFF_WVT);
  unsigned short* WoT  = (unsigned short*)(ws + OFF_WOT);
  unsigned short* objb = (unsigned short*)(ws + OFF_OBJB);
  unsigned short* oe_b = (unsigned short*)(ws + OFF_OBJB);  // alias (objb dead)
  unsigned short* T    = (unsigned short*)(ws + OFF_T);
  unsigned short* oeT  = (unsigned short*)(ws + OFF_T);     // alias (T dead)
  float* part          = (float*)(ws + OFF_PART);
  float* Yv            = (float*)(ws + OFF_YV);
  float* ve_f          = (float*)(ws + OFF_VEF);
  unsigned short* ve_b = (unsigned short*)(ws + OFF_VEB);
  float* adjT          = (float*)(ws + OFF_ADJ);
  unsigned short* adjs = (unsigned short*)(ws + OFF_ADJS);
  float* agg           = (float*)(ws + OFF_AGG);

  dim3 b256(256);
  // 1) weight transpose+convert (both), obj fp32->bf16
  k_wprep2<<<dim3(32, 32, 2), b256, 0, stream>>>(W_v, W_o, WvT, WoT);
  k_cvt_bf16<<<dim3(2048), b256, 0, stream>>>(obj, objb, MO * DD / 16);
  // 2) branch GEMMs (obj GEMM fused with tanh + LN partials)
  k_gemm_xw<<<dim3(16, MV / 128), b256, 0, stream>>>(visual, WvT, b_v, Yv);
  k_gemm_bbf<<<dim3(16, MO / 256), dim3(512), 0, stream>>>(objb, WoT, b_o, T, part);
  // 3) LN epilogues
  k_ep_ln<<<dim3(MV), b256, 0, stream>>>(Yv, nullptr, ln_v_g, ln_v_b, ve_b, ve_f);
  k_ep_ln2<<<dim3(MO), b256, 0, stream>>>(T, part, ln_o_g, ln_o_b, oe_b);
  // 4) oe transpose (oeT aliases T)
  k_troe<<<dim3(36, 32, 8), b256, 0, stream>>>(oe_b, oeT);
  // 5) adjacency + softmax
  k_gemm_adj<<<dim3(NOBJ / 64, BS), b256, 0, stream>>>(oe_b, ve_b, adjT);
  k_smax<<<dim3(MV), b256, 0, stream>>>(adjT, adjs);
  // 6) aggregation
  k_gemm_agg<<<dim3(DD / 64, BS), b256, 0, stream>>>(adjs, oeT, agg);
  // 7) final add + tanh + LN -> d_out (fp32)
  k_ep_ln<<<dim3(MV), b256, 0, stream>>>(agg, ve_f, ln_ov_g, ln_ov_b, nullptr, (float*)d_out);
}

// Round 9
// 451.944 us; speedup vs baseline: 1.3053x; 1.0126x over previous
//
#include <hip/hip_runtime.h>
#include <cstdint>
#include <cstddef>

// ---------------------------------------------------------------------------
// EnhancedObj: visual/object attention block, bf16-MFMA implementation.
// Shapes (hardcoded): bs=8, F=64, obj=36, d=2048.
//   MO = 18432 object rows, MV = 512 visual rows, NOBJ = 2304.
// Round 9: round-8 GEMM kept (r3 pipeline + fused tanh/LN-partial epilogue).
// ep_ln2 + troe chain replaced by:
//   k_stats: part -> stats[row] = (mean, rstd)   (bit-identical reduction)
//   k_lnT:   tile-wise LN applied to T; writes oe_b (row-major) AND oeT
//            (transposed via LDS) in ONE pass (300 MB -> 225 MB traffic).
// Workspace re-laid so oeT no longer aliases T (k_lnT reads T, writes oeT):
// oeT takes the dead objb region; adjT/adjs/agg alias dead WvT/WoT.
// ---------------------------------------------------------------------------

typedef __attribute__((ext_vector_type(4))) float f32x4;
typedef __attribute__((ext_vector_type(4))) unsigned int u32x4;
typedef __attribute__((ext_vector_type(8))) short bf16x8;

#define DD 2048
#define BS 8
#define FF 64
#define NOBJ 2304
#define MO 18432
#define MV 512

__device__ __forceinline__ unsigned short f2bf(float f) {
  unsigned int u = __float_as_uint(f);
  u += 0x7fffu + ((u >> 16) & 1u);          // RTNE (inputs finite)
  return (unsigned short)(u >> 16);
}
__device__ __forceinline__ unsigned int pk2(float a, float b) {
  return (unsigned int)f2bf(a) | ((unsigned int)f2bf(b) << 16);
}
__device__ __forceinline__ float bf2f(unsigned short u) {
  return __uint_as_float((unsigned int)u << 16);
}

typedef __attribute__((address_space(1))) const unsigned int gas_u32;
typedef __attribute__((address_space(3))) unsigned int las_u32;
__device__ __forceinline__ void gl_lds16(const void* g, void* l) {
  __builtin_amdgcn_global_load_lds((gas_u32*)g, (las_u32*)l, 16, 0, 0);
}

// --------------------------------------------------------------------------
// fp32 -> bf16 bulk convert. Each thread: 16 elements per iter.
// --------------------------------------------------------------------------
__global__ __launch_bounds__(256) void k_cvt_bf16(const float* __restrict__ X,
                                                  unsigned short* __restrict__ O,
                                                  int n16) {
  int idx = blockIdx.x * 256 + threadIdx.x;
  const int stride = gridDim.x * 256;
  for (int i = idx; i < n16; i += stride) {
    const f32x4* src = (const f32x4*)(X + (size_t)i * 16);
    f32x4 a = src[0], b = src[1], c = src[2], d = src[3];
    u32x4 p = {pk2(a.x, a.y), pk2(a.z, a.w), pk2(b.x, b.y), pk2(b.z, b.w)};
    u32x4 q = {pk2(c.x, c.y), pk2(c.z, c.w), pk2(d.x, d.y), pk2(d.z, d.w)};
    u32x4* dst = (u32x4*)(O + (size_t)i * 16);
    dst[0] = p;
    dst[1] = q;
  }
}

// --------------------------------------------------------------------------
// Both W[k][n] fp32 (2048x2048) -> Wt[n][k] bf16. 64x64 tiles via LDS.
// grid (32, 32, 2): z selects (W_v -> WvT) or (W_o -> WoT).
// --------------------------------------------------------------------------
__global__ __launch_bounds__(256) void k_wprep2(const float* __restrict__ Wv,
                                                const float* __restrict__ Wo,
                                                unsigned short* __restrict__ WvT,
                                                unsigned short* __restrict__ WoT) {
  __shared__ unsigned short sh[64][65];
  const float* W = blockIdx.z ? Wo : Wv;
  unsigned short* Wt = blockIdx.z ? WoT : WvT;
  const int t = threadIdx.x;
  const int kb = blockIdx.x * 64, nb = blockIdx.y * 64;
  {
    const int rk = t >> 2, seg = t & 3;
    const float* src = W + (size_t)(kb + rk) * DD + nb + seg * 16;
#pragma unroll
    for (int q = 0; q < 4; ++q) {
      f32x4 x = *(const f32x4*)(src + q * 4);
      sh[rk][seg * 16 + q * 4 + 0] = f2bf(x.x);
      sh[rk][seg * 16 + q * 4 + 1] = f2bf(x.y);
      sh[rk][seg * 16 + q * 4 + 2] = f2bf(x.z);
      sh[rk][seg * 16 + q * 4 + 3] = f2bf(x.w);
    }
  }
  __syncthreads();
  {
    const int nn = t >> 2, ks = t & 3;
    unsigned int o[8];
#pragma unroll
    for (int j = 0; j < 8; ++j)
      o[j] = (unsigned int)sh[ks * 16 + 2 * j][nn] |
             ((unsigned int)sh[ks * 16 + 2 * j + 1][nn] << 16);
    u32x4 p0 = {o[0], o[1], o[2], o[3]};
    u32x4 p1 = {o[4], o[5], o[6], o[7]};
    unsigned short* dst = Wt + (size_t)(nb + nn) * DD + kb + ks * 16;
    ((u32x4*)dst)[0] = p0;
    ((u32x4*)dst)[1] = p1;
  }
}

// --------------------------------------------------------------------------
// Obj GEMM fused (round-3 pipeline + fused epilogue):
// T[MO][2048] = bf16(tanh(A@Bt^T + bias)); part[row][32][2] = {sum, sumsq}
// of tanh over 64-col groups.
// BM=256 BN=128 BK=64, 512 thr = 8 waves (wm 0..3, wn 0..1), 64x64 out/wave.
// 3 LDS buffers rotate; counted vmcnt(6) + raw s_barrier per K-step.
// grid = (16, 72); XCD-bijective swizzle (1152 wgs).
// --------------------------------------------------------------------------
__global__ __launch_bounds__(512, 1) void k_gemm_bbf(const unsigned short* __restrict__ A,
                                                     const unsigned short* __restrict__ Bt,
                                                     const float* __restrict__ bias,
                                                     unsigned short* __restrict__ T,
                                                     float* __restrict__ part) {
  // per buffer: A tile 256x64 (16384 e) + B tile 128x64 (8192 e) = 48 KiB
  __shared__ __align__(16) unsigned short lds[3 * 24576];
  const int tid = threadIdx.x;
  const int lane = tid & 63, wave = tid >> 6;
  const int r = lane & 15, g = lane >> 4;
  const int wm = wave >> 1, wn = wave & 1;

  // XCD-aware bijective remap (nwg = 1152, %8 == 0, per = 144)
  const int orig = blockIdx.y * 16 + blockIdx.x;
  const int lin = (orig & 7) * 144 + (orig >> 3);
  const int bm = (lin >> 4) * 256;
  const int bn = (lin & 15) * 128;

  // staging: thread covers 16B chunk c = q*512+tid -> row = c>>3, slot = c&7
  // physical slot holds logical k16 = slot ^ (row&7)  (XOR involution)
  const int srow = tid >> 3;                    // 0..63 (row within q-block)
  const int k16s = (tid & 7) ^ (srow & 7);
  const unsigned short* aSrc[4];
#pragma unroll
  for (int q = 0; q < 4; ++q)
    aSrc[q] = A + (size_t)(bm + q * 64 + srow) * DD + k16s * 8;
  const unsigned short* bSrc[2];
#pragma unroll
  for (int q = 0; q < 2; ++q)
    bSrc[q] = Bt + (size_t)(bn + q * 64 + srow) * DD + k16s * 8;

  auto stage = [&](int buf, int kt) {
    unsigned short* ab = lds + buf * 24576;
    unsigned short* bb = ab + 16384;
    const size_t ko = (size_t)kt * 64;
#pragma unroll
    for (int q = 0; q < 4; ++q)
      gl_lds16(aSrc[q] + ko, ab + ((q * 512 + tid) << 3));
#pragma unroll
    for (int q = 0; q < 2; ++q)
      gl_lds16(bSrc[q] + ko, bb + ((q * 512 + tid) << 3));
  };

  // frag-read swizzled slot offsets (elements): slot = (kk*4+g) ^ (r&7)
  const int rs = r & 7;
  const int sa0 = ((0 + g) ^ rs) * 8;
  const int sa1 = ((4 + g) ^ rs) * 8;
  const int arow0 = wm * 64 + r;
  const int brow0 = wn * 64 + r;

  f32x4 acc[4][4] = {};
  stage(0, 0);
  stage(1, 1);
  asm volatile("s_waitcnt vmcnt(6)" ::: "memory");  // tile0 landed (per wave)
  __builtin_amdgcn_s_barrier();

  for (int kt = 0; kt < DD / 64; ++kt) {
    const int cur = kt % 3;
    if (kt + 2 < DD / 64) stage((kt + 2) % 3, kt + 2);
    const unsigned short* ab = lds + cur * 24576;
    const unsigned short* bb = ab + 16384;
    bf16x8 af[4][2], bfr[4][2];
#pragma unroll
    for (int mi = 0; mi < 4; ++mi) {
      const int ro = (arow0 + mi * 16) * 64;
      af[mi][0] = *(const bf16x8*)(ab + ro + sa0);
      af[mi][1] = *(const bf16x8*)(ab + ro + sa1);
    }
#pragma unroll
    for (int ni = 0; ni < 4; ++ni) {
      const int ro = (brow0 + ni * 16) * 64;
      bfr[ni][0] = *(const bf16x8*)(bb + ro + sa0);
      bfr[ni][1] = *(const bf16x8*)(bb + ro + sa1);
    }
    __builtin_amdgcn_s_setprio(1);
#pragma unroll
    for (int mi = 0; mi < 4; ++mi)
#pragma unroll
      for (int ni = 0; ni < 4; ++ni) {
        acc[mi][ni] = __builtin_amdgcn_mfma_f32_16x16x32_bf16(af[mi][0], bfr[ni][0], acc[mi][ni], 0, 0, 0);
        acc[mi][ni] = __builtin_amdgcn_mfma_f32_16x16x32_bf16(af[mi][1], bfr[ni][1], acc[mi][ni], 0, 0, 0);
      }
    __builtin_amdgcn_s_setprio(0);
    if (kt < DD / 64 - 2) {
      asm volatile("s_waitcnt vmcnt(6)" ::: "memory");  // tile kt+1 landed
    } else {
      asm volatile("s_waitcnt vmcnt(0)" ::: "memory");  // tail drain
    }
    __builtin_amdgcn_s_barrier();
  }

  // ---- fused epilogue: bias + tanh -> bf16 T, per-row partial LN sums ----
  float bv[4];
#pragma unroll
  for (int ni = 0; ni < 4; ++ni) bv[ni] = bias[bn + wn * 64 + ni * 16 + r];
  const int slot = ((lin & 15) << 1) + wn;  // 32 col-groups of 64
#pragma unroll
  for (int mi = 0; mi < 4; ++mi) {
#pragma unroll
    for (int i2 = 0; i2 < 4; ++i2) {
      const int row = bm + wm * 64 + mi * 16 + g * 4 + i2;
      unsigned short* trow = T + (size_t)row * DD + bn + wn * 64 + r;
      float s1 = 0.f, s2 = 0.f;
#pragma unroll
      for (int ni = 0; ni < 4; ++ni) {
        const float tv = tanhf(acc[mi][ni][i2] + bv[ni]);
        trow[ni * 16] = f2bf(tv);
        s1 += tv;
        s2 += tv * tv;
      }
#pragma unroll
      for (int m = 1; m < 16; m <<= 1) {
        s1 += __shfl_xor(s1, m, 64);
        s2 += __shfl_xor(s2, m, 64);
      }
      if (r == 0) {
        float2 p2 = make_float2(s1, s2);
        *(float2*)(part + (size_t)row * 64 + slot * 2) = p2;
      }
    }
  }
}

// --------------------------------------------------------------------------
// part[row][32][2] -> stats[row] = (mean, rstd). One 32-lane group per row.
// Balanced 32-leaf tree == ep_ln2's predicated 64-lane butterfly.
// grid = MO/8, block 256.
// --------------------------------------------------------------------------
__global__ __launch_bounds__(256) void k_stats(const float* __restrict__ part,
                                               float2* __restrict__ stats) {
  const int t = threadIdx.x;
  const int row = blockIdx.x * 8 + (t >> 5);
  const int i = t & 31;
  float2 p = ((const float2*)(part + (size_t)row * 64))[i];
  float s1 = p.x, s2 = p.y;
#pragma unroll
  for (int m = 1; m < 32; m <<= 1) {
    s1 += __shfl_xor(s1, m, 64);
    s2 += __shfl_xor(s2, m, 64);
  }
  if (i == 0) {
    const float mean = s1 * (1.0f / DD);
    const float var = s2 * (1.0f / DD) - mean * mean;
    stats[row] = make_float2(mean, rsqrtf(var + 1e-5f));
  }
}

// --------------------------------------------------------------------------
// Fused LN + dual-layout write: o = (T - mean)*rstd*g + b (bf16);
// writes oe[b][n][d] (row-major, coalesced) AND oeT[b][d][n] (via LDS
// transpose, troe pattern). grid (36, 32, 8), block 256.
// --------------------------------------------------------------------------
__global__ __launch_bounds__(256) void k_lnT(const unsigned short* __restrict__ T,
                                             const float2* __restrict__ stats,
                                             const float* __restrict__ gw,
                                             const float* __restrict__ bw,
                                             unsigned short* __restrict__ oe,
                                             unsigned short* __restrict__ oeT) {
  __shared__ unsigned short sh[64][65];
  const int t = threadIdx.x;
  const int b = blockIdx.z, nt = blockIdx.x, dt = blockIdx.y;
  {
    const int nn = t >> 2, seg = t & 3;
    const int row = b * NOBJ + nt * 64 + nn;
    const size_t base = (size_t)row * DD + dt * 64 + seg * 16;
    u32x4 x0 = ((const u32x4*)(T + base))[0];
    u32x4 x1 = ((const u32x4*)(T + base))[1];
    const float2 st = stats[row];
    const float* gp = gw + dt * 64 + seg * 16;
    const float* bp = bw + dt * 64 + seg * 16;
    f32x4 gq[4], bq[4];
#pragma unroll
    for (int q = 0; q < 4; ++q) {
      gq[q] = ((const f32x4*)gp)[q];
      bq[q] = ((const f32x4*)bp)[q];
    }
    const unsigned short* px0 = (const unsigned short*)&x0;
    const unsigned short* px1 = (const unsigned short*)&x1;
    unsigned short ov[16];
#pragma unroll
    for (int j = 0; j < 8; ++j) {
      const float v = bf2f(px0[j]);
      ov[j] = f2bf((v - st.x) * st.y * gq[j >> 2][j & 3] + bq[j >> 2][j & 3]);
    }
#pragma unroll
    for (int j = 0; j < 8; ++j) {
      const float v = bf2f(px1[j]);
      ov[8 + j] = f2bf((v - st.x) * st.y * gq[2 + (j >> 2)][j & 3] + bq[2 + (j >> 2)][j & 3]);
    }
    u32x4 o0 = {(unsigned int)ov[0] | ((unsigned int)ov[1] << 16),
                (unsigned int)ov[2] | ((unsigned int)ov[3] << 16),
                (unsigned int)ov[4] | ((unsigned int)ov[5] << 16),
                (unsigned int)ov[6] | ((unsigned int)ov[7] << 16)};
    u32x4 o1 = {(unsigned int)ov[8] | ((unsigned int)ov[9] << 16),
                (unsigned int)ov[10] | ((unsigned int)ov[11] << 16),
                (unsigned int)ov[12] | ((unsigned int)ov[13] << 16),
                (unsigned int)ov[14] | ((unsigned int)ov[15] << 16)};
    ((u32x4*)(oe + base))[0] = o0;
    ((u32x4*)(oe + base))[1] = o1;
#pragma unroll
    for (int j = 0; j < 16; ++j) sh[nn][seg * 16 + j] = ov[j];
  }
  __syncthreads();
  {
    const int dd = t >> 2, ns = t & 3;
    unsigned int o[8];
#pragma unroll
    for (int j = 0; j < 8; ++j)
      o[j] = (unsigned int)sh[ns * 16 + 2 * j][dd] |
             ((unsigned int)sh[ns * 16 + 2 * j + 1][dd] << 16);
    u32x4 p0 = {o[0], o[1], o[2], o[3]};
    u32x4 p1 = {o[4], o[5], o[6], o[7]};
    unsigned short* dst = oeT + ((size_t)b * DD + dt * 64 + dd) * NOBJ + nt * 64 + ns * 16;
    ((u32x4*)dst)[0] = p0;
    ((u32x4*)dst)[1] = p1;
  }
}

// --------------------------------------------------------------------------
// Y[M][2048] = X[M][2048](fp32) @ W + bias (inline convert). Visual branch.
// --------------------------------------------------------------------------
__global__ __launch_bounds__(256) void k_gemm_xw(const float* __restrict__ X,
                                                 const unsigned short* __restrict__ Wt,
                                                 const float* __restrict__ bias,
                                                 float* __restrict__ Y) {
  __shared__ __align__(16) unsigned short As[128 * 32];
  __shared__ __align__(16) unsigned short Bs[128 * 32];
  const int t = threadIdx.x;
  const int lane = t & 63, wave = t >> 6;
  const int r = lane & 15, g = lane >> 4;
  const int wm = wave >> 1, wn = wave & 1;
  const int bm = blockIdx.y * 128, bn = blockIdx.x * 128;
  const int arow = t >> 1, ah = t & 1;
  f32x4 acc[4][4] = {};
  const float* aptr = X + (size_t)(bm + arow) * DD + ah * 16;
  const unsigned short* bptr = Wt + (size_t)(bn + arow) * DD + ah * 16;
  for (int kt = 0; kt < DD / 32; ++kt) {
    const int kb = kt * 32;
    f32x4 a0 = *(const f32x4*)(aptr + kb);
    f32x4 a1 = *(const f32x4*)(aptr + kb + 4);
    f32x4 a2 = *(const f32x4*)(aptr + kb + 8);
    f32x4 a3 = *(const f32x4*)(aptr + kb + 12);
    u32x4 b0 = *(const u32x4*)(bptr + kb);
    u32x4 b1 = *(const u32x4*)(bptr + kb + 8);
    __syncthreads();
    u32x4 p0 = {pk2(a0.x, a0.y), pk2(a0.z, a0.w), pk2(a1.x, a1.y), pk2(a1.z, a1.w)};
    u32x4 p1 = {pk2(a2.x, a2.y), pk2(a2.z, a2.w), pk2(a3.x, a3.y), pk2(a3.z, a3.w)};
    ((u32x4*)As)[arow * 4 + ah * 2 + 0] = p0;
    ((u32x4*)As)[arow * 4 + ah * 2 + 1] = p1;
    ((u32x4*)Bs)[arow * 4 + ah * 2 + 0] = b0;
    ((u32x4*)Bs)[arow * 4 + ah * 2 + 1] = b1;
    __syncthreads();
    bf16x8 af[4], bfr[4];
#pragma unroll
    for (int m = 0; m < 4; ++m) af[m] = ((const bf16x8*)As)[(wm * 64 + m * 16 + r) * 4 + g];
#pragma unroll
    for (int n = 0; n < 4; ++n) bfr[n] = ((const bf16x8*)Bs)[(wn * 64 + n * 16 + r) * 4 + g];
#pragma unroll
    for (int m = 0; m < 4; ++m)
#pragma unroll
      for (int n = 0; n < 4; ++n)
        acc[m][n] = __builtin_amdgcn_mfma_f32_16x16x32_bf16(af[m], bfr[n], acc[m][n], 0, 0, 0);
  }
#pragma unroll
  for (int m = 0; m < 4; ++m) {
    const int row0 = bm + wm * 64 + m * 16 + g * 4;
#pragma unroll
    for (int n = 0; n < 4; ++n) {
      const int col = bn + wn * 64 + n * 16 + r;
      const float bvx = bias[col];
#pragma unroll
      for (int i = 0; i < 4; ++i)
        Y[(size_t)(row0 + i) * DD + col] = acc[m][n][i] + bvx;
    }
  }
}

// --------------------------------------------------------------------------
// Row-wise: t = tanh(Y[row] (+ Y2[row])); LN(t)*g+b -> optional bf16 / fp32.
// --------------------------------------------------------------------------
__global__ __launch_bounds__(256) void k_ep_ln(const float* __restrict__ Y,
                                               const float* __restrict__ Y2,
                                               const float* __restrict__ gw,
                                               const float* __restrict__ bw,
                                               unsigned short* __restrict__ obf,
                                               float* __restrict__ of32) {
  const int row = blockIdx.x, t = threadIdx.x;
  const size_t base = (size_t)row * DD + t * 8;
  f32x4 v0 = ((const f32x4*)(Y + base))[0];
  f32x4 v1 = ((const f32x4*)(Y + base))[1];
  if (Y2 != nullptr) {
    v0 += ((const f32x4*)(Y2 + base))[0];
    v1 += ((const f32x4*)(Y2 + base))[1];
  }
  float tv[8];
#pragma unroll
  for (int j = 0; j < 4; ++j) {
    tv[j] = tanhf(v0[j]);
    tv[4 + j] = tanhf(v1[j]);
  }
  float s1 = 0.f, s2 = 0.f;
#pragma unroll
  for (int j = 0; j < 8; ++j) {
    s1 += tv[j];
    s2 += tv[j] * tv[j];
  }
#pragma unroll
  for (int m = 1; m < 64; m <<= 1) {
    s1 += __shfl_xor(s1, m, 64);
    s2 += __shfl_xor(s2, m, 64);
  }
  __shared__ float r1[4], r2[4];
  const int wave = t >> 6;
  if ((t & 63) == 0) {
    r1[wave] = s1;
    r2[wave] = s2;
  }
  __syncthreads();
  const float S1 = r1[0] + r1[1] + r1[2] + r1[3];
  const float S2 = r2[0] + r2[1] + r2[2] + r2[3];
  const float mean = S1 * (1.0f / DD);
  const float var = S2 * (1.0f / DD) - mean * mean;
  const float rstd = rsqrtf(var + 1e-5f);
  f32x4 g0 = ((const f32x4*)(gw + t * 8))[0], g1 = ((const f32x4*)(gw + t * 8))[1];
  f32x4 bb0 = ((const f32x4*)(bw + t * 8))[0], bb1 = ((const f32x4*)(bw + t * 8))[1];
  float o[8];
#pragma unroll
  for (int j = 0; j < 4; ++j) {
    o[j] = (tv[j] - mean) * rstd * g0[j] + bb0[j];
    o[4 + j] = (tv[4 + j] - mean) * rstd * g1[j] + bb1[j];
  }
  if (obf != nullptr) {
    u32x4 p = {pk2(o[0], o[1]), pk2(o[2], o[3]), pk2(o[4], o[5]), pk2(o[6], o[7])};
    *((u32x4*)(obf + base)) = p;
  }
  if (of32 != nullptr) {
    f32x4 w0 = {o[0], o[1], o[2], o[3]}, w1 = {o[4], o[5], o[6], o[7]};
    ((f32x4*)(of32 + base))[0] = w0;
    ((f32x4*)(of32 + base))[1] = w1;
  }
}

// --------------------------------------------------------------------------
// adjT[b][f][n] = (oe[b][n][:] . ve[b][f][:]) / sqrt(2048).
// BM=64(n), 256 thr 4 waves. grid (36, 8) = 288 blocks.
// --------------------------------------------------------------------------
__global__ __launch_bounds__(256) void k_gemm_adj(const unsigned short* __restrict__ oe,
                                                  const unsigned short* __restrict__ veb,
                                                  float* __restrict__ adjT) {
  __shared__ __align__(16) unsigned short As[64 * 32];
  __shared__ __align__(16) unsigned short Bs[64 * 32];
  const int t = threadIdx.x;
  const int lane = t & 63, wave = t >> 6;
  const int r = lane & 15, g = lane >> 4;
  const int wm = wave >> 1, wn = wave & 1;
  const int b = blockIdx.y, bm = blockIdx.x * 64;
  const int arow = t >> 2, aseg = t & 3;
  f32x4 acc[2][2] = {};
  const unsigned short* aptr = oe + ((size_t)b * NOBJ + bm + arow) * DD + aseg * 8;
  const unsigned short* bptr = veb + ((size_t)b * FF + arow) * DD + aseg * 8;
  for (int kt = 0; kt < DD / 32; ++kt) {
    const int kb = kt * 32;
    u32x4 a0 = *(const u32x4*)(aptr + kb);
    u32x4 bvx = *(const u32x4*)(bptr + kb);
    __syncthreads();
    ((u32x4*)As)[arow * 4 + aseg] = a0;
    ((u32x4*)Bs)[arow * 4 + aseg] = bvx;
    __syncthreads();
    bf16x8 af[2], bfr[2];
#pragma unroll
    for (int m = 0; m < 2; ++m) af[m] = ((const bf16x8*)As)[(wm * 32 + m * 16 + r) * 4 + g];
#pragma unroll
    for (int n = 0; n < 2; ++n) bfr[n] = ((const bf16x8*)Bs)[(wn * 32 + n * 16 + r) * 4 + g];
#pragma unroll
    for (int m = 0; m < 2; ++m)
#pragma unroll
      for (int n = 0; n < 2; ++n)
        acc[m][n] = __builtin_amdgcn_mfma_f32_16x16x32_bf16(af[m], bfr[n], acc[m][n], 0, 0, 0);
  }
  const float scale = 0.02209708691207961f;  // 1/sqrt(2048)
#pragma unroll
  for (int m = 0; m < 2; ++m)
#pragma unroll
    for (int n = 0; n < 2; ++n) {
      const int f = wn * 32 + n * 16 + r;
      const int n0 = bm + wm * 32 + m * 16 + g * 4;
      f32x4 v = acc[m][n];
      v *= scale;
      *(f32x4*)(adjT + ((size_t)b * FF + f) * NOBJ + n0) = v;
    }
}

// --------------------------------------------------------------------------
// Row softmax over 2304 (rows of adjT), write bf16. grid = 512 rows.
// --------------------------------------------------------------------------
__global__ __launch_bounds__(256) void k_smax(const float* __restrict__ adjT,
                                              unsigned short* __restrict__ out) {
  const int t = threadIdx.x;
  const size_t base = (size_t)blockIdx.x * NOBJ;
  float v[9];
#pragma unroll
  for (int j = 0; j < 9; ++j) v[j] = adjT[base + t + j * 256];
  float m = v[0];
#pragma unroll
  for (int j = 1; j < 9; ++j) m = fmaxf(m, v[j]);
#pragma unroll
  for (int s = 1; s < 64; s <<= 1) m = fmaxf(m, __shfl_xor(m, s, 64));
  __shared__ float rm[4], rs[4];
  const int wave = t >> 6;
  if ((t & 63) == 0) rm[wave] = m;
  __syncthreads();
  m = fmaxf(fmaxf(rm[0], rm[1]), fmaxf(rm[2], rm[3]));
  float e[9];
  float s = 0.f;
#pragma unroll
  for (int j = 0; j < 9; ++j) {
    e[j] = __expf(v[j] - m);
    s += e[j];
  }
#pragma unroll
  for (int q = 1; q < 64; q <<= 1) s += __shfl_xor(s, q, 64);
  if ((t & 63) == 0) rs[wave] = s;
  __syncthreads();
  const float S = rs[0] + rs[1] + rs[2] + rs[3];
  const float inv = 1.0f / S;
#pragma unroll
  for (int j = 0; j < 9; ++j) out[base + t + j * 256] = f2bf(e[j] * inv);
}

// --------------------------------------------------------------------------
// agg[b][f][d] = sum_n adj_sm[b][f][n] * oeT[b][d][n].
// BN=64(d), 256 thr 4 waves. grid (32, 8) = 256 blocks.
// --------------------------------------------------------------------------
__global__ __launch_bounds__(256) void k_gemm_agg(const unsigned short* __restrict__ adjsm,
                                                  const unsigned short* __restrict__ oeT,
                                                  float* __restrict__ agg) {
  __shared__ __align__(16) unsigned short As[64 * 32];
  __shared__ __align__(16) unsigned short Bs[64 * 32];
  const int t = threadIdx.x;
  const int lane = t & 63, wave = t >> 6;
  const int r = lane & 15, g = lane >> 4;
  const int wm = wave >> 1, wn = wave & 1;
  const int b = blockIdx.y, bn = blockIdx.x * 64;
  const int arow = t >> 2, aseg = t & 3;
  f32x4 acc[2][2] = {};
  const unsigned short* aptr = adjsm + ((size_t)b * FF + arow) * NOBJ + aseg * 8;
  const unsigned short* bptr = oeT + ((size_t)b * DD + bn + arow) * NOBJ + aseg * 8;
  for (int kt = 0; kt < NOBJ / 32; ++kt) {
    const int kb = kt * 32;
    u32x4 av = *(const u32x4*)(aptr + kb);
    u32x4 bvx = *(const u32x4*)(bptr + kb);
    __syncthreads();
    ((u32x4*)As)[arow * 4 + aseg] = av;
    ((u32x4*)Bs)[arow * 4 + aseg] = bvx;
    __syncthreads();
    bf16x8 af[2], bfr[2];
#pragma unroll
    for (int m = 0; m < 2; ++m) af[m] = ((const bf16x8*)As)[(wm * 32 + m * 16 + r) * 4 + g];
#pragma unroll
    for (int n = 0; n < 2; ++n) bfr[n] = ((const bf16x8*)Bs)[(wn * 32 + n * 16 + r) * 4 + g];
#pragma unroll
    for (int m = 0; m < 2; ++m)
#pragma unroll
      for (int n = 0; n < 2; ++n)
        acc[m][n] = __builtin_amdgcn_mfma_f32_16x16x32_bf16(af[m], bfr[n], acc[m][n], 0, 0, 0);
  }
#pragma unroll
  for (int m = 0; m < 2; ++m)
#pragma unroll
    for (int n = 0; n < 2; ++n) {
      const int d = bn + wn * 32 + n * 16 + r;
#pragma unroll
      for (int i = 0; i < 4; ++i) {
        const int f = wm * 32 + m * 16 + g * 4 + i;
        agg[((size_t)b * FF + f) * DD + d] = acc[m][n][i];
      }
    }
}

// --------------------------------------------------------------------------

extern "C" void kernel_launch(void* const* d_in, const int* in_sizes, int n_in,
                              void* d_out, int out_size, void* d_ws, size_t ws_size,
                              hipStream_t stream) {
  (void)in_sizes; (void)n_in; (void)out_size;
  const float* visual = (const float*)d_in[0];
  const float* obj    = (const float*)d_in[1];
  const float* W_v    = (const float*)d_in[2];
  const float* b_v    = (const float*)d_in[3];
  const float* W_o    = (const float*)d_in[4];
  const float* b_o    = (const float*)d_in[5];
  const float* ln_v_g = (const float*)d_in[6];
  const float* ln_v_b = (const float*)d_in[7];
  const float* ln_o_g = (const float*)d_in[8];
  const float* ln_o_b = (const float*)d_in[9];
  const float* ln_ov_g = (const float*)d_in[10];
  const float* ln_ov_b = (const float*)d_in[11];

  // Workspace layout (248 MiB; aliases annotated with lifetimes):
  //   [0,8M)      WvT (dead after gemm_xw)      -> adjT @0 (4.5M), adjs @5M
  //   [8M,16M)    WoT (dead after gemm_bbf)     -> agg @8M (4M)
  //   [16M,88M)   objb (dead after gemm_bbf)    -> oeT (written by k_lnT)
  //   [88M,160M)  T (bf16 tanh; read by k_lnT)
  //   [160M,165M) part
  //   [165M,166M) stats (147 KB)
  //   [166M,170M) Yv
  //   [170M,174M) ve_f
  //   [174M,176M) ve_b
  //   [176M,248M) oe_b
  char* ws = (char*)d_ws;
  constexpr size_t OFF_WVT  = 0;
  constexpr size_t OFF_ADJ  = 0;                  // alias (WvT dead)
  constexpr size_t OFF_ADJS = 5ull << 20;         // alias (WvT dead)
  constexpr size_t OFF_WOT  = 8ull << 20;
  constexpr size_t OFF_AGG  = 8ull << 20;         // alias (WoT dead)
  constexpr size_t OFF_OBJB = 16ull << 20;
  constexpr size_t OFF_OET  = 16ull << 20;        // alias (objb dead)
  constexpr size_t OFF_T    = 88ull << 20;
  constexpr size_t OFF_PART = 160ull << 20;
  constexpr size_t OFF_STAT = 165ull << 20;
  constexpr size_t OFF_YV   = 166ull << 20;
  constexpr size_t OFF_VEF  = 170ull << 20;
  constexpr size_t OFF_VEB  = 174ull << 20;
  constexpr size_t OFF_OEB  = 176ull << 20;
  constexpr size_t WS_NEED  = 248ull << 20;
  if (ws_size < WS_NEED) return;

  unsigned short* WvT  = (unsigned short*)(ws + OFF_WVT);
  unsigned short* WoT  = (unsigned short*)(ws + OFF_WOT);
  unsigned short* objb = (unsigned short*)(ws + OFF_OBJB);
  unsigned short* oeT  = (unsigned short*)(ws + OFF_OET);
  unsigned short* T    = (unsigned short*)(ws + OFF_T);
  float* part          = (float*)(ws + OFF_PART);
  float2* stats        = (float2*)(ws + OFF_STAT);
  float* Yv            = (float*)(ws + OFF_YV);
  float* ve_f          = (float*)(ws + OFF_VEF);
  unsigned short* ve_b = (unsigned short*)(ws + OFF_VEB);
  unsigned short* oe_b = (unsigned short*)(ws + OFF_OEB);
  float* adjT          = (float*)(ws + OFF_ADJ);
  unsigned short* adjs = (unsigned short*)(ws + OFF_ADJS);
  float* agg           = (float*)(ws + OFF_AGG);

  dim3 b256(256);
  // 1) weight transpose+convert (both), obj fp32->bf16
  k_wprep2<<<dim3(32, 32, 2), b256, 0, stream>>>(W_v, W_o, WvT, WoT);
  k_cvt_bf16<<<dim3(2048), b256, 0, stream>>>(obj, objb, MO * DD / 16);
  // 2) branch GEMMs (obj GEMM fused with tanh + LN partials)
  k_gemm_xw<<<dim3(16, MV / 128), b256, 0, stream>>>(visual, WvT, b_v, Yv);
  k_gemm_bbf<<<dim3(16, MO / 256), dim3(512), 0, stream>>>(objb, WoT, b_o, T, part);
  // 3) LN finish: visual row-wise; obj stats + fused LN/transpose
  k_ep_ln<<<dim3(MV), b256, 0, stream>>>(Yv, nullptr, ln_v_g, ln_v_b, ve_b, ve_f);
  k_stats<<<dim3(MO / 8), b256, 0, stream>>>(part, stats);
  k_lnT<<<dim3(36, 32, 8), b256, 0, stream>>>(T, stats, ln_o_g, ln_o_b, oe_b, oeT);
  // 4) adjacency + softmax
  k_gemm_adj<<<dim3(NOBJ / 64, BS), b256, 0, stream>>>(oe_b, ve_b, adjT);
  k_smax<<<dim3(MV), b256, 0, stream>>>(adjT, adjs);
  // 5) aggregation
  k_gemm_agg<<<dim3(DD / 64, BS), b256, 0, stream>>>(adjs, oeT, agg);
  // 6) final add + tanh + LN -> d_out (fp32)
  k_ep_ln<<<dim3(MV), b256, 0, stream>>>(agg, ve_f, ln_ov_g, ln_ov_b, nullptr, (float*)d_out);
}